// Round 6
// baseline (1039.182 us; speedup 1.0000x reference)
//
#include <hip/hip_runtime.h>
#include <stdint.h>

typedef unsigned short u16;
typedef __bf16 bf16v8 __attribute__((ext_vector_type(8)));
typedef u16    u16v8  __attribute__((ext_vector_type(8)));
typedef float  f32x4  __attribute__((ext_vector_type(4)));
typedef int    i32x4  __attribute__((ext_vector_type(4)));

#define MFMA_BF16(a,b,c) __builtin_amdgcn_mfma_f32_16x16x32_bf16((a),(b),(c),0,0,0)
#define MFMA_I8(a,b,c)   __builtin_amdgcn_mfma_i32_16x16x64_i8((a),(b),(c),0,0,0)

__device__ __forceinline__ float b2f(u16 u){ union{unsigned u;float f;}v; v.u=((unsigned)u)<<16; return v.f; }
__device__ __forceinline__ u16 f2b(float f){ union{float f;unsigned u;}v; v.f=f;
  return (u16)((v.u + 0x7fffu + ((v.u>>16)&1u))>>16); }
__device__ __forceinline__ bf16v8 ldv8(const u16* p){ return __builtin_bit_cast(bf16v8, *(const u16v8*)p); }
__device__ __forceinline__ void gl2lds16(const void* g, void* l){
  __builtin_amdgcn_global_load_lds(
    (const __attribute__((address_space(1))) unsigned int*)g,
    (__attribute__((address_space(3))) unsigned int*)l,
    16, 0, 0);
}
__device__ __forceinline__ float gelu_t(float x){
  float t = tanhf(0.7978845608028654f*(x + 0.044715f*x*x*x));
  return 0.5f*x*(1.0f+t);
}

// ---------------- elementwise / prep ----------------
__global__ void mod_add_k(const float* __restrict__ sst, const float* __restrict__ t, float* __restrict__ mod){
  int i = blockIdx.x*256 + threadIdx.x;
  if (i < 2*6*1152) mod[i] = sst[i % 6912] + t[i];
}
__global__ void conv_i8_k(const int* __restrict__ src, int8_t* __restrict__ dst, int n){
  int i = blockIdx.x*256 + threadIdx.x;
  if (i < n) dst[i] = (int8_t)src[i];
}
// f32 -> bf16 hi/lo planes
__global__ void split2_k(const float* __restrict__ src, u16* __restrict__ hi, u16* __restrict__ lo, int n){
  int i = blockIdx.x*256 + threadIdx.x;
  if (i >= n) return;
  float v = src[i];
  u16 hh = f2b(v);
  hi[i] = hh; lo[i] = f2b(v - b2f(hh));
}
// LN over C=1152 with modulation -> hi/lo bf16 planes
__global__ void ln_mod_split_k(const float* __restrict__ src, u16* __restrict__ xh, u16* __restrict__ xl,
                               const float* __restrict__ mod, int shift_row, int scale_row){
  const int row = blockIdx.x, tid = threadIdx.x;
  const int b = row >> 11;
  const float* ms = mod + ((size_t)b*6 + shift_row)*1152;
  const float* mc = mod + ((size_t)b*6 + scale_row)*1152;
  __shared__ float r1[256], r2[256];
  float s = 0.f, sq = 0.f, vals[5]; int cnt = 0;
  for (int c = tid; c < 1152; c += 256){
    float v = src[(size_t)row*1152+c];
    vals[cnt++] = v; s += v; sq += v*v;
  }
  r1[tid]=s; r2[tid]=sq; __syncthreads();
  for (int st=128; st>0; st>>=1){ if (tid<st){ r1[tid]+=r1[tid+st]; r2[tid]+=r2[tid+st]; } __syncthreads(); }
  float mean = r1[0]*(1.f/1152.f);
  float var  = r2[0]*(1.f/1152.f) - mean*mean;
  float rstd = rsqrtf(var + 1e-6f);
  cnt = 0;
  for (int c = tid; c < 1152; c += 256){
    float v = (vals[cnt++]-mean)*rstd*(1.f+mc[c]) + ms[c];
    u16 hh = f2b(v);
    xh[(size_t)row*1152+c] = hh;
    xl[(size_t)row*1152+c] = f2b(v - b2f(hh));
  }
}
// fused: xw = x + gate*ao, then per-row int8 quant of xw
__global__ void rgq_k(const float* __restrict__ x, const float* __restrict__ ao,
                      const float* __restrict__ mod, int gate_row, float* __restrict__ xw,
                      int8_t* __restrict__ q8, float* __restrict__ s_out, int* __restrict__ q_out){
  const int row = blockIdx.x, tid = threadIdx.x;
  const int b = row >> 11;
  const float* mg = mod + ((size_t)b*6 + gate_row)*1152;
  __shared__ float r1[256];
  __shared__ int ri[256];
  float mx = 0.f, vals[5]; int cnt = 0;
  for (int c = tid; c < 1152; c += 256){
    float v = x[(size_t)row*1152+c] + mg[c]*ao[(size_t)row*1152+c];
    xw[(size_t)row*1152+c] = v;
    vals[cnt++] = v; mx = fmaxf(mx, fabsf(v));
  }
  r1[tid]=mx; __syncthreads();
  for (int st=128; st>0; st>>=1){ if (tid<st) r1[tid]=fmaxf(r1[tid],r1[tid+st]); __syncthreads(); }
  const float s_ = fmaxf(r1[0]*(1.f/127.f), 1e-8f);
  const float inv = 1.f/s_;
  int acc = 0; cnt = 0;
  for (int c = tid; c < 1152; c += 256){
    float q = rintf(vals[cnt++]*inv);
    q = fminf(fmaxf(q, -127.f), 127.f);
    q8[(size_t)row*1152+c] = (int8_t)q;
    acc += (int)q;
  }
  ri[tid]=acc; __syncthreads();
  for (int st=128; st>0; st>>=1){ if (tid<st) ri[tid]+=ri[tid+st]; __syncthreads(); }
  if (tid==0){ s_out[row]=s_; q_out[row]=ri[0]; }
}
// fused: xw += add; LN+mod; per-row int8 quant
__global__ void rlq_k(float* __restrict__ xw, const float* __restrict__ add,
                      const float* __restrict__ mod, int shift_row, int scale_row,
                      int8_t* __restrict__ q8, float* __restrict__ s_out, int* __restrict__ q_out){
  const int row = blockIdx.x, tid = threadIdx.x;
  const int b = row >> 11;
  const float* ms = mod + ((size_t)b*6 + shift_row)*1152;
  const float* mc = mod + ((size_t)b*6 + scale_row)*1152;
  __shared__ float r1[256], r2[256];
  __shared__ int ri[256];
  float s = 0.f, sq = 0.f, vals[5]; int cnt = 0;
  for (int c = tid; c < 1152; c += 256){
    float v = xw[(size_t)row*1152+c] + add[(size_t)row*1152+c];
    xw[(size_t)row*1152+c] = v;
    vals[cnt++] = v; s += v; sq += v*v;
  }
  r1[tid]=s; r2[tid]=sq; __syncthreads();
  for (int st=128; st>0; st>>=1){ if (tid<st){ r1[tid]+=r1[tid+st]; r2[tid]+=r2[tid+st]; } __syncthreads(); }
  float mean = r1[0]*(1.f/1152.f);
  float var  = r2[0]*(1.f/1152.f) - mean*mean;
  float rstd = rsqrtf(var + 1e-6f);
  __syncthreads();
  float mx = 0.f; cnt = 0;
  for (int c = tid; c < 1152; c += 256){
    float v = (vals[cnt]-mean)*rstd*(1.f+mc[c]) + ms[c];
    vals[cnt++] = v; mx = fmaxf(mx, fabsf(v));
  }
  r1[tid]=mx; __syncthreads();
  for (int st=128; st>0; st>>=1){ if (tid<st) r1[tid]=fmaxf(r1[tid],r1[tid+st]); __syncthreads(); }
  const float s_ = fmaxf(r1[0]*(1.f/127.f), 1e-8f);
  const float inv = 1.f/s_;
  int acc = 0; cnt = 0;
  for (int c = tid; c < 1152; c += 256){
    float q = rintf(vals[cnt++]*inv);
    q = fminf(fmaxf(q, -127.f), 127.f);
    q8[(size_t)row*1152+c] = (int8_t)q;
    acc += (int)q;
  }
  ri[tid]=acc; __syncthreads();
  for (int st=128; st>0; st>>=1){ if (tid<st) ri[tid]+=ri[tid+st]; __syncthreads(); }
  if (tid==0){ s_out[row]=s_; q_out[row]=ri[0]; }
}
// register-cached row quant (C_ <= 4608)
template<int SRC_F32>
__global__ void quant_rows_k(const void* __restrict__ src, int C_,
                             int8_t* __restrict__ q8, float* __restrict__ s_out, int* __restrict__ q_out){
  const int row = blockIdx.x, tid = threadIdx.x;
  __shared__ float red[256];
  __shared__ int redi[256];
  float vals[18];
  float mx = 0.f; int cnt = 0;
  for (int c = tid; c < C_; c += 256){
    float v = SRC_F32 ? ((const float*)src)[(size_t)row*C_+c] : b2f(((const u16*)src)[(size_t)row*C_+c]);
    vals[cnt++] = v;
    mx = fmaxf(mx, fabsf(v));
  }
  red[tid]=mx; __syncthreads();
  for (int st=128; st>0; st>>=1){ if (tid<st) red[tid]=fmaxf(red[tid],red[tid+st]); __syncthreads(); }
  const float s_ = fmaxf(red[0]*(1.f/127.f), 1e-8f);
  const float inv = 1.f/s_;
  int acc = 0; cnt = 0;
  for (int c = tid; c < C_; c += 256){
    float q = rintf(vals[cnt++]*inv);
    q = fminf(fmaxf(q, -127.f), 127.f);
    q8[(size_t)row*C_+c] = (int8_t)q;
    acc += (int)q;
  }
  redi[tid]=acc; __syncthreads();
  for (int st=128; st>0; st>>=1){ if (tid<st) redi[tid]+=redi[tid+st]; __syncthreads(); }
  if (tid==0){ s_out[row]=s_; q_out[row]=redi[0]; }
}
__global__ void final_out_f32_k(const float* __restrict__ xw, const float* __restrict__ h,
                                const float* __restrict__ mod, float* __restrict__ out){
  size_t i = (size_t)blockIdx.x*256 + threadIdx.x;
  if (i >= (size_t)4096*1152) return;
  int c = (int)(i % 1152); int b = (int)((i/1152) >> 11);
  out[i] = xw[i] + mod[((size_t)b*6+5)*1152 + c] * h[i];
}
__global__ void build_vt_cross_k(const float* __restrict__ kv32, u16* __restrict__ vt){
  int h = blockIdx.x;
  u16* dst = vt + (size_t)h*80*448;
  const float* srcb = kv32 + 1152 + h*72;
  for (int idx = threadIdx.x; idx < 72*448; idx += 256){
    int d = idx/448, ss = idx - d*448;
    dst[d*448 + ss] = f2b(srcb[(size_t)ss*2304 + d]);
  }
}
__global__ void build_kv_split_k(const float* __restrict__ kv32, u16* __restrict__ khi, u16* __restrict__ klo){
  int i = blockIdx.x*256 + threadIdx.x;
  if (i >= 448*1152) return;
  int row = i / 1152, c = i - row*1152;
  float v = kv32[(size_t)row*2304 + c];
  u16 h16 = f2b(v);
  khi[i] = h16;
  klo[i] = f2b(v - b2f(h16));
}

// ------- high-precision GEMM on pre-split bf16 hi/lo planes -------
// out[M,N] = (Ah+Al)[M,K] @ (Wh+Wl)[N,K]^T + bias  (3-product MFMA, err ~2^-18)
// BK=64, XOR-swizzled LDS (phys chunk = logical ^ (row&7)) -> conflict-free ds_read_b128
// MODE 0: f32 out.  MODE 1: QKV epilogue (qk hi/lo planes + V transpose)
template<int MODE>
__global__ __launch_bounds__(256,2) void gemm_hp2(
    const u16* __restrict__ Ah, const u16* __restrict__ Al, int lda,
    const u16* __restrict__ Wh, const u16* __restrict__ Wl, int ldw,
    const float* __restrict__ bias, float* __restrict__ out, int ldo, int M, int K,
    u16* __restrict__ qkh, u16* __restrict__ qkl, u16* __restrict__ vth){
  __shared__ u16 sAh[128*64];
  __shared__ u16 sAl[128*64];
  __shared__ u16 sWh[128*64];
  __shared__ u16 sWl[128*64];
  const int tid = threadIdx.x, lane = tid & 63;
  const int wv = tid >> 6, wx = wv & 1, wy = wv >> 1;
  const int quad = lane >> 4, l16 = lane & 15;
  const int m0 = blockIdx.y*128, n0 = blockIdx.x*128;
  f32x4 acc[4][4];
  #pragma unroll
  for (int i=0;i<4;i++)
    #pragma unroll
    for (int j=0;j<4;j++) acc[i][j] = (f32x4){0.f,0.f,0.f,0.f};
  for (int k0=0; k0<K; k0+=64){
    #pragma unroll
    for (int r=0;r<4;r++){
      int slotbase = r*256 + wv*64;        // wave-uniform LDS base (slot*16B)
      int slot = slotbase + lane;
      int row = slot >> 3;
      int col8 = ((slot ^ row) & 7) * 8;   // XOR swizzle: fetch chunk cphys^(row&7)
      int gm = m0 + row; if (gm > M-1) gm = M-1;
      size_t aoff = (size_t)gm*lda + k0 + col8;
      size_t woff = (size_t)(n0+row)*ldw + k0 + col8;
      gl2lds16(Ah + aoff, &sAh[(size_t)slotbase*8]);
      gl2lds16(Al + aoff, &sAl[(size_t)slotbase*8]);
      gl2lds16(Wh + woff, &sWh[(size_t)slotbase*8]);
      gl2lds16(Wl + woff, &sWl[(size_t)slotbase*8]);
    }
    __syncthreads();
    #pragma unroll
    for (int kk=0; kk<2; kk++){
      const int cs = (((kk*4 + quad) ^ (l16 & 7)) * 8);
      bf16v8 ah[4], al[4], bh[4], bl[4];
      #pragma unroll
      for (int i=0;i<4;i++){
        ah[i] = ldv8(&sAh[(wy*64+i*16+l16)*64 + cs]);
        al[i] = ldv8(&sAl[(wy*64+i*16+l16)*64 + cs]);
      }
      #pragma unroll
      for (int j=0;j<4;j++){
        bh[j] = ldv8(&sWh[(wx*64+j*16+l16)*64 + cs]);
        bl[j] = ldv8(&sWl[(wx*64+j*16+l16)*64 + cs]);
      }
      #pragma unroll
      for (int i=0;i<4;i++)
        #pragma unroll
        for (int j=0;j<4;j++){
          acc[i][j] = MFMA_BF16(ah[i], bh[j], acc[i][j]);
          acc[i][j] = MFMA_BF16(ah[i], bl[j], acc[i][j]);
          acc[i][j] = MFMA_BF16(al[i], bh[j], acc[i][j]);
        }
    }
    __syncthreads();
  }
  #pragma unroll
  for (int j=0;j<4;j++){
    int col = n0 + wx*64 + j*16 + l16;
    float bc = bias ? bias[col] : 0.f;
    #pragma unroll
    for (int i=0;i<4;i++)
      #pragma unroll
      for (int r=0;r<4;r++){
        int row = m0 + wy*64 + i*16 + quad*4 + r;
        if (row >= M) continue;
        float v = acc[i][j][r] + bc;
        if (MODE == 0){
          out[(size_t)row*ldo + col] = v;
        } else {
          if (col < 2304){
            u16 hh = f2b(v);
            qkh[(size_t)row*2304 + col] = hh;
            qkl[(size_t)row*2304 + col] = f2b(v - b2f(hh));
          } else {
            int vc = col - 2304;
            int hd_ = vc/72, d = vc - hd_*72;
            int z = row >> 8, s2 = row & 255;
            vth[((size_t)(z*16+hd_)*80 + d)*256 + s2] = f2b(v);
          }
        }
      }
  }
}

// ---------------- int8 GEMM with W8A8 epilogue (XOR-swizzled LDS) ----------------
__global__ __launch_bounds__(256,2) void gemm_i8(
    const int8_t* __restrict__ A, int lda, const int8_t* __restrict__ W, int ldw,
    const float* __restrict__ rs, const int* __restrict__ rq,
    const float* __restrict__ sw, const int* __restrict__ zw, const float* __restrict__ bias,
    void* __restrict__ out, int ldo, int M, int K, int do_gelu, int out_f32){
  __shared__ int8_t As[128*128];
  __shared__ int8_t Bs[128*128];
  const int tid = threadIdx.x, lane = tid & 63, wv = tid >> 6;
  const int wx = wv & 1, wy = wv >> 1, quad = lane >> 4, l16 = lane & 15;
  const int m0 = blockIdx.y*128, n0 = blockIdx.x*128;
  const int srow = lane >> 3, schunk = lane & 7;
  const int scol = ((schunk ^ srow) & 7) * 16;   // XOR swizzle fetch column
  i32x4 zi4 = {0,0,0,0};
  i32x4 acc[4][4];
  #pragma unroll
  for (int i=0;i<4;i++){ acc[i][0]=zi4; acc[i][1]=zi4; acc[i][2]=zi4; acc[i][3]=zi4; }
  for (int k0 = 0; k0 < K; k0 += 128){
    #pragma unroll
    for (int i=0;i<4;i++){
      int rr = (i*4 + wv)*8;
      int gm = m0 + rr + srow; if (gm > M-1) gm = M-1;
      gl2lds16(A + (size_t)gm*lda + k0 + scol, &As[rr*128]);
      int gn = n0 + rr + srow;
      gl2lds16(W + (size_t)gn*ldw + k0 + scol, &Bs[rr*128]);
    }
    __syncthreads();
    #pragma unroll
    for (int kk=0; kk<2; kk++){
      const int cs = (((kk*4 + quad) ^ (l16 & 7)) * 16);
      i32x4 af[4], bw[4];
      #pragma unroll
      for (int i=0;i<4;i++) af[i] = *(const i32x4*)&As[(wy*64+i*16+l16)*128 + cs];
      #pragma unroll
      for (int j=0;j<4;j++) bw[j] = *(const i32x4*)&Bs[(wx*64+j*16+l16)*128 + cs];
      #pragma unroll
      for (int i=0;i<4;i++)
        #pragma unroll
        for (int j=0;j<4;j++)
          acc[i][j] = MFMA_I8(af[i], bw[j], acc[i][j]);
    }
    __syncthreads();
  }
  #pragma unroll
  for (int j=0;j<4;j++){
    int col = n0 + wx*64 + j*16 + l16;
    float swc = sw[col]; float zwc = (float)zw[col]; float bc = bias[col];
    #pragma unroll
    for (int i=0;i<4;i++)
      #pragma unroll
      for (int r=0;r<4;r++){
        int row = m0 + wy*64 + i*16 + quad*4 + r;
        if (row < M){
          float v = ((float)acc[i][j][r] - (float)rq[row]*zwc) * (rs[row]*swc) + bc;
          if (do_gelu) v = gelu_t(v);
          if (out_f32) ((float*)out)[(size_t)row*ldo + col] = v;
          else         ((u16*)out)[(size_t)row*ldo + col] = f2b(v);
        }
      }
  }
}

// ---------------- self-attention, high precision ----------------
__global__ __launch_bounds__(256) void attn_self_hp(
    const u16* __restrict__ qkh, const u16* __restrict__ qkl,
    const u16* __restrict__ vth, u16* __restrict__ ohi, u16* __restrict__ olo, float scale){
  constexpr int NT = 16, PSTR = 264, VSTR = 256;
  __shared__ u16 PH[4*16*PSTR];
  __shared__ u16 PL[4*16*PSTR];
  const int tid = threadIdx.x, lane = tid & 63, wv = tid >> 6;
  const int quad = lane >> 4, l16 = lane & 15;
  const int h = blockIdx.y, z = blockIdx.z;
  const int qbase = z*256 + blockIdx.x*64;
  const int qc = h*72, kc = 1152 + h*72;
  const u16* Vth = vth + (size_t)(z*16+h)*80*VSTR;
  const bf16v8 zf = __builtin_bit_cast(bf16v8, (u16v8)0);
  const int mrow = qbase + wv*16 + l16;

  bf16v8 qh[3], ql[3];
  #pragma unroll
  for (int t=0;t<3;t++){
    if (t==2 && quad!=0){ qh[t]=zf; ql[t]=zf; }
    else {
      size_t off = (size_t)mrow*2304 + qc + t*32 + (t==2?0:quad*8);
      qh[t] = ldv8(qkh + off); ql[t] = ldv8(qkl + off);
    }
  }
  f32x4 sc[NT];
  #pragma unroll
  for (int nt=0; nt<NT; nt++){
    f32x4 a = {0.f,0.f,0.f,0.f};
    #pragma unroll
    for (int t=0;t<3;t++){
      bf16v8 kh = zf, kl = zf;
      if (!(t==2 && quad!=0)){
        size_t koff = (size_t)(z*256 + nt*16 + l16)*2304 + kc + t*32 + (t==2?0:quad*8);
        kh = ldv8(qkh + koff); kl = ldv8(qkl + koff);
      }
      a = MFMA_BF16(qh[t], kh, a);
      a = MFMA_BF16(qh[t], kl, a);
      a = MFMA_BF16(ql[t], kh, a);
    }
    sc[nt] = a;
  }
  float mx[4] = {-1e30f,-1e30f,-1e30f,-1e30f};
  #pragma unroll
  for (int nt=0; nt<NT; nt++)
    #pragma unroll
    for (int r=0;r<4;r++){ float v = sc[nt][r]*scale; sc[nt][r]=v; mx[r]=fmaxf(mx[r],v); }
  #pragma unroll
  for (int r=0;r<4;r++)
    for (int d=1; d<16; d<<=1) mx[r] = fmaxf(mx[r], __shfl_xor(mx[r], d, 64));
  float sm[4] = {0.f,0.f,0.f,0.f};
  #pragma unroll
  for (int nt=0; nt<NT; nt++)
    #pragma unroll
    for (int r=0;r<4;r++){ float p = __expf(sc[nt][r]-mx[r]); sc[nt][r]=p; sm[r]+=p; }
  #pragma unroll
  for (int r=0;r<4;r++){
    for (int d=1; d<16; d<<=1) sm[r] += __shfl_xor(sm[r], d, 64);
    sm[r] = 1.f/sm[r];
  }
  u16* Pwh = PH + wv*16*PSTR;
  u16* Pwl = PL + wv*16*PSTR;
  #pragma unroll
  for (int nt=0; nt<NT; nt++)
    #pragma unroll
    for (int r=0;r<4;r++){
      float p = sc[nt][r]*sm[r];
      u16 hi = f2b(p);
      Pwh[(quad*4+r)*PSTR + nt*16 + l16] = hi;
      Pwl[(quad*4+r)*PSTR + nt*16 + l16] = f2b(p - b2f(hi));
    }
  const u16* Prh = PH + wv*16*PSTR + (size_t)l16*PSTR;
  const u16* Prl = PL + wv*16*PSTR + (size_t)l16*PSTR;
  #pragma unroll
  for (int dt=0; dt<5; dt++){
    f32x4 o = {0.f,0.f,0.f,0.f};
    #pragma unroll
    for (int kk=0; kk<8; kk++){
      bf16v8 ph = ldv8(Prh + kk*32 + quad*8);
      bf16v8 pl = ldv8(Prl + kk*32 + quad*8);
      bf16v8 bv = ldv8(Vth + (size_t)(dt*16+l16)*VSTR + kk*32 + quad*8);
      o = MFMA_BF16(ph, bv, o);
      o = MFMA_BF16(pl, bv, o);
    }
    int d = dt*16 + l16;
    if (d < 72){
      #pragma unroll
      for (int r=0;r<4;r++){
        int row = qbase + wv*16 + quad*4 + r;
        size_t oi = (size_t)row*1152 + h*72 + d;
        u16 hh = f2b(o[r]);
        ohi[oi] = hh; olo[oi] = f2b(o[r] - b2f(hh));
      }
    }
  }
}

// ---------------- cross-attention, high-precision QK ----------------
__global__ __launch_bounds__(256) void attn_cross_hp(
    const float* __restrict__ Q32,
    const u16* __restrict__ Khi, const u16* __restrict__ Klo,
    const u16* __restrict__ Vt,                  // [h][80][448]
    float* __restrict__ O, float scale){
  constexpr int NT = 28, PSTR = 456, VSTR = 448;
  __shared__ u16 P[4*16*PSTR];
  const int tid = threadIdx.x, lane = tid & 63, wv = tid >> 6;
  const int quad = lane >> 4, l16 = lane & 15;
  const int h = blockIdx.y;
  const int qbase = blockIdx.x*64;
  const u16* Vth = Vt + (size_t)h*80*VSTR;
  const bf16v8 zf = __builtin_bit_cast(bf16v8, (u16v8)0);

  const int mrow = qbase + wv*16 + l16;
  const float* qp = Q32 + (size_t)mrow*1152 + h*72;
  bf16v8 qhi[3], qlo[3];
  #pragma unroll
  for (int t=0;t<3;t++){
    if (t==2 && quad!=0){ qhi[t]=zf; qlo[t]=zf; continue; }
    u16v8 hv, lv;
    #pragma unroll
    for (int j=0;j<8;j++){
      float v = qp[t*32 + (t==2?0:quad*8) + j];
      u16 h16 = f2b(v);
      hv[j] = h16; lv[j] = f2b(v - b2f(h16));
    }
    qhi[t] = __builtin_bit_cast(bf16v8, hv);
    qlo[t] = __builtin_bit_cast(bf16v8, lv);
  }
  f32x4 sc[NT];
  #pragma unroll
  for (int nt=0; nt<NT; nt++){
    f32x4 a = {0.f,0.f,0.f,0.f};
    #pragma unroll
    for (int t=0;t<3;t++){
      bf16v8 kh = zf, kl = zf;
      if (!(t==2 && quad!=0)){
        size_t koff = (size_t)(nt*16 + l16)*1152 + h*72 + t*32 + (t==2?0:quad*8);
        kh = ldv8(Khi + koff); kl = ldv8(Klo + koff);
      }
      a = MFMA_BF16(qhi[t], kh, a);
      a = MFMA_BF16(qhi[t], kl, a);
      a = MFMA_BF16(qlo[t], kh, a);
    }
    sc[nt] = a;
  }
  float mx[4] = {-1e30f,-1e30f,-1e30f,-1e30f};
  #pragma unroll
  for (int nt=0; nt<NT; nt++)
    #pragma unroll
    for (int r=0;r<4;r++){ float v = sc[nt][r]*scale; sc[nt][r]=v; mx[r]=fmaxf(mx[r],v); }
  #pragma unroll
  for (int r=0;r<4;r++)
    for (int d=1; d<16; d<<=1) mx[r] = fmaxf(mx[r], __shfl_xor(mx[r], d, 64));
  float sm[4] = {0.f,0.f,0.f,0.f};
  #pragma unroll
  for (int nt=0; nt<NT; nt++)
    #pragma unroll
    for (int r=0;r<4;r++){ float p = __expf(sc[nt][r]-mx[r]); sc[nt][r]=p; sm[r]+=p; }
  #pragma unroll
  for (int r=0;r<4;r++){
    for (int d=1; d<16; d<<=1) sm[r] += __shfl_xor(sm[r], d, 64);
    sm[r] = 1.f/sm[r];
  }
  u16* Pw = P + wv*16*PSTR;
  #pragma unroll
  for (int nt=0; nt<NT; nt++)
    #pragma unroll
    for (int r=0;r<4;r++)
      Pw[(quad*4+r)*PSTR + nt*16 + l16] = f2b(sc[nt][r]*sm[r]);
  const u16* Pr = P + wv*16*PSTR + (size_t)l16*PSTR;
  #pragma unroll
  for (int dt=0; dt<5; dt++){
    f32x4 o = {0.f,0.f,0.f,0.f};
    #pragma unroll
    for (int kk=0; kk<14; kk++){
      bf16v8 ap = ldv8(Pr + kk*32 + quad*8);
      bf16v8 bv = ldv8(Vth + (size_t)(dt*16+l16)*VSTR + kk*32 + quad*8);
      o = MFMA_BF16(ap, bv, o);
    }
    int d = dt*16 + l16;
    if (d < 72){
      #pragma unroll
      for (int r=0;r<4;r++){
        int row = qbase + wv*16 + quad*4 + r;
        O[(size_t)row*1152 + h*72 + d] = o[r];
      }
    }
  }
}

// ---------------- launch ----------------
extern "C" void kernel_launch(void* const* d_in, const int* in_sizes, int n_in,
                              void* d_out, int out_size, void* d_ws, size_t ws_size,
                              hipStream_t stream){
  const float* x    = (const float*)d_in[0];
  const float* y    = (const float*)d_in[1];
  const float* t    = (const float*)d_in[2];
  const float* sst  = (const float*)d_in[3];
  const float* Wqkv = (const float*)d_in[4];
  const float* bqkv = (const float*)d_in[5];
  const float* Wo   = (const float*)d_in[6];
  const float* bo   = (const float*)d_in[7];
  const float* Wkv  = (const float*)d_in[8];
  const float* bkv  = (const float*)d_in[9];
  const int*   qw_q  = (const int*)d_in[10];
  const float* sw_q  = (const float*)d_in[11];
  const int*   zw_q  = (const int*)d_in[12];
  const float* b_q   = (const float*)d_in[13];
  const int*   qw_cp = (const int*)d_in[14];
  const float* sw_cp = (const float*)d_in[15];
  const int*   zw_cp = (const int*)d_in[16];
  const float* b_cp  = (const float*)d_in[17];
  const int*   qw_f1 = (const int*)d_in[18];
  const float* sw_f1 = (const float*)d_in[19];
  const int*   zw_f1 = (const int*)d_in[20];
  const float* b_f1  = (const float*)d_in[21];
  const int*   qw_f2 = (const int*)d_in[22];
  const float* sw_f2 = (const float*)d_in[23];
  const int*   zw_f2 = (const int*)d_in[24];
  const float* b_f2  = (const float*)d_in[25];
  (void)in_sizes; (void)n_in; (void)out_size;

  // ---- workspace: 6 big regions, phase-disjoint aliasing (journal r5) ----
  constexpr size_t SZR = (size_t)4096*1152*4;        // 18,874,368
  constexpr size_t R0 = 0;                           // xw f32
  constexpr size_t R1 = R0 + SZR;                    // wqkv splits -> wkv/y splits -> q32/cp-out f32 -> q8h
  constexpr size_t R2 = R1 + SZR;                    // qkh -> wo-out/ao f32 -> hbuf(lo half) -> f2out f32
  constexpr size_t R3 = R2 + SZR;                    // qkl -> hbuf(hi half)
  constexpr size_t R4 = R3 + SZR;                    // xmh/ohi -> kv32+khi+klo+vtc -> w8f2   (9,437,184)
  constexpr size_t R5 = R4 + (size_t)9437184;        // xml/olo -> w8q,w8cp,w8f1              (9,437,184)
  constexpr size_t R6 = R5 + (size_t)9437184;        // vth -> woh/wol -> q8x                 (10,485,760)
  constexpr size_t RS = R6 + (size_t)10485760;
  constexpr size_t RQ = RS + (size_t)4096*4;
  constexpr size_t RM = RQ + (size_t)4096*4;
  constexpr size_t WS_NEED = RM + (size_t)2*6*1152*4;  // ~100.1 MB (proven ws >= 130 MB)
  if (ws_size < WS_NEED) return;

  char* ws = (char*)d_ws;
  float*  xw    = (float*)(ws + R0);
  u16*    wqkvh = (u16*)(ws + R1);
  u16*    wqkvl = (u16*)(ws + R1 + (size_t)3456*1152*2);
  u16*    wkvh  = (u16*)(ws + R1);
  u16*    wkvl  = (u16*)(ws + R1 + (size_t)2304*1152*2);
  u16*    yh    = (u16*)(ws + R1 + (size_t)2*2304*1152*2);
  u16*    yl    = (u16*)(ws + R1 + (size_t)2*2304*1152*2 + (size_t)448*1152*2);
  float*  q32   = (float*)(ws + R1);
  float*  cpout = (float*)(ws + R1);
  int8_t* q8h   = (int8_t*)(ws + R1);
  u16*    qkh   = (u16*)(ws + R2);
  float*  aof   = (float*)(ws + R2);   // wo-out, later cross-attn out
  u16*    hbuf  = (u16*)(ws + R2);     // 4096x4608 bf16 spans R2+R3
  float*  f2out = (float*)(ws + R2);
  u16*    qkl   = (u16*)(ws + R3);
  u16*    xmh   = (u16*)(ws + R4);
  u16*    ohi   = (u16*)(ws + R4);
  float*  kv32  = (float*)(ws + R4);
  u16*    khi   = (u16*)(ws + R4 + (size_t)4128768);
  u16*    klo   = (u16*)(ws + R4 + (size_t)5160960);
  u16*    vtc   = (u16*)(ws + R4 + (size_t)6193152);
  int8_t* w8f2  = (int8_t*)(ws + R4);
  u16*    xml   = (u16*)(ws + R5);
  u16*    olo   = (u16*)(ws + R5);
  int8_t* w8q   = (int8_t*)(ws + R5);
  int8_t* w8cp  = (int8_t*)(ws + R5 + (size_t)1327104);
  int8_t* w8f1  = (int8_t*)(ws + R5 + (size_t)2654208);
  u16*    vth   = (u16*)(ws + R6);
  u16*    woh   = (u16*)(ws + R6);
  u16*    wol   = (u16*)(ws + R6 + (size_t)1152*1152*2);
  int8_t* q8x   = (int8_t*)(ws + R6);
  float*  rs    = (float*)(ws + RS);
  int*    rq    = (int*)(ws + RQ);
  float*  mod   = (float*)(ws + RM);

  const float scale = 0.11785113019775793f; // 72^-0.5
  const int ETOT = 4096*1152, EB = (ETOT+255)/256;

  mod_add_k<<<(2*6*1152+255)/256,256,0,stream>>>(sst, t, mod);

  // ---- MSA branch (hp GEMMs on pre-split planes) ----
  ln_mod_split_k<<<4096,256,0,stream>>>(x, xmh, xml, mod, 0, 1);
  split2_k<<<(3456*1152+255)/256,256,0,stream>>>(Wqkv, wqkvh, wqkvl, 3456*1152);
  gemm_hp2<1><<<dim3(27,32),256,0,stream>>>(xmh,xml,1152, wqkvh,wqkvl,1152, bqkv, nullptr,0, 4096,1152, qkh,qkl,vth);
  attn_self_hp<<<dim3(4,16,16),256,0,stream>>>(qkh, qkl, vth, ohi, olo, scale);
  split2_k<<<(1152*1152+255)/256,256,0,stream>>>(Wo, woh, wol, 1152*1152);
  gemm_hp2<0><<<dim3(9,32),256,0,stream>>>(ohi,olo,1152, woh,wol,1152, bo, aof,1152, 4096,1152, nullptr,nullptr,nullptr);
  rgq_k<<<4096,256,0,stream>>>(x, aof, mod, 2, xw, q8x, rs, rq);

  // ---- cross-attn branch ----
  conv_i8_k<<<(1152*1152+255)/256,256,0,stream>>>(qw_q,  w8q,  1152*1152);
  conv_i8_k<<<(1152*1152+255)/256,256,0,stream>>>(qw_cp, w8cp, 1152*1152);
  split2_k<<<(2304*1152+255)/256,256,0,stream>>>(Wkv, wkvh, wkvl, 2304*1152);
  split2_k<<<(448*1152+255)/256,256,0,stream>>>(y, yh, yl, 448*1152);
  gemm_hp2<0><<<dim3(18,4),256,0,stream>>>(yh,yl,1152, wkvh,wkvl,1152, bkv, kv32,2304, 448,1152, nullptr,nullptr,nullptr);
  build_kv_split_k<<<(448*1152+255)/256,256,0,stream>>>(kv32, khi, klo);
  build_vt_cross_k<<<16,256,0,stream>>>(kv32, vtc);
  gemm_i8<<<dim3(9,32),256,0,stream>>>(q8x,1152, w8q,1152, rs,rq, sw_q,zw_q,b_q, q32,1152, 4096,1152, 0, 1);
  attn_cross_hp<<<dim3(64,16),256,0,stream>>>(q32, khi, klo, vtc, aof, scale);
  quant_rows_k<1><<<4096,256,0,stream>>>(aof, 1152, q8x, rs, rq);
  gemm_i8<<<dim3(9,32),256,0,stream>>>(q8x,1152, w8cp,1152, rs,rq, sw_cp,zw_cp,b_cp, cpout,1152, 4096,1152, 0, 1);

  // ---- MLP branch ----
  rlq_k<<<4096,256,0,stream>>>(xw, cpout, mod, 3, 4, q8x, rs, rq);
  conv_i8_k<<<(4608*1152+255)/256,256,0,stream>>>(qw_f1, w8f1, 4608*1152);
  gemm_i8<<<dim3(36,32),256,0,stream>>>(q8x,1152, w8f1,1152, rs,rq, sw_f1,zw_f1,b_f1, hbuf,4608, 4096,1152, 1, 0);
  quant_rows_k<0><<<4096,256,0,stream>>>(hbuf, 4608, q8h, rs, rq);
  conv_i8_k<<<(1152*4608+255)/256,256,0,stream>>>(qw_f2, w8f2, 1152*4608);
  gemm_i8<<<dim3(9,32),256,0,stream>>>(q8h,4608, w8f2,4608, rs,rq, sw_f2,zw_f2,b_f2, f2out,1152, 4096,4608, 0, 1);
  final_out_f32_k<<<EB,256,0,stream>>>(xw, f2out, mod, (float*)d_out);
}

// Round 7
// 955.228 us; speedup vs baseline: 1.0879x; 1.0879x over previous
//
#include <hip/hip_runtime.h>
#include <stdint.h>

typedef unsigned short u16;
typedef __bf16 bf16v8 __attribute__((ext_vector_type(8)));
typedef u16    u16v8  __attribute__((ext_vector_type(8)));
typedef float  f32x4  __attribute__((ext_vector_type(4)));
typedef int    i32x4  __attribute__((ext_vector_type(4)));

#define MFMA_BF16(a,b,c) __builtin_amdgcn_mfma_f32_16x16x32_bf16((a),(b),(c),0,0,0)
#define MFMA_I8(a,b,c)   __builtin_amdgcn_mfma_i32_16x16x64_i8((a),(b),(c),0,0,0)

__device__ __forceinline__ float b2f(u16 u){ union{unsigned u;float f;}v; v.u=((unsigned)u)<<16; return v.f; }
__device__ __forceinline__ u16 f2b(float f){ union{float f;unsigned u;}v; v.f=f;
  return (u16)((v.u + 0x7fffu + ((v.u>>16)&1u))>>16); }
__device__ __forceinline__ bf16v8 ldv8(const u16* p){ return __builtin_bit_cast(bf16v8, *(const u16v8*)p); }
__device__ __forceinline__ void gl2lds16(const void* g, void* l){
  __builtin_amdgcn_global_load_lds(
    (const __attribute__((address_space(1))) unsigned int*)g,
    (__attribute__((address_space(3))) unsigned int*)l,
    16, 0, 0);
}
__device__ __forceinline__ float gelu_t(float x){
  float t = tanhf(0.7978845608028654f*(x + 0.044715f*x*x*x));
  return 0.5f*x*(1.0f+t);
}

// ---------------- elementwise / prep ----------------
__global__ void mod_add_k(const float* __restrict__ sst, const float* __restrict__ t, float* __restrict__ mod){
  int i = blockIdx.x*256 + threadIdx.x;
  if (i < 2*6*1152) mod[i] = sst[i % 6912] + t[i];
}
__global__ void conv_i8_k(const int* __restrict__ src, int8_t* __restrict__ dst, int n){
  int i = blockIdx.x*256 + threadIdx.x;
  if (i < n) dst[i] = (int8_t)src[i];
}
// f32 -> bf16 hi/lo planes
__global__ void split2_k(const float* __restrict__ src, u16* __restrict__ hi, u16* __restrict__ lo, int n){
  int i = blockIdx.x*256 + threadIdx.x;
  if (i >= n) return;
  float v = src[i];
  u16 hh = f2b(v);
  hi[i] = hh; lo[i] = f2b(v - b2f(hh));
}
// LN over C=1152 with modulation -> hi/lo bf16 planes
__global__ void ln_mod_split_k(const float* __restrict__ src, u16* __restrict__ xh, u16* __restrict__ xl,
                               const float* __restrict__ mod, int shift_row, int scale_row){
  const int row = blockIdx.x, tid = threadIdx.x;
  const int b = row >> 11;
  const float* ms = mod + ((size_t)b*6 + shift_row)*1152;
  const float* mc = mod + ((size_t)b*6 + scale_row)*1152;
  __shared__ float r1[256], r2[256];
  float s = 0.f, sq = 0.f, vals[5]; int cnt = 0;
  for (int c = tid; c < 1152; c += 256){
    float v = src[(size_t)row*1152+c];
    vals[cnt++] = v; s += v; sq += v*v;
  }
  r1[tid]=s; r2[tid]=sq; __syncthreads();
  for (int st=128; st>0; st>>=1){ if (tid<st){ r1[tid]+=r1[tid+st]; r2[tid]+=r2[tid+st]; } __syncthreads(); }
  float mean = r1[0]*(1.f/1152.f);
  float var  = r2[0]*(1.f/1152.f) - mean*mean;
  float rstd = rsqrtf(var + 1e-6f);
  cnt = 0;
  for (int c = tid; c < 1152; c += 256){
    float v = (vals[cnt++]-mean)*rstd*(1.f+mc[c]) + ms[c];
    u16 hh = f2b(v);
    xh[(size_t)row*1152+c] = hh;
    xl[(size_t)row*1152+c] = f2b(v - b2f(hh));
  }
}
// fused: xw = x + gate*ao, then per-row int8 quant of xw
__global__ void rgq_k(const float* __restrict__ x, const float* __restrict__ ao,
                      const float* __restrict__ mod, int gate_row, float* __restrict__ xw,
                      int8_t* __restrict__ q8, float* __restrict__ s_out, int* __restrict__ q_out){
  const int row = blockIdx.x, tid = threadIdx.x;
  const int b = row >> 11;
  const float* mg = mod + ((size_t)b*6 + gate_row)*1152;
  __shared__ float r1[256];
  __shared__ int ri[256];
  float mx = 0.f, vals[5]; int cnt = 0;
  for (int c = tid; c < 1152; c += 256){
    float v = x[(size_t)row*1152+c] + mg[c]*ao[(size_t)row*1152+c];
    xw[(size_t)row*1152+c] = v;
    vals[cnt++] = v; mx = fmaxf(mx, fabsf(v));
  }
  r1[tid]=mx; __syncthreads();
  for (int st=128; st>0; st>>=1){ if (tid<st) r1[tid]=fmaxf(r1[tid],r1[tid+st]); __syncthreads(); }
  const float s_ = fmaxf(r1[0]*(1.f/127.f), 1e-8f);
  const float inv = 1.f/s_;
  int acc = 0; cnt = 0;
  for (int c = tid; c < 1152; c += 256){
    float q = rintf(vals[cnt++]*inv);
    q = fminf(fmaxf(q, -127.f), 127.f);
    q8[(size_t)row*1152+c] = (int8_t)q;
    acc += (int)q;
  }
  ri[tid]=acc; __syncthreads();
  for (int st=128; st>0; st>>=1){ if (tid<st) ri[tid]+=ri[tid+st]; __syncthreads(); }
  if (tid==0){ s_out[row]=s_; q_out[row]=ri[0]; }
}
// fused: xw += add; LN+mod; per-row int8 quant
__global__ void rlq_k(float* __restrict__ xw, const float* __restrict__ add,
                      const float* __restrict__ mod, int shift_row, int scale_row,
                      int8_t* __restrict__ q8, float* __restrict__ s_out, int* __restrict__ q_out){
  const int row = blockIdx.x, tid = threadIdx.x;
  const int b = row >> 11;
  const float* ms = mod + ((size_t)b*6 + shift_row)*1152;
  const float* mc = mod + ((size_t)b*6 + scale_row)*1152;
  __shared__ float r1[256], r2[256];
  __shared__ int ri[256];
  float s = 0.f, sq = 0.f, vals[5]; int cnt = 0;
  for (int c = tid; c < 1152; c += 256){
    float v = xw[(size_t)row*1152+c] + add[(size_t)row*1152+c];
    xw[(size_t)row*1152+c] = v;
    vals[cnt++] = v; s += v; sq += v*v;
  }
  r1[tid]=s; r2[tid]=sq; __syncthreads();
  for (int st=128; st>0; st>>=1){ if (tid<st){ r1[tid]+=r1[tid+st]; r2[tid]+=r2[tid+st]; } __syncthreads(); }
  float mean = r1[0]*(1.f/1152.f);
  float var  = r2[0]*(1.f/1152.f) - mean*mean;
  float rstd = rsqrtf(var + 1e-6f);
  __syncthreads();
  float mx = 0.f; cnt = 0;
  for (int c = tid; c < 1152; c += 256){
    float v = (vals[cnt]-mean)*rstd*(1.f+mc[c]) + ms[c];
    vals[cnt++] = v; mx = fmaxf(mx, fabsf(v));
  }
  r1[tid]=mx; __syncthreads();
  for (int st=128; st>0; st>>=1){ if (tid<st) r1[tid]=fmaxf(r1[tid],r1[tid+st]); __syncthreads(); }
  const float s_ = fmaxf(r1[0]*(1.f/127.f), 1e-8f);
  const float inv = 1.f/s_;
  int acc = 0; cnt = 0;
  for (int c = tid; c < 1152; c += 256){
    float q = rintf(vals[cnt++]*inv);
    q = fminf(fmaxf(q, -127.f), 127.f);
    q8[(size_t)row*1152+c] = (int8_t)q;
    acc += (int)q;
  }
  ri[tid]=acc; __syncthreads();
  for (int st=128; st>0; st>>=1){ if (tid<st) ri[tid]+=ri[tid+st]; __syncthreads(); }
  if (tid==0){ s_out[row]=s_; q_out[row]=ri[0]; }
}
// register-cached row quant (C_ <= 4608)
template<int SRC_F32>
__global__ void quant_rows_k(const void* __restrict__ src, int C_,
                             int8_t* __restrict__ q8, float* __restrict__ s_out, int* __restrict__ q_out){
  const int row = blockIdx.x, tid = threadIdx.x;
  __shared__ float red[256];
  __shared__ int redi[256];
  float vals[18];
  float mx = 0.f; int cnt = 0;
  for (int c = tid; c < C_; c += 256){
    float v = SRC_F32 ? ((const float*)src)[(size_t)row*C_+c] : b2f(((const u16*)src)[(size_t)row*C_+c]);
    vals[cnt++] = v;
    mx = fmaxf(mx, fabsf(v));
  }
  red[tid]=mx; __syncthreads();
  for (int st=128; st>0; st>>=1){ if (tid<st) red[tid]=fmaxf(red[tid],red[tid+st]); __syncthreads(); }
  const float s_ = fmaxf(red[0]*(1.f/127.f), 1e-8f);
  const float inv = 1.f/s_;
  int acc = 0; cnt = 0;
  for (int c = tid; c < C_; c += 256){
    float q = rintf(vals[cnt++]*inv);
    q = fminf(fmaxf(q, -127.f), 127.f);
    q8[(size_t)row*C_+c] = (int8_t)q;
    acc += (int)q;
  }
  redi[tid]=acc; __syncthreads();
  for (int st=128; st>0; st>>=1){ if (tid<st) redi[tid]+=redi[tid+st]; __syncthreads(); }
  if (tid==0){ s_out[row]=s_; q_out[row]=redi[0]; }
}
__global__ void final_out_f32_k(const float* __restrict__ xw, const float* __restrict__ h,
                                const float* __restrict__ mod, float* __restrict__ out){
  size_t i = (size_t)blockIdx.x*256 + threadIdx.x;
  if (i >= (size_t)4096*1152) return;
  int c = (int)(i % 1152); int b = (int)((i/1152) >> 11);
  out[i] = xw[i] + mod[((size_t)b*6+5)*1152 + c] * h[i];
}
__global__ void build_vt_cross_k(const float* __restrict__ kv32, u16* __restrict__ vt){
  int h = blockIdx.x;
  u16* dst = vt + (size_t)h*80*448;
  const float* srcb = kv32 + 1152 + h*72;
  for (int idx = threadIdx.x; idx < 72*448; idx += 256){
    int d = idx/448, ss = idx - d*448;
    dst[d*448 + ss] = f2b(srcb[(size_t)ss*2304 + d]);
  }
}
__global__ void build_kv_split_k(const float* __restrict__ kv32, u16* __restrict__ khi, u16* __restrict__ klo){
  int i = blockIdx.x*256 + threadIdx.x;
  if (i >= 448*1152) return;
  int row = i / 1152, c = i - row*1152;
  float v = kv32[(size_t)row*2304 + c];
  u16 h16 = f2b(v);
  khi[i] = h16;
  klo[i] = f2b(v - b2f(h16));
}

// ------- high-precision GEMM on pre-split bf16 hi/lo planes -------
// out[M,N] = (Ah+Al)[M,K] @ (Wh+Wl)[N,K]^T + bias  (3-product MFMA, err ~2^-18)
// BK=32, XOR-swizzled LDS (phys chunk = logical ^ (row&3)) -> conflict-free ds_read_b128
// 32KB LDS + launch_bounds(256,3) -> 3 blocks/CU (occupancy was the R6 limiter)
// MODE 0: f32 out.  MODE 1: QKV epilogue (qk hi/lo planes + V transpose)
template<int MODE>
__global__ __launch_bounds__(256,3) void gemm_hp2(
    const u16* __restrict__ Ah, const u16* __restrict__ Al, int lda,
    const u16* __restrict__ Wh, const u16* __restrict__ Wl, int ldw,
    const float* __restrict__ bias, float* __restrict__ out, int ldo, int M, int K,
    u16* __restrict__ qkh, u16* __restrict__ qkl, u16* __restrict__ vth){
  __shared__ u16 sAh[128*32];
  __shared__ u16 sAl[128*32];
  __shared__ u16 sWh[128*32];
  __shared__ u16 sWl[128*32];
  const int tid = threadIdx.x, lane = tid & 63;
  const int wv = tid >> 6, wx = wv & 1, wy = wv >> 1;
  const int quad = lane >> 4, l16 = lane & 15;
  const int m0 = blockIdx.y*128, n0 = blockIdx.x*128;
  f32x4 acc[4][4];
  #pragma unroll
  for (int i=0;i<4;i++)
    #pragma unroll
    for (int j=0;j<4;j++) acc[i][j] = (f32x4){0.f,0.f,0.f,0.f};
  for (int k0=0; k0<K; k0+=32){
    #pragma unroll
    for (int r=0;r<2;r++){
      int slotbase = r*256 + wv*64;        // wave-uniform LDS base (slot*16B)
      int slot = slotbase + lane;
      int row = slot >> 2;                 // 4 chunks of 16B per 32-u16 row
      int col8 = ((slot ^ row) & 3) * 8;   // XOR swizzle: fetch chunk phys^(row&3)
      int gm = m0 + row; if (gm > M-1) gm = M-1;
      size_t aoff = (size_t)gm*lda + k0 + col8;
      size_t woff = (size_t)(n0+row)*ldw + k0 + col8;
      gl2lds16(Ah + aoff, &sAh[(size_t)slotbase*8]);
      gl2lds16(Al + aoff, &sAl[(size_t)slotbase*8]);
      gl2lds16(Wh + woff, &sWh[(size_t)slotbase*8]);
      gl2lds16(Wl + woff, &sWl[(size_t)slotbase*8]);
    }
    __syncthreads();
    const int cs = ((quad ^ (l16 & 3)) * 8);
    bf16v8 ah[4], al[4], bh[4], bl[4];
    #pragma unroll
    for (int i=0;i<4;i++){
      ah[i] = ldv8(&sAh[(wy*64+i*16+l16)*32 + cs]);
      al[i] = ldv8(&sAl[(wy*64+i*16+l16)*32 + cs]);
    }
    #pragma unroll
    for (int j=0;j<4;j++){
      bh[j] = ldv8(&sWh[(wx*64+j*16+l16)*32 + cs]);
      bl[j] = ldv8(&sWl[(wx*64+j*16+l16)*32 + cs]);
    }
    #pragma unroll
    for (int i=0;i<4;i++)
      #pragma unroll
      for (int j=0;j<4;j++){
        acc[i][j] = MFMA_BF16(ah[i], bh[j], acc[i][j]);
        acc[i][j] = MFMA_BF16(ah[i], bl[j], acc[i][j]);
        acc[i][j] = MFMA_BF16(al[i], bh[j], acc[i][j]);
      }
    __syncthreads();
  }
  #pragma unroll
  for (int j=0;j<4;j++){
    int col = n0 + wx*64 + j*16 + l16;
    float bc = bias ? bias[col] : 0.f;
    #pragma unroll
    for (int i=0;i<4;i++)
      #pragma unroll
      for (int r=0;r<4;r++){
        int row = m0 + wy*64 + i*16 + quad*4 + r;
        if (row >= M) continue;
        float v = acc[i][j][r] + bc;
        if (MODE == 0){
          out[(size_t)row*ldo + col] = v;
        } else {
          if (col < 2304){
            u16 hh = f2b(v);
            qkh[(size_t)row*2304 + col] = hh;
            qkl[(size_t)row*2304 + col] = f2b(v - b2f(hh));
          } else {
            int vc = col - 2304;
            int hd_ = vc/72, d = vc - hd_*72;
            int z = row >> 8, s2 = row & 255;
            vth[((size_t)(z*16+hd_)*80 + d)*256 + s2] = f2b(v);
          }
        }
      }
  }
}

// ---------------- int8 GEMM with W8A8 epilogue (XOR-swizzled LDS) ----------------
__global__ __launch_bounds__(256,2) void gemm_i8(
    const int8_t* __restrict__ A, int lda, const int8_t* __restrict__ W, int ldw,
    const float* __restrict__ rs, const int* __restrict__ rq,
    const float* __restrict__ sw, const int* __restrict__ zw, const float* __restrict__ bias,
    void* __restrict__ out, int ldo, int M, int K, int do_gelu, int out_f32){
  __shared__ int8_t As[128*128];
  __shared__ int8_t Bs[128*128];
  const int tid = threadIdx.x, lane = tid & 63, wv = tid >> 6;
  const int wx = wv & 1, wy = wv >> 1, quad = lane >> 4, l16 = lane & 15;
  const int m0 = blockIdx.y*128, n0 = blockIdx.x*128;
  const int srow = lane >> 3, schunk = lane & 7;
  const int scol = ((schunk ^ srow) & 7) * 16;   // XOR swizzle fetch column
  i32x4 zi4 = {0,0,0,0};
  i32x4 acc[4][4];
  #pragma unroll
  for (int i=0;i<4;i++){ acc[i][0]=zi4; acc[i][1]=zi4; acc[i][2]=zi4; acc[i][3]=zi4; }
  for (int k0 = 0; k0 < K; k0 += 128){
    #pragma unroll
    for (int i=0;i<4;i++){
      int rr = (i*4 + wv)*8;
      int gm = m0 + rr + srow; if (gm > M-1) gm = M-1;
      gl2lds16(A + (size_t)gm*lda + k0 + scol, &As[rr*128]);
      int gn = n0 + rr + srow;
      gl2lds16(W + (size_t)gn*ldw + k0 + scol, &Bs[rr*128]);
    }
    __syncthreads();
    #pragma unroll
    for (int kk=0; kk<2; kk++){
      const int cs = (((kk*4 + quad) ^ (l16 & 7)) * 16);
      i32x4 af[4], bw[4];
      #pragma unroll
      for (int i=0;i<4;i++) af[i] = *(const i32x4*)&As[(wy*64+i*16+l16)*128 + cs];
      #pragma unroll
      for (int j=0;j<4;j++) bw[j] = *(const i32x4*)&Bs[(wx*64+j*16+l16)*128 + cs];
      #pragma unroll
      for (int i=0;i<4;i++)
        #pragma unroll
        for (int j=0;j<4;j++)
          acc[i][j] = MFMA_I8(af[i], bw[j], acc[i][j]);
    }
    __syncthreads();
  }
  #pragma unroll
  for (int j=0;j<4;j++){
    int col = n0 + wx*64 + j*16 + l16;
    float swc = sw[col]; float zwc = (float)zw[col]; float bc = bias[col];
    #pragma unroll
    for (int i=0;i<4;i++)
      #pragma unroll
      for (int r=0;r<4;r++){
        int row = m0 + wy*64 + i*16 + quad*4 + r;
        if (row < M){
          float v = ((float)acc[i][j][r] - (float)rq[row]*zwc) * (rs[row]*swc) + bc;
          if (do_gelu) v = gelu_t(v);
          if (out_f32) ((float*)out)[(size_t)row*ldo + col] = v;
          else         ((u16*)out)[(size_t)row*ldo + col] = f2b(v);
        }
      }
  }
}

// ---------------- self-attention, high precision ----------------
__global__ __launch_bounds__(256) void attn_self_hp(
    const u16* __restrict__ qkh, const u16* __restrict__ qkl,
    const u16* __restrict__ vth, u16* __restrict__ ohi, u16* __restrict__ olo, float scale){
  constexpr int NT = 16, PSTR = 264, VSTR = 256;
  __shared__ u16 PH[4*16*PSTR];
  __shared__ u16 PL[4*16*PSTR];
  const int tid = threadIdx.x, lane = tid & 63, wv = tid >> 6;
  const int quad = lane >> 4, l16 = lane & 15;
  const int h = blockIdx.y, z = blockIdx.z;
  const int qbase = z*256 + blockIdx.x*64;
  const int qc = h*72, kc = 1152 + h*72;
  const u16* Vth = vth + (size_t)(z*16+h)*80*VSTR;
  const bf16v8 zf = __builtin_bit_cast(bf16v8, (u16v8)0);
  const int mrow = qbase + wv*16 + l16;

  bf16v8 qh[3], ql[3];
  #pragma unroll
  for (int t=0;t<3;t++){
    if (t==2 && quad!=0){ qh[t]=zf; ql[t]=zf; }
    else {
      size_t off = (size_t)mrow*2304 + qc + t*32 + (t==2?0:quad*8);
      qh[t] = ldv8(qkh + off); ql[t] = ldv8(qkl + off);
    }
  }
  f32x4 sc[NT];
  #pragma unroll
  for (int nt=0; nt<NT; nt++){
    f32x4 a = {0.f,0.f,0.f,0.f};
    #pragma unroll
    for (int t=0;t<3;t++){
      bf16v8 kh = zf, kl = zf;
      if (!(t==2 && quad!=0)){
        size_t koff = (size_t)(z*256 + nt*16 + l16)*2304 + kc + t*32 + (t==2?0:quad*8);
        kh = ldv8(qkh + koff); kl = ldv8(qkl + koff);
      }
      a = MFMA_BF16(qh[t], kh, a);
      a = MFMA_BF16(qh[t], kl, a);
      a = MFMA_BF16(ql[t], kh, a);
    }
    sc[nt] = a;
  }
  float mx[4] = {-1e30f,-1e30f,-1e30f,-1e30f};
  #pragma unroll
  for (int nt=0; nt<NT; nt++)
    #pragma unroll
    for (int r=0;r<4;r++){ float v = sc[nt][r]*scale; sc[nt][r]=v; mx[r]=fmaxf(mx[r],v); }
  #pragma unroll
  for (int r=0;r<4;r++)
    for (int d=1; d<16; d<<=1) mx[r] = fmaxf(mx[r], __shfl_xor(mx[r], d, 64));
  float sm[4] = {0.f,0.f,0.f,0.f};
  #pragma unroll
  for (int nt=0; nt<NT; nt++)
    #pragma unroll
    for (int r=0;r<4;r++){ float p = __expf(sc[nt][r]-mx[r]); sc[nt][r]=p; sm[r]+=p; }
  #pragma unroll
  for (int r=0;r<4;r++){
    for (int d=1; d<16; d<<=1) sm[r] += __shfl_xor(sm[r], d, 64);
    sm[r] = 1.f/sm[r];
  }
  u16* Pwh = PH + wv*16*PSTR;
  u16* Pwl = PL + wv*16*PSTR;
  #pragma unroll
  for (int nt=0; nt<NT; nt++)
    #pragma unroll
    for (int r=0;r<4;r++){
      float p = sc[nt][r]*sm[r];
      u16 hi = f2b(p);
      Pwh[(quad*4+r)*PSTR + nt*16 + l16] = hi;
      Pwl[(quad*4+r)*PSTR + nt*16 + l16] = f2b(p - b2f(hi));
    }
  const u16* Prh = PH + wv*16*PSTR + (size_t)l16*PSTR;
  const u16* Prl = PL + wv*16*PSTR + (size_t)l16*PSTR;
  #pragma unroll
  for (int dt=0; dt<5; dt++){
    f32x4 o = {0.f,0.f,0.f,0.f};
    #pragma unroll
    for (int kk=0; kk<8; kk++){
      bf16v8 ph = ldv8(Prh + kk*32 + quad*8);
      bf16v8 pl = ldv8(Prl + kk*32 + quad*8);
      bf16v8 bv = ldv8(Vth + (size_t)(dt*16+l16)*VSTR + kk*32 + quad*8);
      o = MFMA_BF16(ph, bv, o);
      o = MFMA_BF16(pl, bv, o);
    }
    int d = dt*16 + l16;
    if (d < 72){
      #pragma unroll
      for (int r=0;r<4;r++){
        int row = qbase + wv*16 + quad*4 + r;
        size_t oi = (size_t)row*1152 + h*72 + d;
        u16 hh = f2b(o[r]);
        ohi[oi] = hh; olo[oi] = f2b(o[r] - b2f(hh));
      }
    }
  }
}

// ---------------- cross-attention, high-precision QK ----------------
__global__ __launch_bounds__(256) void attn_cross_hp(
    const float* __restrict__ Q32,
    const u16* __restrict__ Khi, const u16* __restrict__ Klo,
    const u16* __restrict__ Vt,                  // [h][80][448]
    float* __restrict__ O, float scale){
  constexpr int NT = 28, PSTR = 456, VSTR = 448;
  __shared__ u16 P[4*16*PSTR];
  const int tid = threadIdx.x, lane = tid & 63, wv = tid >> 6;
  const int quad = lane >> 4, l16 = lane & 15;
  const int h = blockIdx.y;
  const int qbase = blockIdx.x*64;
  const u16* Vth = Vt + (size_t)h*80*VSTR;
  const bf16v8 zf = __builtin_bit_cast(bf16v8, (u16v8)0);

  const int mrow = qbase + wv*16 + l16;
  const float* qp = Q32 + (size_t)mrow*1152 + h*72;
  bf16v8 qhi[3], qlo[3];
  #pragma unroll
  for (int t=0;t<3;t++){
    if (t==2 && quad!=0){ qhi[t]=zf; qlo[t]=zf; continue; }
    u16v8 hv, lv;
    #pragma unroll
    for (int j=0;j<8;j++){
      float v = qp[t*32 + (t==2?0:quad*8) + j];
      u16 h16 = f2b(v);
      hv[j] = h16; lv[j] = f2b(v - b2f(h16));
    }
    qhi[t] = __builtin_bit_cast(bf16v8, hv);
    qlo[t] = __builtin_bit_cast(bf16v8, lv);
  }
  f32x4 sc[NT];
  #pragma unroll
  for (int nt=0; nt<NT; nt++){
    f32x4 a = {0.f,0.f,0.f,0.f};
    #pragma unroll
    for (int t=0;t<3;t++){
      bf16v8 kh = zf, kl = zf;
      if (!(t==2 && quad!=0)){
        size_t koff = (size_t)(nt*16 + l16)*1152 + h*72 + t*32 + (t==2?0:quad*8);
        kh = ldv8(Khi + koff); kl = ldv8(Klo + koff);
      }
      a = MFMA_BF16(qhi[t], kh, a);
      a = MFMA_BF16(qhi[t], kl, a);
      a = MFMA_BF16(qlo[t], kh, a);
    }
    sc[nt] = a;
  }
  float mx[4] = {-1e30f,-1e30f,-1e30f,-1e30f};
  #pragma unroll
  for (int nt=0; nt<NT; nt++)
    #pragma unroll
    for (int r=0;r<4;r++){ float v = sc[nt][r]*scale; sc[nt][r]=v; mx[r]=fmaxf(mx[r],v); }
  #pragma unroll
  for (int r=0;r<4;r++)
    for (int d=1; d<16; d<<=1) mx[r] = fmaxf(mx[r], __shfl_xor(mx[r], d, 64));
  float sm[4] = {0.f,0.f,0.f,0.f};
  #pragma unroll
  for (int nt=0; nt<NT; nt++)
    #pragma unroll
    for (int r=0;r<4;r++){ float p = __expf(sc[nt][r]-mx[r]); sc[nt][r]=p; sm[r]+=p; }
  #pragma unroll
  for (int r=0;r<4;r++){
    for (int d=1; d<16; d<<=1) sm[r] += __shfl_xor(sm[r], d, 64);
    sm[r] = 1.f/sm[r];
  }
  u16* Pw = P + wv*16*PSTR;
  #pragma unroll
  for (int nt=0; nt<NT; nt++)
    #pragma unroll
    for (int r=0;r<4;r++)
      Pw[(quad*4+r)*PSTR + nt*16 + l16] = f2b(sc[nt][r]*sm[r]);
  const u16* Pr = P + wv*16*PSTR + (size_t)l16*PSTR;
  #pragma unroll
  for (int dt=0; dt<5; dt++){
    f32x4 o = {0.f,0.f,0.f,0.f};
    #pragma unroll
    for (int kk=0; kk<14; kk++){
      bf16v8 ap = ldv8(Pr + kk*32 + quad*8);
      bf16v8 bv = ldv8(Vth + (size_t)(dt*16+l16)*VSTR + kk*32 + quad*8);
      o = MFMA_BF16(ap, bv, o);
    }
    int d = dt*16 + l16;
    if (d < 72){
      #pragma unroll
      for (int r=0;r<4;r++){
        int row = qbase + wv*16 + quad*4 + r;
        O[(size_t)row*1152 + h*72 + d] = o[r];
      }
    }
  }
}

// ---------------- launch ----------------
extern "C" void kernel_launch(void* const* d_in, const int* in_sizes, int n_in,
                              void* d_out, int out_size, void* d_ws, size_t ws_size,
                              hipStream_t stream){
  const float* x    = (const float*)d_in[0];
  const float* y    = (const float*)d_in[1];
  const float* t    = (const float*)d_in[2];
  const float* sst  = (const float*)d_in[3];
  const float* Wqkv = (const float*)d_in[4];
  const float* bqkv = (const float*)d_in[5];
  const float* Wo   = (const float*)d_in[6];
  const float* bo   = (const float*)d_in[7];
  const float* Wkv  = (const float*)d_in[8];
  const float* bkv  = (const float*)d_in[9];
  const int*   qw_q  = (const int*)d_in[10];
  const float* sw_q  = (const float*)d_in[11];
  const int*   zw_q  = (const int*)d_in[12];
  const float* b_q   = (const float*)d_in[13];
  const int*   qw_cp = (const int*)d_in[14];
  const float* sw_cp = (const float*)d_in[15];
  const int*   zw_cp = (const int*)d_in[16];
  const float* b_cp  = (const float*)d_in[17];
  const int*   qw_f1 = (const int*)d_in[18];
  const float* sw_f1 = (const float*)d_in[19];
  const int*   zw_f1 = (const int*)d_in[20];
  const float* b_f1  = (const float*)d_in[21];
  const int*   qw_f2 = (const int*)d_in[22];
  const float* sw_f2 = (const float*)d_in[23];
  const int*   zw_f2 = (const int*)d_in[24];
  const float* b_f2  = (const float*)d_in[25];
  (void)in_sizes; (void)n_in; (void)out_size;

  // ---- workspace: 6 big regions, phase-disjoint aliasing (journal r5) ----
  constexpr size_t SZR = (size_t)4096*1152*4;        // 18,874,368
  constexpr size_t R0 = 0;                           // xw f32
  constexpr size_t R1 = R0 + SZR;                    // wqkv splits -> wkv/y splits -> q32/cp-out f32 -> q8h
  constexpr size_t R2 = R1 + SZR;                    // qkh -> wo-out/ao f32 -> hbuf(lo half) -> f2out f32
  constexpr size_t R3 = R2 + SZR;                    // qkl -> hbuf(hi half)
  constexpr size_t R4 = R3 + SZR;                    // xmh/ohi -> kv32+khi+klo+vtc -> w8f2   (9,437,184)
  constexpr size_t R5 = R4 + (size_t)9437184;        // xml/olo -> w8q,w8cp,w8f1              (9,437,184)
  constexpr size_t R6 = R5 + (size_t)9437184;        // vth -> woh/wol -> q8x                 (10,485,760)
  constexpr size_t RS = R6 + (size_t)10485760;
  constexpr size_t RQ = RS + (size_t)4096*4;
  constexpr size_t RM = RQ + (size_t)4096*4;
  constexpr size_t WS_NEED = RM + (size_t)2*6*1152*4;  // ~100.1 MB (proven ws >= 130 MB)
  if (ws_size < WS_NEED) return;

  char* ws = (char*)d_ws;
  float*  xw    = (float*)(ws + R0);
  u16*    wqkvh = (u16*)(ws + R1);
  u16*    wqkvl = (u16*)(ws + R1 + (size_t)3456*1152*2);
  u16*    wkvh  = (u16*)(ws + R1);
  u16*    wkvl  = (u16*)(ws + R1 + (size_t)2304*1152*2);
  u16*    yh    = (u16*)(ws + R1 + (size_t)2*2304*1152*2);
  u16*    yl    = (u16*)(ws + R1 + (size_t)2*2304*1152*2 + (size_t)448*1152*2);
  float*  q32   = (float*)(ws + R1);
  float*  cpout = (float*)(ws + R1);
  int8_t* q8h   = (int8_t*)(ws + R1);
  u16*    qkh   = (u16*)(ws + R2);
  float*  aof   = (float*)(ws + R2);   // wo-out, later cross-attn out
  u16*    hbuf  = (u16*)(ws + R2);     // 4096x4608 bf16 spans R2+R3
  float*  f2out = (float*)(ws + R2);
  u16*    qkl   = (u16*)(ws + R3);
  u16*    xmh   = (u16*)(ws + R4);
  u16*    ohi   = (u16*)(ws + R4);
  float*  kv32  = (float*)(ws + R4);
  u16*    khi   = (u16*)(ws + R4 + (size_t)4128768);
  u16*    klo   = (u16*)(ws + R4 + (size_t)5160960);
  u16*    vtc   = (u16*)(ws + R4 + (size_t)6193152);
  int8_t* w8f2  = (int8_t*)(ws + R4);
  u16*    xml   = (u16*)(ws + R5);
  u16*    olo   = (u16*)(ws + R5);
  int8_t* w8q   = (int8_t*)(ws + R5);
  int8_t* w8cp  = (int8_t*)(ws + R5 + (size_t)1327104);
  int8_t* w8f1  = (int8_t*)(ws + R5 + (size_t)2654208);
  u16*    vth   = (u16*)(ws + R6);
  u16*    woh   = (u16*)(ws + R6);
  u16*    wol   = (u16*)(ws + R6 + (size_t)1152*1152*2);
  int8_t* q8x   = (int8_t*)(ws + R6);
  float*  rs    = (float*)(ws + RS);
  int*    rq    = (int*)(ws + RQ);
  float*  mod   = (float*)(ws + RM);

  const float scale = 0.11785113019775793f; // 72^-0.5
  const int ETOT = 4096*1152, EB = (ETOT+255)/256;

  mod_add_k<<<(2*6*1152+255)/256,256,0,stream>>>(sst, t, mod);

  // ---- MSA branch (hp GEMMs on pre-split planes) ----
  ln_mod_split_k<<<4096,256,0,stream>>>(x, xmh, xml, mod, 0, 1);
  split2_k<<<(3456*1152+255)/256,256,0,stream>>>(Wqkv, wqkvh, wqkvl, 3456*1152);
  gemm_hp2<1><<<dim3(27,32),256,0,stream>>>(xmh,xml,1152, wqkvh,wqkvl,1152, bqkv, nullptr,0, 4096,1152, qkh,qkl,vth);
  attn_self_hp<<<dim3(4,16,16),256,0,stream>>>(qkh, qkl, vth, ohi, olo, scale);
  split2_k<<<(1152*1152+255)/256,256,0,stream>>>(Wo, woh, wol, 1152*1152);
  gemm_hp2<0><<<dim3(9,32),256,0,stream>>>(ohi,olo,1152, woh,wol,1152, bo, aof,1152, 4096,1152, nullptr,nullptr,nullptr);
  rgq_k<<<4096,256,0,stream>>>(x, aof, mod, 2, xw, q8x, rs, rq);

  // ---- cross-attn branch ----
  conv_i8_k<<<(1152*1152+255)/256,256,0,stream>>>(qw_q,  w8q,  1152*1152);
  conv_i8_k<<<(1152*1152+255)/256,256,0,stream>>>(qw_cp, w8cp, 1152*1152);
  split2_k<<<(2304*1152+255)/256,256,0,stream>>>(Wkv, wkvh, wkvl, 2304*1152);
  split2_k<<<(448*1152+255)/256,256,0,stream>>>(y, yh, yl, 448*1152);
  gemm_hp2<0><<<dim3(18,4),256,0,stream>>>(yh,yl,1152, wkvh,wkvl,1152, bkv, kv32,2304, 448,1152, nullptr,nullptr,nullptr);
  build_kv_split_k<<<(448*1152+255)/256,256,0,stream>>>(kv32, khi, klo);
  build_vt_cross_k<<<16,256,0,stream>>>(kv32, vtc);
  gemm_i8<<<dim3(9,32),256,0,stream>>>(q8x,1152, w8q,1152, rs,rq, sw_q,zw_q,b_q, q32,1152, 4096,1152, 0, 1);
  attn_cross_hp<<<dim3(64,16),256,0,stream>>>(q32, khi, klo, vtc, aof, scale);
  quant_rows_k<1><<<4096,256,0,stream>>>(aof, 1152, q8x, rs, rq);
  gemm_i8<<<dim3(9,32),256,0,stream>>>(q8x,1152, w8cp,1152, rs,rq, sw_cp,zw_cp,b_cp, cpout,1152, 4096,1152, 0, 1);

  // ---- MLP branch ----
  rlq_k<<<4096,256,0,stream>>>(xw, cpout, mod, 3, 4, q8x, rs, rq);
  conv_i8_k<<<(4608*1152+255)/256,256,0,stream>>>(qw_f1, w8f1, 4608*1152);
  gemm_i8<<<dim3(36,32),256,0,stream>>>(q8x,1152, w8f1,1152, rs,rq, sw_f1,zw_f1,b_f1, hbuf,4608, 4096,1152, 1, 0);
  quant_rows_k<0><<<4096,256,0,stream>>>(hbuf, 4608, q8h, rs, rq);
  conv_i8_k<<<(1152*4608+255)/256,256,0,stream>>>(qw_f2, w8f2, 1152*4608);
  gemm_i8<<<dim3(9,32),256,0,stream>>>(q8h,4608, w8f2,4608, rs,rq, sw_f2,zw_f2,b_f2, f2out,1152, 4096,4608, 0, 1);
  final_out_f32_k<<<EB,256,0,stream>>>(xw, f2out, mod, (float*)d_out);
}

// Round 8
// 939.779 us; speedup vs baseline: 1.1058x; 1.0164x over previous
//
#include <hip/hip_runtime.h>
#include <stdint.h>

typedef unsigned short u16;
typedef __bf16 bf16v8 __attribute__((ext_vector_type(8)));
typedef u16    u16v8  __attribute__((ext_vector_type(8)));
typedef float  f32x4  __attribute__((ext_vector_type(4)));
typedef int    i32x4  __attribute__((ext_vector_type(4)));

#define MFMA_BF16(a,b,c) __builtin_amdgcn_mfma_f32_16x16x32_bf16((a),(b),(c),0,0,0)
#define MFMA_I8(a,b,c)   __builtin_amdgcn_mfma_i32_16x16x64_i8((a),(b),(c),0,0,0)

__device__ __forceinline__ float b2f(u16 u){ union{unsigned u;float f;}v; v.u=((unsigned)u)<<16; return v.f; }
__device__ __forceinline__ u16 f2b(float f){ union{float f;unsigned u;}v; v.f=f;
  return (u16)((v.u + 0x7fffu + ((v.u>>16)&1u))>>16); }
__device__ __forceinline__ bf16v8 ldv8(const u16* p){ return __builtin_bit_cast(bf16v8, *(const u16v8*)p); }
__device__ __forceinline__ void gl2lds16(const void* g, void* l){
  __builtin_amdgcn_global_load_lds(
    (const __attribute__((address_space(1))) unsigned int*)g,
    (__attribute__((address_space(3))) unsigned int*)l,
    16, 0, 0);
}
__device__ __forceinline__ float gelu_t(float x){
  float t = tanhf(0.7978845608028654f*(x + 0.044715f*x*x*x));
  return 0.5f*x*(1.0f+t);
}

// ---------------- elementwise / prep ----------------
__global__ void mod_add_k(const float* __restrict__ sst, const float* __restrict__ t, float* __restrict__ mod){
  int i = blockIdx.x*256 + threadIdx.x;
  if (i < 2*6*1152) mod[i] = sst[i % 6912] + t[i];
}
__global__ void conv_i8_k(const int* __restrict__ src, int8_t* __restrict__ dst, int n){
  int i = blockIdx.x*256 + threadIdx.x;
  if (i < n) dst[i] = (int8_t)src[i];
}
// f32 -> bf16 hi/lo planes
__global__ void split2_k(const float* __restrict__ src, u16* __restrict__ hi, u16* __restrict__ lo, int n){
  int i = blockIdx.x*256 + threadIdx.x;
  if (i >= n) return;
  float v = src[i];
  u16 hh = f2b(v);
  hi[i] = hh; lo[i] = f2b(v - b2f(hh));
}
// LN over C=1152 with modulation -> hi/lo bf16 planes
__global__ void ln_mod_split_k(const float* __restrict__ src, u16* __restrict__ xh, u16* __restrict__ xl,
                               const float* __restrict__ mod, int shift_row, int scale_row){
  const int row = blockIdx.x, tid = threadIdx.x;
  const int b = row >> 11;
  const float* ms = mod + ((size_t)b*6 + shift_row)*1152;
  const float* mc = mod + ((size_t)b*6 + scale_row)*1152;
  __shared__ float r1[256], r2[256];
  float s = 0.f, sq = 0.f, vals[5]; int cnt = 0;
  for (int c = tid; c < 1152; c += 256){
    float v = src[(size_t)row*1152+c];
    vals[cnt++] = v; s += v; sq += v*v;
  }
  r1[tid]=s; r2[tid]=sq; __syncthreads();
  for (int st=128; st>0; st>>=1){ if (tid<st){ r1[tid]+=r1[tid+st]; r2[tid]+=r2[tid+st]; } __syncthreads(); }
  float mean = r1[0]*(1.f/1152.f);
  float var  = r2[0]*(1.f/1152.f) - mean*mean;
  float rstd = rsqrtf(var + 1e-6f);
  cnt = 0;
  for (int c = tid; c < 1152; c += 256){
    float v = (vals[cnt++]-mean)*rstd*(1.f+mc[c]) + ms[c];
    u16 hh = f2b(v);
    xh[(size_t)row*1152+c] = hh;
    xl[(size_t)row*1152+c] = f2b(v - b2f(hh));
  }
}
// fused: xw = x + gate*ao, then per-row int8 quant of xw
__global__ void rgq_k(const float* __restrict__ x, const float* __restrict__ ao,
                      const float* __restrict__ mod, int gate_row, float* __restrict__ xw,
                      int8_t* __restrict__ q8, float* __restrict__ s_out, int* __restrict__ q_out){
  const int row = blockIdx.x, tid = threadIdx.x;
  const int b = row >> 11;
  const float* mg = mod + ((size_t)b*6 + gate_row)*1152;
  __shared__ float r1[256];
  __shared__ int ri[256];
  float mx = 0.f, vals[5]; int cnt = 0;
  for (int c = tid; c < 1152; c += 256){
    float v = x[(size_t)row*1152+c] + mg[c]*ao[(size_t)row*1152+c];
    xw[(size_t)row*1152+c] = v;
    vals[cnt++] = v; mx = fmaxf(mx, fabsf(v));
  }
  r1[tid]=mx; __syncthreads();
  for (int st=128; st>0; st>>=1){ if (tid<st) r1[tid]=fmaxf(r1[tid],r1[tid+st]); __syncthreads(); }
  const float s_ = fmaxf(r1[0]*(1.f/127.f), 1e-8f);
  const float inv = 1.f/s_;
  int acc = 0; cnt = 0;
  for (int c = tid; c < 1152; c += 256){
    float q = rintf(vals[cnt++]*inv);
    q = fminf(fmaxf(q, -127.f), 127.f);
    q8[(size_t)row*1152+c] = (int8_t)q;
    acc += (int)q;
  }
  ri[tid]=acc; __syncthreads();
  for (int st=128; st>0; st>>=1){ if (tid<st) ri[tid]+=ri[tid+st]; __syncthreads(); }
  if (tid==0){ s_out[row]=s_; q_out[row]=ri[0]; }
}
// fused: xw += add; LN+mod; per-row int8 quant
__global__ void rlq_k(float* __restrict__ xw, const float* __restrict__ add,
                      const float* __restrict__ mod, int shift_row, int scale_row,
                      int8_t* __restrict__ q8, float* __restrict__ s_out, int* __restrict__ q_out){
  const int row = blockIdx.x, tid = threadIdx.x;
  const int b = row >> 11;
  const float* ms = mod + ((size_t)b*6 + shift_row)*1152;
  const float* mc = mod + ((size_t)b*6 + scale_row)*1152;
  __shared__ float r1[256], r2[256];
  __shared__ int ri[256];
  float s = 0.f, sq = 0.f, vals[5]; int cnt = 0;
  for (int c = tid; c < 1152; c += 256){
    float v = xw[(size_t)row*1152+c] + add[(size_t)row*1152+c];
    xw[(size_t)row*1152+c] = v;
    vals[cnt++] = v; s += v; sq += v*v;
  }
  r1[tid]=s; r2[tid]=sq; __syncthreads();
  for (int st=128; st>0; st>>=1){ if (tid<st){ r1[tid]+=r1[tid+st]; r2[tid]+=r2[tid+st]; } __syncthreads(); }
  float mean = r1[0]*(1.f/1152.f);
  float var  = r2[0]*(1.f/1152.f) - mean*mean;
  float rstd = rsqrtf(var + 1e-6f);
  __syncthreads();
  float mx = 0.f; cnt = 0;
  for (int c = tid; c < 1152; c += 256){
    float v = (vals[cnt]-mean)*rstd*(1.f+mc[c]) + ms[c];
    vals[cnt++] = v; mx = fmaxf(mx, fabsf(v));
  }
  r1[tid]=mx; __syncthreads();
  for (int st=128; st>0; st>>=1){ if (tid<st) r1[tid]=fmaxf(r1[tid],r1[tid+st]); __syncthreads(); }
  const float s_ = fmaxf(r1[0]*(1.f/127.f), 1e-8f);
  const float inv = 1.f/s_;
  int acc = 0; cnt = 0;
  for (int c = tid; c < 1152; c += 256){
    float q = rintf(vals[cnt++]*inv);
    q = fminf(fmaxf(q, -127.f), 127.f);
    q8[(size_t)row*1152+c] = (int8_t)q;
    acc += (int)q;
  }
  ri[tid]=acc; __syncthreads();
  for (int st=128; st>0; st>>=1){ if (tid<st) ri[tid]+=ri[tid+st]; __syncthreads(); }
  if (tid==0){ s_out[row]=s_; q_out[row]=ri[0]; }
}
// register-cached row quant (C_ <= 4608)
template<int SRC_F32>
__global__ void quant_rows_k(const void* __restrict__ src, int C_,
                             int8_t* __restrict__ q8, float* __restrict__ s_out, int* __restrict__ q_out){
  const int row = blockIdx.x, tid = threadIdx.x;
  __shared__ float red[256];
  __shared__ int redi[256];
  float vals[18];
  float mx = 0.f; int cnt = 0;
  for (int c = tid; c < C_; c += 256){
    float v = SRC_F32 ? ((const float*)src)[(size_t)row*C_+c] : b2f(((const u16*)src)[(size_t)row*C_+c]);
    vals[cnt++] = v;
    mx = fmaxf(mx, fabsf(v));
  }
  red[tid]=mx; __syncthreads();
  for (int st=128; st>0; st>>=1){ if (tid<st) red[tid]=fmaxf(red[tid],red[tid+st]); __syncthreads(); }
  const float s_ = fmaxf(red[0]*(1.f/127.f), 1e-8f);
  const float inv = 1.f/s_;
  int acc = 0; cnt = 0;
  for (int c = tid; c < C_; c += 256){
    float q = rintf(vals[cnt++]*inv);
    q = fminf(fmaxf(q, -127.f), 127.f);
    q8[(size_t)row*C_+c] = (int8_t)q;
    acc += (int)q;
  }
  redi[tid]=acc; __syncthreads();
  for (int st=128; st>0; st>>=1){ if (tid<st) redi[tid]+=redi[tid+st]; __syncthreads(); }
  if (tid==0){ s_out[row]=s_; q_out[row]=redi[0]; }
}
__global__ void final_out_f32_k(const float* __restrict__ xw, const float* __restrict__ h,
                                const float* __restrict__ mod, float* __restrict__ out){
  size_t i = (size_t)blockIdx.x*256 + threadIdx.x;
  if (i >= (size_t)4096*1152) return;
  int c = (int)(i % 1152); int b = (int)((i/1152) >> 11);
  out[i] = xw[i] + mod[((size_t)b*6+5)*1152 + c] * h[i];
}
__global__ void build_vt_cross_k(const float* __restrict__ kv32, u16* __restrict__ vt){
  int h = blockIdx.x;
  u16* dst = vt + (size_t)h*80*448;
  const float* srcb = kv32 + 1152 + h*72;
  for (int idx = threadIdx.x; idx < 72*448; idx += 256){
    int d = idx/448, ss = idx - d*448;
    dst[d*448 + ss] = f2b(srcb[(size_t)ss*2304 + d]);
  }
}
__global__ void build_kv_split_k(const float* __restrict__ kv32, u16* __restrict__ khi, u16* __restrict__ klo){
  int i = blockIdx.x*256 + threadIdx.x;
  if (i >= 448*1152) return;
  int row = i / 1152, c = i - row*1152;
  float v = kv32[(size_t)row*2304 + c];
  u16 h16 = f2b(v);
  khi[i] = h16;
  klo[i] = f2b(v - b2f(h16));
}

// ------- high-precision GEMM on pre-split bf16 hi/lo planes -------
// out[M,N] = (Ah+Al)[M,K] @ (Wh+Wl)[N,K]^T + bias  (3-product MFMA, err ~2^-18)
// BK=32, corrected XOR swizzle for 64B rows: phys chunk = logical ^ ((row>>1)&3)
// -> ds_read window = 4*(l16&1) + quad^((l16>>1)&3): all 8 windows x2 = conflict-free
template<int MODE>
__global__ __launch_bounds__(256,4) void gemm_hp2(
    const u16* __restrict__ Ah, const u16* __restrict__ Al, int lda,
    const u16* __restrict__ Wh, const u16* __restrict__ Wl, int ldw,
    const float* __restrict__ bias, float* __restrict__ out, int ldo, int M, int K,
    u16* __restrict__ qkh, u16* __restrict__ qkl, u16* __restrict__ vth){
  __shared__ u16 sAh[128*32];
  __shared__ u16 sAl[128*32];
  __shared__ u16 sWh[128*32];
  __shared__ u16 sWl[128*32];
  const int tid = threadIdx.x, lane = tid & 63;
  const int wv = tid >> 6, wx = wv & 1, wy = wv >> 1;
  const int quad = lane >> 4, l16 = lane & 15;
  const int m0 = blockIdx.y*128, n0 = blockIdx.x*128;
  f32x4 acc[4][4];
  #pragma unroll
  for (int i=0;i<4;i++)
    #pragma unroll
    for (int j=0;j<4;j++) acc[i][j] = (f32x4){0.f,0.f,0.f,0.f};
  for (int k0=0; k0<K; k0+=32){
    #pragma unroll
    for (int r=0;r<2;r++){
      int slotbase = r*256 + wv*64;        // wave-uniform LDS base (slot*16B)
      int slot = slotbase + lane;
      int row = slot >> 2;                 // 4 chunks of 16B per 32-u16 row
      int col8 = ((slot ^ (row>>1)) & 3) * 8;  // phys chunk = logical ^ ((row>>1)&3)
      int gm = m0 + row; if (gm > M-1) gm = M-1;
      size_t aoff = (size_t)gm*lda + k0 + col8;
      size_t woff = (size_t)(n0+row)*ldw + k0 + col8;
      gl2lds16(Ah + aoff, &sAh[(size_t)slotbase*8]);
      gl2lds16(Al + aoff, &sAl[(size_t)slotbase*8]);
      gl2lds16(Wh + woff, &sWh[(size_t)slotbase*8]);
      gl2lds16(Wl + woff, &sWl[(size_t)slotbase*8]);
    }
    __syncthreads();
    const int cs = ((quad ^ ((l16>>1)&3)) * 8);  // recovers logical chunk = quad
    bf16v8 ah[4], al[4], bh[4], bl[4];
    #pragma unroll
    for (int i=0;i<4;i++){
      ah[i] = ldv8(&sAh[(wy*64+i*16+l16)*32 + cs]);
      al[i] = ldv8(&sAl[(wy*64+i*16+l16)*32 + cs]);
    }
    #pragma unroll
    for (int j=0;j<4;j++){
      bh[j] = ldv8(&sWh[(wx*64+j*16+l16)*32 + cs]);
      bl[j] = ldv8(&sWl[(wx*64+j*16+l16)*32 + cs]);
    }
    #pragma unroll
    for (int i=0;i<4;i++)
      #pragma unroll
      for (int j=0;j<4;j++){
        acc[i][j] = MFMA_BF16(ah[i], bh[j], acc[i][j]);
        acc[i][j] = MFMA_BF16(ah[i], bl[j], acc[i][j]);
        acc[i][j] = MFMA_BF16(al[i], bh[j], acc[i][j]);
      }
    __syncthreads();
  }
  #pragma unroll
  for (int j=0;j<4;j++){
    int col = n0 + wx*64 + j*16 + l16;
    float bc = bias ? bias[col] : 0.f;
    #pragma unroll
    for (int i=0;i<4;i++)
      #pragma unroll
      for (int r=0;r<4;r++){
        int row = m0 + wy*64 + i*16 + quad*4 + r;
        if (row >= M) continue;
        float v = acc[i][j][r] + bc;
        if (MODE == 0){
          out[(size_t)row*ldo + col] = v;
        } else {
          if (col < 2304){
            u16 hh = f2b(v);
            qkh[(size_t)row*2304 + col] = hh;
            qkl[(size_t)row*2304 + col] = f2b(v - b2f(hh));
          } else {
            int vc = col - 2304;
            int hd_ = vc/72, d = vc - hd_*72;
            int z = row >> 8, s2 = row & 255;
            vth[((size_t)(z*16+hd_)*80 + d)*256 + s2] = f2b(v);
          }
        }
      }
  }
}

// ---------------- int8 GEMM with W8A8 epilogue (XOR-swizzled LDS) ----------------
__global__ __launch_bounds__(256,3) void gemm_i8(
    const int8_t* __restrict__ A, int lda, const int8_t* __restrict__ W, int ldw,
    const float* __restrict__ rs, const int* __restrict__ rq,
    const float* __restrict__ sw, const int* __restrict__ zw, const float* __restrict__ bias,
    void* __restrict__ out, int ldo, int M, int K, int do_gelu, int out_f32){
  __shared__ int8_t As[128*128];
  __shared__ int8_t Bs[128*128];
  const int tid = threadIdx.x, lane = tid & 63, wv = tid >> 6;
  const int wx = wv & 1, wy = wv >> 1, quad = lane >> 4, l16 = lane & 15;
  const int m0 = blockIdx.y*128, n0 = blockIdx.x*128;
  const int srow = lane >> 3, schunk = lane & 7;
  const int scol = ((schunk ^ srow) & 7) * 16;   // XOR swizzle fetch column (128B rows)
  i32x4 zi4 = {0,0,0,0};
  i32x4 acc[4][4];
  #pragma unroll
  for (int i=0;i<4;i++){ acc[i][0]=zi4; acc[i][1]=zi4; acc[i][2]=zi4; acc[i][3]=zi4; }
  for (int k0 = 0; k0 < K; k0 += 128){
    #pragma unroll
    for (int i=0;i<4;i++){
      int rr = (i*4 + wv)*8;
      int gm = m0 + rr + srow; if (gm > M-1) gm = M-1;
      gl2lds16(A + (size_t)gm*lda + k0 + scol, &As[rr*128]);
      int gn = n0 + rr + srow;
      gl2lds16(W + (size_t)gn*ldw + k0 + scol, &Bs[rr*128]);
    }
    __syncthreads();
    #pragma unroll
    for (int kk=0; kk<2; kk++){
      const int cs = (((kk*4 + quad) ^ (l16 & 7)) * 16);
      i32x4 af[4], bw[4];
      #pragma unroll
      for (int i=0;i<4;i++) af[i] = *(const i32x4*)&As[(wy*64+i*16+l16)*128 + cs];
      #pragma unroll
      for (int j=0;j<4;j++) bw[j] = *(const i32x4*)&Bs[(wx*64+j*16+l16)*128 + cs];
      #pragma unroll
      for (int i=0;i<4;i++)
        #pragma unroll
        for (int j=0;j<4;j++)
          acc[i][j] = MFMA_I8(af[i], bw[j], acc[i][j]);
    }
    __syncthreads();
  }
  #pragma unroll
  for (int j=0;j<4;j++){
    int col = n0 + wx*64 + j*16 + l16;
    float swc = sw[col]; float zwc = (float)zw[col]; float bc = bias[col];
    #pragma unroll
    for (int i=0;i<4;i++)
      #pragma unroll
      for (int r=0;r<4;r++){
        int row = m0 + wy*64 + i*16 + quad*4 + r;
        if (row < M){
          float v = ((float)acc[i][j][r] - (float)rq[row]*zwc) * (rs[row]*swc) + bc;
          if (do_gelu) v = gelu_t(v);
          if (out_f32) ((float*)out)[(size_t)row*ldo + col] = v;
          else         ((u16*)out)[(size_t)row*ldo + col] = f2b(v);
        }
      }
  }
}

// ---------------- self-attention, high precision ----------------
__global__ __launch_bounds__(256) void attn_self_hp(
    const u16* __restrict__ qkh, const u16* __restrict__ qkl,
    const u16* __restrict__ vth, u16* __restrict__ ohi, u16* __restrict__ olo, float scale){
  constexpr int NT = 16, PSTR = 264, VSTR = 256;
  __shared__ u16 PH[4*16*PSTR];
  __shared__ u16 PL[4*16*PSTR];
  const int tid = threadIdx.x, lane = tid & 63, wv = tid >> 6;
  const int quad = lane >> 4, l16 = lane & 15;
  const int h = blockIdx.y, z = blockIdx.z;
  const int qbase = z*256 + blockIdx.x*64;
  const int qc = h*72, kc = 1152 + h*72;
  const u16* Vth = vth + (size_t)(z*16+h)*80*VSTR;
  const bf16v8 zf = __builtin_bit_cast(bf16v8, (u16v8)0);
  const int mrow = qbase + wv*16 + l16;

  bf16v8 qh[3], ql[3];
  #pragma unroll
  for (int t=0;t<3;t++){
    if (t==2 && quad!=0){ qh[t]=zf; ql[t]=zf; }
    else {
      size_t off = (size_t)mrow*2304 + qc + t*32 + (t==2?0:quad*8);
      qh[t] = ldv8(qkh + off); ql[t] = ldv8(qkl + off);
    }
  }
  f32x4 sc[NT];
  #pragma unroll
  for (int nt=0; nt<NT; nt++){
    f32x4 a = {0.f,0.f,0.f,0.f};
    #pragma unroll
    for (int t=0;t<3;t++){
      bf16v8 kh = zf, kl = zf;
      if (!(t==2 && quad!=0)){
        size_t koff = (size_t)(z*256 + nt*16 + l16)*2304 + kc + t*32 + (t==2?0:quad*8);
        kh = ldv8(qkh + koff); kl = ldv8(qkl + koff);
      }
      a = MFMA_BF16(qh[t], kh, a);
      a = MFMA_BF16(qh[t], kl, a);
      a = MFMA_BF16(ql[t], kh, a);
    }
    sc[nt] = a;
  }
  float mx[4] = {-1e30f,-1e30f,-1e30f,-1e30f};
  #pragma unroll
  for (int nt=0; nt<NT; nt++)
    #pragma unroll
    for (int r=0;r<4;r++){ float v = sc[nt][r]*scale; sc[nt][r]=v; mx[r]=fmaxf(mx[r],v); }
  #pragma unroll
  for (int r=0;r<4;r++)
    for (int d=1; d<16; d<<=1) mx[r] = fmaxf(mx[r], __shfl_xor(mx[r], d, 64));
  float sm[4] = {0.f,0.f,0.f,0.f};
  #pragma unroll
  for (int nt=0; nt<NT; nt++)
    #pragma unroll
    for (int r=0;r<4;r++){ float p = __expf(sc[nt][r]-mx[r]); sc[nt][r]=p; sm[r]+=p; }
  #pragma unroll
  for (int r=0;r<4;r++){
    for (int d=1; d<16; d<<=1) sm[r] += __shfl_xor(sm[r], d, 64);
    sm[r] = 1.f/sm[r];
  }
  u16* Pwh = PH + wv*16*PSTR;
  u16* Pwl = PL + wv*16*PSTR;
  #pragma unroll
  for (int nt=0; nt<NT; nt++)
    #pragma unroll
    for (int r=0;r<4;r++){
      float p = sc[nt][r]*sm[r];
      u16 hi = f2b(p);
      Pwh[(quad*4+r)*PSTR + nt*16 + l16] = hi;
      Pwl[(quad*4+r)*PSTR + nt*16 + l16] = f2b(p - b2f(hi));
    }
  const u16* Prh = PH + wv*16*PSTR + (size_t)l16*PSTR;
  const u16* Prl = PL + wv*16*PSTR + (size_t)l16*PSTR;
  #pragma unroll
  for (int dt=0; dt<5; dt++){
    f32x4 o = {0.f,0.f,0.f,0.f};
    #pragma unroll
    for (int kk=0; kk<8; kk++){
      bf16v8 ph = ldv8(Prh + kk*32 + quad*8);
      bf16v8 pl = ldv8(Prl + kk*32 + quad*8);
      bf16v8 bv = ldv8(Vth + (size_t)(dt*16+l16)*VSTR + kk*32 + quad*8);
      o = MFMA_BF16(ph, bv, o);
      o = MFMA_BF16(pl, bv, o);
    }
    int d = dt*16 + l16;
    if (d < 72){
      #pragma unroll
      for (int r=0;r<4;r++){
        int row = qbase + wv*16 + quad*4 + r;
        size_t oi = (size_t)row*1152 + h*72 + d;
        u16 hh = f2b(o[r]);
        ohi[oi] = hh; olo[oi] = f2b(o[r] - b2f(hh));
      }
    }
  }
}

// ---------------- cross-attention, high-precision QK ----------------
__global__ __launch_bounds__(256) void attn_cross_hp(
    const float* __restrict__ Q32,
    const u16* __restrict__ Khi, const u16* __restrict__ Klo,
    const u16* __restrict__ Vt,                  // [h][80][448]
    float* __restrict__ O, float scale){
  constexpr int NT = 28, PSTR = 456, VSTR = 448;
  __shared__ u16 P[4*16*PSTR];
  const int tid = threadIdx.x, lane = tid & 63, wv = tid >> 6;
  const int quad = lane >> 4, l16 = lane & 15;
  const int h = blockIdx.y;
  const int qbase = blockIdx.x*64;
  const u16* Vth = Vt + (size_t)h*80*VSTR;
  const bf16v8 zf = __builtin_bit_cast(bf16v8, (u16v8)0);

  const int mrow = qbase + wv*16 + l16;
  const float* qp = Q32 + (size_t)mrow*1152 + h*72;
  bf16v8 qhi[3], qlo[3];
  #pragma unroll
  for (int t=0;t<3;t++){
    if (t==2 && quad!=0){ qhi[t]=zf; qlo[t]=zf; continue; }
    u16v8 hv, lv;
    #pragma unroll
    for (int j=0;j<8;j++){
      float v = qp[t*32 + (t==2?0:quad*8) + j];
      u16 h16 = f2b(v);
      hv[j] = h16; lv[j] = f2b(v - b2f(h16));
    }
    qhi[t] = __builtin_bit_cast(bf16v8, hv);
    qlo[t] = __builtin_bit_cast(bf16v8, lv);
  }
  f32x4 sc[NT];
  #pragma unroll
  for (int nt=0; nt<NT; nt++){
    f32x4 a = {0.f,0.f,0.f,0.f};
    #pragma unroll
    for (int t=0;t<3;t++){
      bf16v8 kh = zf, kl = zf;
      if (!(t==2 && quad!=0)){
        size_t koff = (size_t)(nt*16 + l16)*1152 + h*72 + t*32 + (t==2?0:quad*8);
        kh = ldv8(Khi + koff); kl = ldv8(Klo + koff);
      }
      a = MFMA_BF16(qhi[t], kh, a);
      a = MFMA_BF16(qhi[t], kl, a);
      a = MFMA_BF16(qlo[t], kh, a);
    }
    sc[nt] = a;
  }
  float mx[4] = {-1e30f,-1e30f,-1e30f,-1e30f};
  #pragma unroll
  for (int nt=0; nt<NT; nt++)
    #pragma unroll
    for (int r=0;r<4;r++){ float v = sc[nt][r]*scale; sc[nt][r]=v; mx[r]=fmaxf(mx[r],v); }
  #pragma unroll
  for (int r=0;r<4;r++)
    for (int d=1; d<16; d<<=1) mx[r] = fmaxf(mx[r], __shfl_xor(mx[r], d, 64));
  float sm[4] = {0.f,0.f,0.f,0.f};
  #pragma unroll
  for (int nt=0; nt<NT; nt++)
    #pragma unroll
    for (int r=0;r<4;r++){ float p = __expf(sc[nt][r]-mx[r]); sc[nt][r]=p; sm[r]+=p; }
  #pragma unroll
  for (int r=0;r<4;r++){
    for (int d=1; d<16; d<<=1) sm[r] += __shfl_xor(sm[r], d, 64);
    sm[r] = 1.f/sm[r];
  }
  u16* Pw = P + wv*16*PSTR;
  #pragma unroll
  for (int nt=0; nt<NT; nt++)
    #pragma unroll
    for (int r=0;r<4;r++)
      Pw[(quad*4+r)*PSTR + nt*16 + l16] = f2b(sc[nt][r]*sm[r]);
  const u16* Pr = P + wv*16*PSTR + (size_t)l16*PSTR;
  #pragma unroll
  for (int dt=0; dt<5; dt++){
    f32x4 o = {0.f,0.f,0.f,0.f};
    #pragma unroll
    for (int kk=0; kk<14; kk++){
      bf16v8 ap = ldv8(Pr + kk*32 + quad*8);
      bf16v8 bv = ldv8(Vth + (size_t)(dt*16+l16)*VSTR + kk*32 + quad*8);
      o = MFMA_BF16(ap, bv, o);
    }
    int d = dt*16 + l16;
    if (d < 72){
      #pragma unroll
      for (int r=0;r<4;r++){
        int row = qbase + wv*16 + quad*4 + r;
        O[(size_t)row*1152 + h*72 + d] = o[r];
      }
    }
  }
}

// ---------------- launch ----------------
extern "C" void kernel_launch(void* const* d_in, const int* in_sizes, int n_in,
                              void* d_out, int out_size, void* d_ws, size_t ws_size,
                              hipStream_t stream){
  const float* x    = (const float*)d_in[0];
  const float* y    = (const float*)d_in[1];
  const float* t    = (const float*)d_in[2];
  const float* sst  = (const float*)d_in[3];
  const float* Wqkv = (const float*)d_in[4];
  const float* bqkv = (const float*)d_in[5];
  const float* Wo   = (const float*)d_in[6];
  const float* bo   = (const float*)d_in[7];
  const float* Wkv  = (const float*)d_in[8];
  const float* bkv  = (const float*)d_in[9];
  const int*   qw_q  = (const int*)d_in[10];
  const float* sw_q  = (const float*)d_in[11];
  const int*   zw_q  = (const int*)d_in[12];
  const float* b_q   = (const float*)d_in[13];
  const int*   qw_cp = (const int*)d_in[14];
  const float* sw_cp = (const float*)d_in[15];
  const int*   zw_cp = (const int*)d_in[16];
  const float* b_cp  = (const float*)d_in[17];
  const int*   qw_f1 = (const int*)d_in[18];
  const float* sw_f1 = (const float*)d_in[19];
  const int*   zw_f1 = (const int*)d_in[20];
  const float* b_f1  = (const float*)d_in[21];
  const int*   qw_f2 = (const int*)d_in[22];
  const float* sw_f2 = (const float*)d_in[23];
  const int*   zw_f2 = (const int*)d_in[24];
  const float* b_f2  = (const float*)d_in[25];
  (void)in_sizes; (void)n_in; (void)out_size;

  // ---- workspace: 6 big regions, phase-disjoint aliasing (journal r5) ----
  constexpr size_t SZR = (size_t)4096*1152*4;        // 18,874,368
  constexpr size_t R0 = 0;                           // xw f32
  constexpr size_t R1 = R0 + SZR;                    // wqkv splits -> wkv/y splits -> q32/cp-out f32 -> q8h
  constexpr size_t R2 = R1 + SZR;                    // qkh -> wo-out/ao f32 -> hbuf(lo half) -> f2out f32
  constexpr size_t R3 = R2 + SZR;                    // qkl -> hbuf(hi half)
  constexpr size_t R4 = R3 + SZR;                    // xmh/ohi -> kv32+khi+klo+vtc -> w8f2   (9,437,184)
  constexpr size_t R5 = R4 + (size_t)9437184;        // xml/olo -> w8q,w8cp,w8f1              (9,437,184)
  constexpr size_t R6 = R5 + (size_t)9437184;        // vth -> woh/wol -> q8x                 (10,485,760)
  constexpr size_t RS = R6 + (size_t)10485760;
  constexpr size_t RQ = RS + (size_t)4096*4;
  constexpr size_t RM = RQ + (size_t)4096*4;
  constexpr size_t WS_NEED = RM + (size_t)2*6*1152*4;  // ~100.1 MB (proven ws >= 130 MB)
  if (ws_size < WS_NEED) return;

  char* ws = (char*)d_ws;
  float*  xw    = (float*)(ws + R0);
  u16*    wqkvh = (u16*)(ws + R1);
  u16*    wqkvl = (u16*)(ws + R1 + (size_t)3456*1152*2);
  u16*    wkvh  = (u16*)(ws + R1);
  u16*    wkvl  = (u16*)(ws + R1 + (size_t)2304*1152*2);
  u16*    yh    = (u16*)(ws + R1 + (size_t)2*2304*1152*2);
  u16*    yl    = (u16*)(ws + R1 + (size_t)2*2304*1152*2 + (size_t)448*1152*2);
  float*  q32   = (float*)(ws + R1);
  float*  cpout = (float*)(ws + R1);
  int8_t* q8h   = (int8_t*)(ws + R1);
  u16*    qkh   = (u16*)(ws + R2);
  float*  aof   = (float*)(ws + R2);   // wo-out, later cross-attn out
  u16*    hbuf  = (u16*)(ws + R2);     // 4096x4608 bf16 spans R2+R3
  float*  f2out = (float*)(ws + R2);
  u16*    qkl   = (u16*)(ws + R3);
  u16*    xmh   = (u16*)(ws + R4);
  u16*    ohi   = (u16*)(ws + R4);
  float*  kv32  = (float*)(ws + R4);
  u16*    khi   = (u16*)(ws + R4 + (size_t)4128768);
  u16*    klo   = (u16*)(ws + R4 + (size_t)5160960);
  u16*    vtc   = (u16*)(ws + R4 + (size_t)6193152);
  int8_t* w8f2  = (int8_t*)(ws + R4);
  u16*    xml   = (u16*)(ws + R5);
  u16*    olo   = (u16*)(ws + R5);
  int8_t* w8q   = (int8_t*)(ws + R5);
  int8_t* w8cp  = (int8_t*)(ws + R5 + (size_t)1327104);
  int8_t* w8f1  = (int8_t*)(ws + R5 + (size_t)2654208);
  u16*    vth   = (u16*)(ws + R6);
  u16*    woh   = (u16*)(ws + R6);
  u16*    wol   = (u16*)(ws + R6 + (size_t)1152*1152*2);
  int8_t* q8x   = (int8_t*)(ws + R6);
  float*  rs    = (float*)(ws + RS);
  int*    rq    = (int*)(ws + RQ);
  float*  mod   = (float*)(ws + RM);

  const float scale = 0.11785113019775793f; // 72^-0.5
  const int ETOT = 4096*1152, EB = (ETOT+255)/256;

  mod_add_k<<<(2*6*1152+255)/256,256,0,stream>>>(sst, t, mod);

  // ---- MSA branch (hp GEMMs on pre-split planes) ----
  ln_mod_split_k<<<4096,256,0,stream>>>(x, xmh, xml, mod, 0, 1);
  split2_k<<<(3456*1152+255)/256,256,0,stream>>>(Wqkv, wqkvh, wqkvl, 3456*1152);
  gemm_hp2<1><<<dim3(27,32),256,0,stream>>>(xmh,xml,1152, wqkvh,wqkvl,1152, bqkv, nullptr,0, 4096,1152, qkh,qkl,vth);
  attn_self_hp<<<dim3(4,16,16),256,0,stream>>>(qkh, qkl, vth, ohi, olo, scale);
  split2_k<<<(1152*1152+255)/256,256,0,stream>>>(Wo, woh, wol, 1152*1152);
  gemm_hp2<0><<<dim3(9,32),256,0,stream>>>(ohi,olo,1152, woh,wol,1152, bo, aof,1152, 4096,1152, nullptr,nullptr,nullptr);
  rgq_k<<<4096,256,0,stream>>>(x, aof, mod, 2, xw, q8x, rs, rq);

  // ---- cross-attn branch ----
  conv_i8_k<<<(1152*1152+255)/256,256,0,stream>>>(qw_q,  w8q,  1152*1152);
  conv_i8_k<<<(1152*1152+255)/256,256,0,stream>>>(qw_cp, w8cp, 1152*1152);
  split2_k<<<(2304*1152+255)/256,256,0,stream>>>(Wkv, wkvh, wkvl, 2304*1152);
  split2_k<<<(448*1152+255)/256,256,0,stream>>>(y, yh, yl, 448*1152);
  gemm_hp2<0><<<dim3(18,4),256,0,stream>>>(yh,yl,1152, wkvh,wkvl,1152, bkv, kv32,2304, 448,1152, nullptr,nullptr,nullptr);
  build_kv_split_k<<<(448*1152+255)/256,256,0,stream>>>(kv32, khi, klo);
  build_vt_cross_k<<<16,256,0,stream>>>(kv32, vtc);
  gemm_i8<<<dim3(9,32),256,0,stream>>>(q8x,1152, w8q,1152, rs,rq, sw_q,zw_q,b_q, q32,1152, 4096,1152, 0, 1);
  attn_cross_hp<<<dim3(64,16),256,0,stream>>>(q32, khi, klo, vtc, aof, scale);
  quant_rows_k<1><<<4096,256,0,stream>>>(aof, 1152, q8x, rs, rq);
  gemm_i8<<<dim3(9,32),256,0,stream>>>(q8x,1152, w8cp,1152, rs,rq, sw_cp,zw_cp,b_cp, cpout,1152, 4096,1152, 0, 1);

  // ---- MLP branch ----
  rlq_k<<<4096,256,0,stream>>>(xw, cpout, mod, 3, 4, q8x, rs, rq);
  conv_i8_k<<<(4608*1152+255)/256,256,0,stream>>>(qw_f1, w8f1, 4608*1152);
  gemm_i8<<<dim3(36,32),256,0,stream>>>(q8x,1152, w8f1,1152, rs,rq, sw_f1,zw_f1,b_f1, hbuf,4608, 4096,1152, 1, 0);
  quant_rows_k<0><<<4096,256,0,stream>>>(hbuf, 4608, q8h, rs, rq);
  conv_i8_k<<<(1152*4608+255)/256,256,0,stream>>>(qw_f2, w8f2, 1152*4608);
  gemm_i8<<<dim3(9,32),256,0,stream>>>(q8h,4608, w8f2,4608, rs,rq, sw_f2,zw_f2,b_f2, f2out,1152, 4096,4608, 0, 1);
  final_out_f32_k<<<EB,256,0,stream>>>(xw, f2out, mod, (float*)d_out);
}

// Round 9
// 934.711 us; speedup vs baseline: 1.1118x; 1.0054x over previous
//
#include <hip/hip_runtime.h>
#include <stdint.h>

typedef unsigned short u16;
typedef __bf16 bf16v8 __attribute__((ext_vector_type(8)));
typedef u16    u16v8  __attribute__((ext_vector_type(8)));
typedef float  f32x4  __attribute__((ext_vector_type(4)));
typedef float  f32x16 __attribute__((ext_vector_type(16)));
typedef int    i32x4  __attribute__((ext_vector_type(4)));
typedef int    i32x16 __attribute__((ext_vector_type(16)));

#define MFMA_BF16(a,b,c)    __builtin_amdgcn_mfma_f32_16x16x32_bf16((a),(b),(c),0,0,0)
#define MFMA_BF16_32(a,b,c) __builtin_amdgcn_mfma_f32_32x32x16_bf16((a),(b),(c),0,0,0)
#define MFMA_I8_32(a,b,c)   __builtin_amdgcn_mfma_i32_32x32x32_i8((a),(b),(c),0,0,0)

__device__ __forceinline__ float b2f(u16 u){ union{unsigned u;float f;}v; v.u=((unsigned)u)<<16; return v.f; }
__device__ __forceinline__ u16 f2b(float f){ union{float f;unsigned u;}v; v.f=f;
  return (u16)((v.u + 0x7fffu + ((v.u>>16)&1u))>>16); }
__device__ __forceinline__ bf16v8 ldv8(const u16* p){ return __builtin_bit_cast(bf16v8, *(const u16v8*)p); }
__device__ __forceinline__ void gl2lds16(const void* g, void* l){
  __builtin_amdgcn_global_load_lds(
    (const __attribute__((address_space(1))) unsigned int*)g,
    (__attribute__((address_space(3))) unsigned int*)l,
    16, 0, 0);
}
__device__ __forceinline__ float gelu_t(float x){
  float t = tanhf(0.7978845608028654f*(x + 0.044715f*x*x*x));
  return 0.5f*x*(1.0f+t);
}

// ---------------- elementwise / prep ----------------
__global__ void mod_add_k(const float* __restrict__ sst, const float* __restrict__ t, float* __restrict__ mod){
  int i = blockIdx.x*256 + threadIdx.x;
  if (i < 2*6*1152) mod[i] = sst[i % 6912] + t[i];
}
__global__ void conv_i8_k(const int* __restrict__ src, int8_t* __restrict__ dst, int n){
  int i = blockIdx.x*256 + threadIdx.x;
  if (i < n) dst[i] = (int8_t)src[i];
}
// f32 -> bf16 hi/lo planes
__global__ void split2_k(const float* __restrict__ src, u16* __restrict__ hi, u16* __restrict__ lo, int n){
  int i = blockIdx.x*256 + threadIdx.x;
  if (i >= n) return;
  float v = src[i];
  u16 hh = f2b(v);
  hi[i] = hh; lo[i] = f2b(v - b2f(hh));
}
// LN over C=1152 with modulation -> hi/lo bf16 planes
__global__ void ln_mod_split_k(const float* __restrict__ src, u16* __restrict__ xh, u16* __restrict__ xl,
                               const float* __restrict__ mod, int shift_row, int scale_row){
  const int row = blockIdx.x, tid = threadIdx.x;
  const int b = row >> 11;
  const float* ms = mod + ((size_t)b*6 + shift_row)*1152;
  const float* mc = mod + ((size_t)b*6 + scale_row)*1152;
  __shared__ float r1[256], r2[256];
  float s = 0.f, sq = 0.f, vals[5]; int cnt = 0;
  for (int c = tid; c < 1152; c += 256){
    float v = src[(size_t)row*1152+c];
    vals[cnt++] = v; s += v; sq += v*v;
  }
  r1[tid]=s; r2[tid]=sq; __syncthreads();
  for (int st=128; st>0; st>>=1){ if (tid<st){ r1[tid]+=r1[tid+st]; r2[tid]+=r2[tid+st]; } __syncthreads(); }
  float mean = r1[0]*(1.f/1152.f);
  float var  = r2[0]*(1.f/1152.f) - mean*mean;
  float rstd = rsqrtf(var + 1e-6f);
  cnt = 0;
  for (int c = tid; c < 1152; c += 256){
    float v = (vals[cnt++]-mean)*rstd*(1.f+mc[c]) + ms[c];
    u16 hh = f2b(v);
    xh[(size_t)row*1152+c] = hh;
    xl[(size_t)row*1152+c] = f2b(v - b2f(hh));
  }
}
// fused: xw = x + gate*ao, then per-row int8 quant of xw
__global__ void rgq_k(const float* __restrict__ x, const float* __restrict__ ao,
                      const float* __restrict__ mod, int gate_row, float* __restrict__ xw,
                      int8_t* __restrict__ q8, float* __restrict__ s_out, int* __restrict__ q_out){
  const int row = blockIdx.x, tid = threadIdx.x;
  const int b = row >> 11;
  const float* mg = mod + ((size_t)b*6 + gate_row)*1152;
  __shared__ float r1[256];
  __shared__ int ri[256];
  float mx = 0.f, vals[5]; int cnt = 0;
  for (int c = tid; c < 1152; c += 256){
    float v = x[(size_t)row*1152+c] + mg[c]*ao[(size_t)row*1152+c];
    xw[(size_t)row*1152+c] = v;
    vals[cnt++] = v; mx = fmaxf(mx, fabsf(v));
  }
  r1[tid]=mx; __syncthreads();
  for (int st=128; st>0; st>>=1){ if (tid<st) r1[tid]=fmaxf(r1[tid],r1[tid+st]); __syncthreads(); }
  const float s_ = fmaxf(r1[0]*(1.f/127.f), 1e-8f);
  const float inv = 1.f/s_;
  int acc = 0; cnt = 0;
  for (int c = tid; c < 1152; c += 256){
    float q = rintf(vals[cnt++]*inv);
    q = fminf(fmaxf(q, -127.f), 127.f);
    q8[(size_t)row*1152+c] = (int8_t)q;
    acc += (int)q;
  }
  ri[tid]=acc; __syncthreads();
  for (int st=128; st>0; st>>=1){ if (tid<st) ri[tid]+=ri[tid+st]; __syncthreads(); }
  if (tid==0){ s_out[row]=s_; q_out[row]=ri[0]; }
}
// fused: xw += add; LN+mod; per-row int8 quant
__global__ void rlq_k(float* __restrict__ xw, const float* __restrict__ add,
                      const float* __restrict__ mod, int shift_row, int scale_row,
                      int8_t* __restrict__ q8, float* __restrict__ s_out, int* __restrict__ q_out){
  const int row = blockIdx.x, tid = threadIdx.x;
  const int b = row >> 11;
  const float* ms = mod + ((size_t)b*6 + shift_row)*1152;
  const float* mc = mod + ((size_t)b*6 + scale_row)*1152;
  __shared__ float r1[256], r2[256];
  __shared__ int ri[256];
  float s = 0.f, sq = 0.f, vals[5]; int cnt = 0;
  for (int c = tid; c < 1152; c += 256){
    float v = xw[(size_t)row*1152+c] + add[(size_t)row*1152+c];
    xw[(size_t)row*1152+c] = v;
    vals[cnt++] = v; s += v; sq += v*v;
  }
  r1[tid]=s; r2[tid]=sq; __syncthreads();
  for (int st=128; st>0; st>>=1){ if (tid<st){ r1[tid]+=r1[tid+st]; r2[tid]+=r2[tid+st]; } __syncthreads(); }
  float mean = r1[0]*(1.f/1152.f);
  float var  = r2[0]*(1.f/1152.f) - mean*mean;
  float rstd = rsqrtf(var + 1e-6f);
  __syncthreads();
  float mx = 0.f; cnt = 0;
  for (int c = tid; c < 1152; c += 256){
    float v = (vals[cnt]-mean)*rstd*(1.f+mc[c]) + ms[c];
    vals[cnt++] = v; mx = fmaxf(mx, fabsf(v));
  }
  r1[tid]=mx; __syncthreads();
  for (int st=128; st>0; st>>=1){ if (tid<st) r1[tid]=fmaxf(r1[tid],r1[tid+st]); __syncthreads(); }
  const float s_ = fmaxf(r1[0]*(1.f/127.f), 1e-8f);
  const float inv = 1.f/s_;
  int acc = 0; cnt = 0;
  for (int c = tid; c < 1152; c += 256){
    float q = rintf(vals[cnt++]*inv);
    q = fminf(fmaxf(q, -127.f), 127.f);
    q8[(size_t)row*1152+c] = (int8_t)q;
    acc += (int)q;
  }
  ri[tid]=acc; __syncthreads();
  for (int st=128; st>0; st>>=1){ if (tid<st) ri[tid]+=ri[tid+st]; __syncthreads(); }
  if (tid==0){ s_out[row]=s_; q_out[row]=ri[0]; }
}
// register-cached row quant (C_ <= 4608)
template<int SRC_F32>
__global__ void quant_rows_k(const void* __restrict__ src, int C_,
                             int8_t* __restrict__ q8, float* __restrict__ s_out, int* __restrict__ q_out){
  const int row = blockIdx.x, tid = threadIdx.x;
  __shared__ float red[256];
  __shared__ int redi[256];
  float vals[18];
  float mx = 0.f; int cnt = 0;
  for (int c = tid; c < C_; c += 256){
    float v = SRC_F32 ? ((const float*)src)[(size_t)row*C_+c] : b2f(((const u16*)src)[(size_t)row*C_+c]);
    vals[cnt++] = v;
    mx = fmaxf(mx, fabsf(v));
  }
  red[tid]=mx; __syncthreads();
  for (int st=128; st>0; st>>=1){ if (tid<st) red[tid]=fmaxf(red[tid],red[tid+st]); __syncthreads(); }
  const float s_ = fmaxf(red[0]*(1.f/127.f), 1e-8f);
  const float inv = 1.f/s_;
  int acc = 0; cnt = 0;
  for (int c = tid; c < C_; c += 256){
    float q = rintf(vals[cnt++]*inv);
    q = fminf(fmaxf(q, -127.f), 127.f);
    q8[(size_t)row*C_+c] = (int8_t)q;
    acc += (int)q;
  }
  redi[tid]=acc; __syncthreads();
  for (int st=128; st>0; st>>=1){ if (tid<st) redi[tid]+=redi[tid+st]; __syncthreads(); }
  if (tid==0){ s_out[row]=s_; q_out[row]=redi[0]; }
}
__global__ void final_out_f32_k(const float* __restrict__ xw, const float* __restrict__ h,
                                const float* __restrict__ mod, float* __restrict__ out){
  size_t i = (size_t)blockIdx.x*256 + threadIdx.x;
  if (i >= (size_t)4096*1152) return;
  int c = (int)(i % 1152); int b = (int)((i/1152) >> 11);
  out[i] = xw[i] + mod[((size_t)b*6+5)*1152 + c] * h[i];
}
__global__ void build_vt_cross_k(const float* __restrict__ kv32, u16* __restrict__ vt){
  int h = blockIdx.x;
  u16* dst = vt + (size_t)h*80*448;
  const float* srcb = kv32 + 1152 + h*72;
  for (int idx = threadIdx.x; idx < 72*448; idx += 256){
    int d = idx/448, ss = idx - d*448;
    dst[d*448 + ss] = f2b(srcb[(size_t)ss*2304 + d]);
  }
}
__global__ void build_kv_split_k(const float* __restrict__ kv32, u16* __restrict__ khi, u16* __restrict__ klo){
  int i = blockIdx.x*256 + threadIdx.x;
  if (i >= 448*1152) return;
  int row = i / 1152, c = i - row*1152;
  float v = kv32[(size_t)row*2304 + c];
  u16 h16 = f2b(v);
  khi[i] = h16;
  klo[i] = f2b(v - b2f(h16));
}

// ------- high-precision GEMM on pre-split bf16 hi/lo planes, 32x32x16 MFMA -------
// out[M,N] = (Ah+Al)[M,K] @ (Wh+Wl)[N,K]^T + bias  (3-product MFMA, err ~2^-18)
// BK=32, XOR swizzle (phys chunk = logical ^ ((row>>1)&3)) -> conflict-free (R8: 0)
// C/D map (m74/m101 verified): col=lane&31, row=(reg&3)+8*(reg>>2)+4*(lane>>5)
template<int MODE>
__global__ __launch_bounds__(256,4) void gemm_hp2(
    const u16* __restrict__ Ah, const u16* __restrict__ Al, int lda,
    const u16* __restrict__ Wh, const u16* __restrict__ Wl, int ldw,
    const float* __restrict__ bias, float* __restrict__ out, int ldo, int M, int K,
    u16* __restrict__ qkh, u16* __restrict__ qkl, u16* __restrict__ vth){
  __shared__ u16 sAh[128*32];
  __shared__ u16 sAl[128*32];
  __shared__ u16 sWh[128*32];
  __shared__ u16 sWl[128*32];
  const int tid = threadIdx.x, lane = tid & 63;
  const int wv = tid >> 6, wx = wv & 1, wy = wv >> 1;
  const int l32 = lane & 31, g = lane >> 5;
  const int m0 = blockIdx.y*128, n0 = blockIdx.x*128;
  f32x16 acc[2][2];
  #pragma unroll
  for (int i=0;i<2;i++)
    #pragma unroll
    for (int j=0;j<2;j++)
      #pragma unroll
      for (int r=0;r<16;r++) acc[i][j][r] = 0.f;
  for (int k0=0; k0<K; k0+=32){
    #pragma unroll
    for (int r=0;r<2;r++){
      int slotbase = r*256 + wv*64;        // wave-uniform LDS base (slot*16B)
      int slot = slotbase + lane;
      int row = slot >> 2;                 // 4 chunks of 16B per 32-u16 row
      int col8 = ((slot ^ (row>>1)) & 3) * 8;  // phys chunk = logical ^ ((row>>1)&3)
      int gm = m0 + row; if (gm > M-1) gm = M-1;
      size_t aoff = (size_t)gm*lda + k0 + col8;
      size_t woff = (size_t)(n0+row)*ldw + k0 + col8;
      gl2lds16(Ah + aoff, &sAh[(size_t)slotbase*8]);
      gl2lds16(Al + aoff, &sAl[(size_t)slotbase*8]);
      gl2lds16(Wh + woff, &sWh[(size_t)slotbase*8]);
      gl2lds16(Wl + woff, &sWl[(size_t)slotbase*8]);
    }
    __syncthreads();
    #pragma unroll
    for (int kh=0; kh<2; kh++){
      bf16v8 ah[2], al[2], bh[2], bl[2];
      #pragma unroll
      for (int i=0;i<2;i++){
        int row = wy*64 + i*32 + l32;
        int cs = (((kh*2 + g) ^ ((row>>1)&3))) * 8;
        ah[i] = ldv8(&sAh[row*32 + cs]);
        al[i] = ldv8(&sAl[row*32 + cs]);
      }
      #pragma unroll
      for (int j=0;j<2;j++){
        int row = wx*64 + j*32 + l32;
        int cs = (((kh*2 + g) ^ ((row>>1)&3))) * 8;
        bh[j] = ldv8(&sWh[row*32 + cs]);
        bl[j] = ldv8(&sWl[row*32 + cs]);
      }
      #pragma unroll
      for (int i=0;i<2;i++)
        #pragma unroll
        for (int j=0;j<2;j++){
          acc[i][j] = MFMA_BF16_32(ah[i], bh[j], acc[i][j]);
          acc[i][j] = MFMA_BF16_32(ah[i], bl[j], acc[i][j]);
          acc[i][j] = MFMA_BF16_32(al[i], bh[j], acc[i][j]);
        }
    }
    __syncthreads();
  }
  #pragma unroll
  for (int j=0;j<2;j++){
    int col = n0 + wx*64 + j*32 + l32;
    float bc = bias ? bias[col] : 0.f;
    #pragma unroll
    for (int i=0;i<2;i++)
      #pragma unroll
      for (int r=0;r<16;r++){
        int row = m0 + wy*64 + i*32 + (r&3) + 8*(r>>2) + 4*g;
        if (row >= M) continue;
        float v = acc[i][j][r] + bc;
        if (MODE == 0){
          out[(size_t)row*ldo + col] = v;
        } else {
          if (col < 2304){
            u16 hh = f2b(v);
            qkh[(size_t)row*2304 + col] = hh;
            qkl[(size_t)row*2304 + col] = f2b(v - b2f(hh));
          } else {
            int vc = col - 2304;
            int hd_ = vc/72, d = vc - hd_*72;
            int z = row >> 8, s2 = row & 255;
            vth[((size_t)(z*16+hd_)*80 + d)*256 + s2] = f2b(v);
          }
        }
      }
  }
}

// ---------------- int8 GEMM, 32x32x32 MFMA, W8A8 epilogue (XOR-swizzled LDS) ----------------
__global__ __launch_bounds__(256,3) void gemm_i8(
    const int8_t* __restrict__ A, int lda, const int8_t* __restrict__ W, int ldw,
    const float* __restrict__ rs, const int* __restrict__ rq,
    const float* __restrict__ sw, const int* __restrict__ zw, const float* __restrict__ bias,
    void* __restrict__ out, int ldo, int M, int K, int do_gelu, int out_f32){
  __shared__ int8_t As[128*128];
  __shared__ int8_t Bs[128*128];
  const int tid = threadIdx.x, lane = tid & 63, wv = tid >> 6;
  const int wx = wv & 1, wy = wv >> 1;
  const int l32 = lane & 31, g = lane >> 5;
  const int m0 = blockIdx.y*128, n0 = blockIdx.x*128;
  const int srow = lane >> 3, schunk = lane & 7;
  const int scol = ((schunk ^ srow) & 7) * 16;   // XOR swizzle fetch column (128B rows)
  i32x16 acc[2][2];
  #pragma unroll
  for (int i=0;i<2;i++)
    #pragma unroll
    for (int j=0;j<2;j++)
      #pragma unroll
      for (int r=0;r<16;r++) acc[i][j][r] = 0;
  for (int k0 = 0; k0 < K; k0 += 128){
    #pragma unroll
    for (int i=0;i<4;i++){
      int rr = (i*4 + wv)*8;
      int gm = m0 + rr + srow; if (gm > M-1) gm = M-1;
      gl2lds16(A + (size_t)gm*lda + k0 + scol, &As[rr*128]);
      int gn = n0 + rr + srow;
      gl2lds16(W + (size_t)gn*ldw + k0 + scol, &Bs[rr*128]);
    }
    __syncthreads();
    #pragma unroll
    for (int kq=0; kq<4; kq++){
      i32x4 af[2], bw[2];
      #pragma unroll
      for (int i=0;i<2;i++){
        int row = wy*64 + i*32 + l32;
        int cs = (((kq*2 + g) ^ (row & 7))) * 16;
        af[i] = *(const i32x4*)&As[row*128 + cs];
      }
      #pragma unroll
      for (int j=0;j<2;j++){
        int row = wx*64 + j*32 + l32;
        int cs = (((kq*2 + g) ^ (row & 7))) * 16;
        bw[j] = *(const i32x4*)&Bs[row*128 + cs];
      }
      #pragma unroll
      for (int i=0;i<2;i++)
        #pragma unroll
        for (int j=0;j<2;j++)
          acc[i][j] = MFMA_I8_32(af[i], bw[j], acc[i][j]);
    }
    __syncthreads();
  }
  #pragma unroll
  for (int j=0;j<2;j++){
    int col = n0 + wx*64 + j*32 + l32;
    float swc = sw[col]; float zwc = (float)zw[col]; float bc = bias[col];
    #pragma unroll
    for (int i=0;i<2;i++)
      #pragma unroll
      for (int r=0;r<16;r++){
        int row = m0 + wy*64 + i*32 + (r&3) + 8*(r>>2) + 4*g;
        if (row < M){
          float v = ((float)acc[i][j][r] - (float)rq[row]*zwc) * (rs[row]*swc) + bc;
          if (do_gelu) v = gelu_t(v);
          if (out_f32) ((float*)out)[(size_t)row*ldo + col] = v;
          else         ((u16*)out)[(size_t)row*ldo + col] = f2b(v);
        }
      }
  }
}

// ---------------- self-attention, high precision ----------------
__global__ __launch_bounds__(256) void attn_self_hp(
    const u16* __restrict__ qkh, const u16* __restrict__ qkl,
    const u16* __restrict__ vth, u16* __restrict__ ohi, u16* __restrict__ olo, float scale){
  constexpr int NT = 16, PSTR = 264, VSTR = 256;
  __shared__ u16 PH[4*16*PSTR];
  __shared__ u16 PL[4*16*PSTR];
  const int tid = threadIdx.x, lane = tid & 63, wv = tid >> 6;
  const int quad = lane >> 4, l16 = lane & 15;
  const int h = blockIdx.y, z = blockIdx.z;
  const int qbase = z*256 + blockIdx.x*64;
  const int qc = h*72, kc = 1152 + h*72;
  const u16* Vth = vth + (size_t)(z*16+h)*80*VSTR;
  const bf16v8 zf = __builtin_bit_cast(bf16v8, (u16v8)0);
  const int mrow = qbase + wv*16 + l16;

  bf16v8 qh[3], ql[3];
  #pragma unroll
  for (int t=0;t<3;t++){
    if (t==2 && quad!=0){ qh[t]=zf; ql[t]=zf; }
    else {
      size_t off = (size_t)mrow*2304 + qc + t*32 + (t==2?0:quad*8);
      qh[t] = ldv8(qkh + off); ql[t] = ldv8(qkl + off);
    }
  }
  f32x4 sc[NT];
  #pragma unroll
  for (int nt=0; nt<NT; nt++){
    f32x4 a = {0.f,0.f,0.f,0.f};
    #pragma unroll
    for (int t=0;t<3;t++){
      bf16v8 kh = zf, kl = zf;
      if (!(t==2 && quad!=0)){
        size_t koff = (size_t)(z*256 + nt*16 + l16)*2304 + kc + t*32 + (t==2?0:quad*8);
        kh = ldv8(qkh + koff); kl = ldv8(qkl + koff);
      }
      a = MFMA_BF16(qh[t], kh, a);
      a = MFMA_BF16(qh[t], kl, a);
      a = MFMA_BF16(ql[t], kh, a);
    }
    sc[nt] = a;
  }
  float mx[4] = {-1e30f,-1e30f,-1e30f,-1e30f};
  #pragma unroll
  for (int nt=0; nt<NT; nt++)
    #pragma unroll
    for (int r=0;r<4;r++){ float v = sc[nt][r]*scale; sc[nt][r]=v; mx[r]=fmaxf(mx[r],v); }
  #pragma unroll
  for (int r=0;r<4;r++)
    for (int d=1; d<16; d<<=1) mx[r] = fmaxf(mx[r], __shfl_xor(mx[r], d, 64));
  float sm[4] = {0.f,0.f,0.f,0.f};
  #pragma unroll
  for (int nt=0; nt<NT; nt++)
    #pragma unroll
    for (int r=0;r<4;r++){ float p = __expf(sc[nt][r]-mx[r]); sc[nt][r]=p; sm[r]+=p; }
  #pragma unroll
  for (int r=0;r<4;r++){
    for (int d=1; d<16; d<<=1) sm[r] += __shfl_xor(sm[r], d, 64);
    sm[r] = 1.f/sm[r];
  }
  u16* Pwh = PH + wv*16*PSTR;
  u16* Pwl = PL + wv*16*PSTR;
  #pragma unroll
  for (int nt=0; nt<NT; nt++)
    #pragma unroll
    for (int r=0;r<4;r++){
      float p = sc[nt][r]*sm[r];
      u16 hi = f2b(p);
      Pwh[(quad*4+r)*PSTR + nt*16 + l16] = hi;
      Pwl[(quad*4+r)*PSTR + nt*16 + l16] = f2b(p - b2f(hi));
    }
  const u16* Prh = PH + wv*16*PSTR + (size_t)l16*PSTR;
  const u16* Prl = PL + wv*16*PSTR + (size_t)l16*PSTR;
  #pragma unroll
  for (int dt=0; dt<5; dt++){
    f32x4 o = {0.f,0.f,0.f,0.f};
    #pragma unroll
    for (int kk=0; kk<8; kk++){
      bf16v8 ph = ldv8(Prh + kk*32 + quad*8);
      bf16v8 pl = ldv8(Prl + kk*32 + quad*8);
      bf16v8 bv = ldv8(Vth + (size_t)(dt*16+l16)*VSTR + kk*32 + quad*8);
      o = MFMA_BF16(ph, bv, o);
      o = MFMA_BF16(pl, bv, o);
    }
    int d = dt*16 + l16;
    if (d < 72){
      #pragma unroll
      for (int r=0;r<4;r++){
        int row = qbase + wv*16 + quad*4 + r;
        size_t oi = (size_t)row*1152 + h*72 + d;
        u16 hh = f2b(o[r]);
        ohi[oi] = hh; olo[oi] = f2b(o[r] - b2f(hh));
      }
    }
  }
}

// ---------------- cross-attention, high-precision QK ----------------
__global__ __launch_bounds__(256) void attn_cross_hp(
    const float* __restrict__ Q32,
    const u16* __restrict__ Khi, const u16* __restrict__ Klo,
    const u16* __restrict__ Vt,                  // [h][80][448]
    float* __restrict__ O, float scale){
  constexpr int NT = 28, PSTR = 456, VSTR = 448;
  __shared__ u16 P[4*16*PSTR];
  const int tid = threadIdx.x, lane = tid & 63, wv = tid >> 6;
  const int quad = lane >> 4, l16 = lane & 15;
  const int h = blockIdx.y;
  const int qbase = blockIdx.x*64;
  const u16* Vth = Vt + (size_t)h*80*VSTR;
  const bf16v8 zf = __builtin_bit_cast(bf16v8, (u16v8)0);

  const int mrow = qbase + wv*16 + l16;
  const float* qp = Q32 + (size_t)mrow*1152 + h*72;
  bf16v8 qhi[3], qlo[3];
  #pragma unroll
  for (int t=0;t<3;t++){
    if (t==2 && quad!=0){ qhi[t]=zf; qlo[t]=zf; continue; }
    u16v8 hv, lv;
    #pragma unroll
    for (int j=0;j<8;j++){
      float v = qp[t*32 + (t==2?0:quad*8) + j];
      u16 h16 = f2b(v);
      hv[j] = h16; lv[j] = f2b(v - b2f(h16));
    }
    qhi[t] = __builtin_bit_cast(bf16v8, hv);
    qlo[t] = __builtin_bit_cast(bf16v8, lv);
  }
  f32x4 sc[NT];
  #pragma unroll
  for (int nt=0; nt<NT; nt++){
    f32x4 a = {0.f,0.f,0.f,0.f};
    #pragma unroll
    for (int t=0;t<3;t++){
      bf16v8 kh = zf, kl = zf;
      if (!(t==2 && quad!=0)){
        size_t koff = (size_t)(nt*16 + l16)*1152 + h*72 + t*32 + (t==2?0:quad*8);
        kh = ldv8(Khi + koff); kl = ldv8(Klo + koff);
      }
      a = MFMA_BF16(qhi[t], kh, a);
      a = MFMA_BF16(qhi[t], kl, a);
      a = MFMA_BF16(qlo[t], kh, a);
    }
    sc[nt] = a;
  }
  float mx[4] = {-1e30f,-1e30f,-1e30f,-1e30f};
  #pragma unroll
  for (int nt=0; nt<NT; nt++)
    #pragma unroll
    for (int r=0;r<4;r++){ float v = sc[nt][r]*scale; sc[nt][r]=v; mx[r]=fmaxf(mx[r],v); }
  #pragma unroll
  for (int r=0;r<4;r++)
    for (int d=1; d<16; d<<=1) mx[r] = fmaxf(mx[r], __shfl_xor(mx[r], d, 64));
  float sm[4] = {0.f,0.f,0.f,0.f};
  #pragma unroll
  for (int nt=0; nt<NT; nt++)
    #pragma unroll
    for (int r=0;r<4;r++){ float p = __expf(sc[nt][r]-mx[r]); sc[nt][r]=p; sm[r]+=p; }
  #pragma unroll
  for (int r=0;r<4;r++){
    for (int d=1; d<16; d<<=1) sm[r] += __shfl_xor(sm[r], d, 64);
    sm[r] = 1.f/sm[r];
  }
  u16* Pw = P + wv*16*PSTR;
  #pragma unroll
  for (int nt=0; nt<NT; nt++)
    #pragma unroll
    for (int r=0;r<4;r++)
      Pw[(quad*4+r)*PSTR + nt*16 + l16] = f2b(sc[nt][r]*sm[r]);
  const u16* Pr = P + wv*16*PSTR + (size_t)l16*PSTR;
  #pragma unroll
  for (int dt=0; dt<5; dt++){
    f32x4 o = {0.f,0.f,0.f,0.f};
    #pragma unroll
    for (int kk=0; kk<14; kk++){
      bf16v8 ap = ldv8(Pr + kk*32 + quad*8);
      bf16v8 bv = ldv8(Vth + (size_t)(dt*16+l16)*VSTR + kk*32 + quad*8);
      o = MFMA_BF16(ap, bv, o);
    }
    int d = dt*16 + l16;
    if (d < 72){
      #pragma unroll
      for (int r=0;r<4;r++){
        int row = qbase + wv*16 + quad*4 + r;
        O[(size_t)row*1152 + h*72 + d] = o[r];
      }
    }
  }
}

// ---------------- launch ----------------
extern "C" void kernel_launch(void* const* d_in, const int* in_sizes, int n_in,
                              void* d_out, int out_size, void* d_ws, size_t ws_size,
                              hipStream_t stream){
  const float* x    = (const float*)d_in[0];
  const float* y    = (const float*)d_in[1];
  const float* t    = (const float*)d_in[2];
  const float* sst  = (const float*)d_in[3];
  const float* Wqkv = (const float*)d_in[4];
  const float* bqkv = (const float*)d_in[5];
  const float* Wo   = (const float*)d_in[6];
  const float* bo   = (const float*)d_in[7];
  const float* Wkv  = (const float*)d_in[8];
  const float* bkv  = (const float*)d_in[9];
  const int*   qw_q  = (const int*)d_in[10];
  const float* sw_q  = (const float*)d_in[11];
  const int*   zw_q  = (const int*)d_in[12];
  const float* b_q   = (const float*)d_in[13];
  const int*   qw_cp = (const int*)d_in[14];
  const float* sw_cp = (const float*)d_in[15];
  const int*   zw_cp = (const int*)d_in[16];
  const float* b_cp  = (const float*)d_in[17];
  const int*   qw_f1 = (const int*)d_in[18];
  const float* sw_f1 = (const float*)d_in[19];
  const int*   zw_f1 = (const int*)d_in[20];
  const float* b_f1  = (const float*)d_in[21];
  const int*   qw_f2 = (const int*)d_in[22];
  const float* sw_f2 = (const float*)d_in[23];
  const int*   zw_f2 = (const int*)d_in[24];
  const float* b_f2  = (const float*)d_in[25];
  (void)in_sizes; (void)n_in; (void)out_size;

  // ---- workspace: 6 big regions, phase-disjoint aliasing (journal r5) ----
  constexpr size_t SZR = (size_t)4096*1152*4;        // 18,874,368
  constexpr size_t R0 = 0;                           // xw f32
  constexpr size_t R1 = R0 + SZR;                    // wqkv splits -> wkv/y splits -> q32/cp-out f32 -> q8h
  constexpr size_t R2 = R1 + SZR;                    // qkh -> wo-out/ao f32 -> hbuf(lo half) -> f2out f32
  constexpr size_t R3 = R2 + SZR;                    // qkl -> hbuf(hi half)
  constexpr size_t R4 = R3 + SZR;                    // xmh/ohi -> kv32+khi+klo+vtc -> w8f2   (9,437,184)
  constexpr size_t R5 = R4 + (size_t)9437184;        // xml/olo -> w8q,w8cp,w8f1              (9,437,184)
  constexpr size_t R6 = R5 + (size_t)9437184;        // vth -> woh/wol -> q8x                 (10,485,760)
  constexpr size_t RS = R6 + (size_t)10485760;
  constexpr size_t RQ = RS + (size_t)4096*4;
  constexpr size_t RM = RQ + (size_t)4096*4;
  constexpr size_t WS_NEED = RM + (size_t)2*6*1152*4;  // ~100.1 MB (proven ws >= 130 MB)
  if (ws_size < WS_NEED) return;

  char* ws = (char*)d_ws;
  float*  xw    = (float*)(ws + R0);
  u16*    wqkvh = (u16*)(ws + R1);
  u16*    wqkvl = (u16*)(ws + R1 + (size_t)3456*1152*2);
  u16*    wkvh  = (u16*)(ws + R1);
  u16*    wkvl  = (u16*)(ws + R1 + (size_t)2304*1152*2);
  u16*    yh    = (u16*)(ws + R1 + (size_t)2*2304*1152*2);
  u16*    yl    = (u16*)(ws + R1 + (size_t)2*2304*1152*2 + (size_t)448*1152*2);
  float*  q32   = (float*)(ws + R1);
  float*  cpout = (float*)(ws + R1);
  int8_t* q8h   = (int8_t*)(ws + R1);
  u16*    qkh   = (u16*)(ws + R2);
  float*  aof   = (float*)(ws + R2);   // wo-out, later cross-attn out
  u16*    hbuf  = (u16*)(ws + R2);     // 4096x4608 bf16 spans R2+R3
  float*  f2out = (float*)(ws + R2);
  u16*    qkl   = (u16*)(ws + R3);
  u16*    xmh   = (u16*)(ws + R4);
  u16*    ohi   = (u16*)(ws + R4);
  float*  kv32  = (float*)(ws + R4);
  u16*    khi   = (u16*)(ws + R4 + (size_t)4128768);
  u16*    klo   = (u16*)(ws + R4 + (size_t)5160960);
  u16*    vtc   = (u16*)(ws + R4 + (size_t)6193152);
  int8_t* w8f2  = (int8_t*)(ws + R4);
  u16*    xml   = (u16*)(ws + R5);
  u16*    olo   = (u16*)(ws + R5);
  int8_t* w8q   = (int8_t*)(ws + R5);
  int8_t* w8cp  = (int8_t*)(ws + R5 + (size_t)1327104);
  int8_t* w8f1  = (int8_t*)(ws + R5 + (size_t)2654208);
  u16*    vth   = (u16*)(ws + R6);
  u16*    woh   = (u16*)(ws + R6);
  u16*    wol   = (u16*)(ws + R6 + (size_t)1152*1152*2);
  int8_t* q8x   = (int8_t*)(ws + R6);
  float*  rs    = (float*)(ws + RS);
  int*    rq    = (int*)(ws + RQ);
  float*  mod   = (float*)(ws + RM);

  const float scale = 0.11785113019775793f; // 72^-0.5
  const int ETOT = 4096*1152, EB = (ETOT+255)/256;

  mod_add_k<<<(2*6*1152+255)/256,256,0,stream>>>(sst, t, mod);

  // ---- MSA branch (hp GEMMs on pre-split planes) ----
  ln_mod_split_k<<<4096,256,0,stream>>>(x, xmh, xml, mod, 0, 1);
  split2_k<<<(3456*1152+255)/256,256,0,stream>>>(Wqkv, wqkvh, wqkvl, 3456*1152);
  gemm_hp2<1><<<dim3(27,32),256,0,stream>>>(xmh,xml,1152, wqkvh,wqkvl,1152, bqkv, nullptr,0, 4096,1152, qkh,qkl,vth);
  attn_self_hp<<<dim3(4,16,16),256,0,stream>>>(qkh, qkl, vth, ohi, olo, scale);
  split2_k<<<(1152*1152+255)/256,256,0,stream>>>(Wo, woh, wol, 1152*1152);
  gemm_hp2<0><<<dim3(9,32),256,0,stream>>>(ohi,olo,1152, woh,wol,1152, bo, aof,1152, 4096,1152, nullptr,nullptr,nullptr);
  rgq_k<<<4096,256,0,stream>>>(x, aof, mod, 2, xw, q8x, rs, rq);

  // ---- cross-attn branch ----
  conv_i8_k<<<(1152*1152+255)/256,256,0,stream>>>(qw_q,  w8q,  1152*1152);
  conv_i8_k<<<(1152*1152+255)/256,256,0,stream>>>(qw_cp, w8cp, 1152*1152);
  split2_k<<<(2304*1152+255)/256,256,0,stream>>>(Wkv, wkvh, wkvl, 2304*1152);
  split2_k<<<(448*1152+255)/256,256,0,stream>>>(y, yh, yl, 448*1152);
  gemm_hp2<0><<<dim3(18,4),256,0,stream>>>(yh,yl,1152, wkvh,wkvl,1152, bkv, kv32,2304, 448,1152, nullptr,nullptr,nullptr);
  build_kv_split_k<<<(448*1152+255)/256,256,0,stream>>>(kv32, khi, klo);
  build_vt_cross_k<<<16,256,0,stream>>>(kv32, vtc);
  gemm_i8<<<dim3(9,32),256,0,stream>>>(q8x,1152, w8q,1152, rs,rq, sw_q,zw_q,b_q, q32,1152, 4096,1152, 0, 1);
  attn_cross_hp<<<dim3(64,16),256,0,stream>>>(q32, khi, klo, vtc, aof, scale);
  quant_rows_k<1><<<4096,256,0,stream>>>(aof, 1152, q8x, rs, rq);
  gemm_i8<<<dim3(9,32),256,0,stream>>>(q8x,1152, w8cp,1152, rs,rq, sw_cp,zw_cp,b_cp, cpout,1152, 4096,1152, 0, 1);

  // ---- MLP branch ----
  rlq_k<<<4096,256,0,stream>>>(xw, cpout, mod, 3, 4, q8x, rs, rq);
  conv_i8_k<<<(4608*1152+255)/256,256,0,stream>>>(qw_f1, w8f1, 4608*1152);
  gemm_i8<<<dim3(36,32),256,0,stream>>>(q8x,1152, w8f1,1152, rs,rq, sw_f1,zw_f1,b_f1, hbuf,4608, 4096,1152, 1, 0);
  quant_rows_k<0><<<4096,256,0,stream>>>(hbuf, 4608, q8h, rs, rq);
  conv_i8_k<<<(1152*4608+255)/256,256,0,stream>>>(qw_f2, w8f2, 1152*4608);
  gemm_i8<<<dim3(9,32),256,0,stream>>>(q8h,4608, w8f2,4608, rs,rq, sw_f2,zw_f2,b_f2, f2out,1152, 4096,4608, 0, 1);
  final_out_f32_k<<<EB,256,0,stream>>>(xw, f2out, mod, (float*)d_out);
}

// Round 10
// 927.496 us; speedup vs baseline: 1.1204x; 1.0078x over previous
//
#include <hip/hip_runtime.h>
#include <stdint.h>

typedef unsigned short u16;
typedef __bf16 bf16v8 __attribute__((ext_vector_type(8)));
typedef u16    u16v8  __attribute__((ext_vector_type(8)));
typedef float  f32x4  __attribute__((ext_vector_type(4)));
typedef int    i32x4  __attribute__((ext_vector_type(4)));
typedef int    i32x16 __attribute__((ext_vector_type(16)));

#define MFMA_BF16(a,b,c)  __builtin_amdgcn_mfma_f32_16x16x32_bf16((a),(b),(c),0,0,0)
#define MFMA_I8_32(a,b,c) __builtin_amdgcn_mfma_i32_32x32x32_i8((a),(b),(c),0,0,0)

__device__ __forceinline__ float b2f(u16 u){ union{unsigned u;float f;}v; v.u=((unsigned)u)<<16; return v.f; }
__device__ __forceinline__ u16 f2b(float f){ union{float f;unsigned u;}v; v.f=f;
  return (u16)((v.u + 0x7fffu + ((v.u>>16)&1u))>>16); }
__device__ __forceinline__ bf16v8 ldv8(const u16* p){ return __builtin_bit_cast(bf16v8, *(const u16v8*)p); }
__device__ __forceinline__ void gl2lds16(const void* g, void* l){
  __builtin_amdgcn_global_load_lds(
    (const __attribute__((address_space(1))) unsigned int*)g,
    (__attribute__((address_space(3))) unsigned int*)l,
    16, 0, 0);
}
__device__ __forceinline__ float gelu_t(float x){
  float t = tanhf(0.7978845608028654f*(x + 0.044715f*x*x*x));
  return 0.5f*x*(1.0f+t);
}

// ---------------- elementwise / prep ----------------
__global__ void mod_add_k(const float* __restrict__ sst, const float* __restrict__ t, float* __restrict__ mod){
  int i = blockIdx.x*256 + threadIdx.x;
  if (i < 2*6*1152) mod[i] = sst[i % 6912] + t[i];
}
// f32 -> bf16 hi/lo planes
__global__ void split2_k(const float* __restrict__ src, u16* __restrict__ hi, u16* __restrict__ lo, int n){
  int i = blockIdx.x*256 + threadIdx.x;
  if (i >= n) return;
  float v = src[i];
  u16 hh = f2b(v);
  hi[i] = hh; lo[i] = f2b(v - b2f(hh));
}
// fused cross-phase prep: conv qw_q, conv qw_cp, split Wkv, split y
__global__ void cross_prep_k(const int* __restrict__ qw_q, int8_t* __restrict__ w8q,
                             const int* __restrict__ qw_cp, int8_t* __restrict__ w8cp,
                             const float* __restrict__ Wkv, u16* __restrict__ wkvh, u16* __restrict__ wkvl,
                             const float* __restrict__ y, u16* __restrict__ yh, u16* __restrict__ yl){
  const int S1 = 1327104, S2 = 2654208, S3 = 5308416, S4 = 5824512;
  int i = blockIdx.x*256 + threadIdx.x;
  if (i < S1){ w8q[i] = (int8_t)qw_q[i]; }
  else if (i < S2){ int j = i - S1; w8cp[j] = (int8_t)qw_cp[j]; }
  else if (i < S3){ int j = i - S2; float v = Wkv[j]; u16 hh = f2b(v);
    wkvh[j] = hh; wkvl[j] = f2b(v - b2f(hh)); }
  else if (i < S4){ int j = i - S3; float v = y[j]; u16 hh = f2b(v);
    yh[j] = hh; yl[j] = f2b(v - b2f(hh)); }
}
// fused MLP-phase prep: conv qw_f1, conv qw_f2
__global__ void mlp_prep_k(const int* __restrict__ qw_f1, int8_t* __restrict__ w8f1,
                           const int* __restrict__ qw_f2, int8_t* __restrict__ w8f2){
  const int S1 = 5308416, S2 = 10616832;
  int i = blockIdx.x*256 + threadIdx.x;
  if (i < S1){ w8f1[i] = (int8_t)qw_f1[i]; }
  else if (i < S2){ int j = i - S1; w8f2[j] = (int8_t)qw_f2[j]; }
}
// LN over C=1152 with modulation -> hi/lo bf16 planes
__global__ void ln_mod_split_k(const float* __restrict__ src, u16* __restrict__ xh, u16* __restrict__ xl,
                               const float* __restrict__ mod, int shift_row, int scale_row){
  const int row = blockIdx.x, tid = threadIdx.x;
  const int b = row >> 11;
  const float* ms = mod + ((size_t)b*6 + shift_row)*1152;
  const float* mc = mod + ((size_t)b*6 + scale_row)*1152;
  __shared__ float r1[256], r2[256];
  float s = 0.f, sq = 0.f, vals[5]; int cnt = 0;
  for (int c = tid; c < 1152; c += 256){
    float v = src[(size_t)row*1152+c];
    vals[cnt++] = v; s += v; sq += v*v;
  }
  r1[tid]=s; r2[tid]=sq; __syncthreads();
  for (int st=128; st>0; st>>=1){ if (tid<st){ r1[tid]+=r1[tid+st]; r2[tid]+=r2[tid+st]; } __syncthreads(); }
  float mean = r1[0]*(1.f/1152.f);
  float var  = r2[0]*(1.f/1152.f) - mean*mean;
  float rstd = rsqrtf(var + 1e-6f);
  cnt = 0;
  for (int c = tid; c < 1152; c += 256){
    float v = (vals[cnt++]-mean)*rstd*(1.f+mc[c]) + ms[c];
    u16 hh = f2b(v);
    xh[(size_t)row*1152+c] = hh;
    xl[(size_t)row*1152+c] = f2b(v - b2f(hh));
  }
}
// fused: xw = x + gate*ao, then per-row int8 quant of xw
__global__ void rgq_k(const float* __restrict__ x, const float* __restrict__ ao,
                      const float* __restrict__ mod, int gate_row, float* __restrict__ xw,
                      int8_t* __restrict__ q8, float* __restrict__ s_out, int* __restrict__ q_out){
  const int row = blockIdx.x, tid = threadIdx.x;
  const int b = row >> 11;
  const float* mg = mod + ((size_t)b*6 + gate_row)*1152;
  __shared__ float r1[256];
  __shared__ int ri[256];
  float mx = 0.f, vals[5]; int cnt = 0;
  for (int c = tid; c < 1152; c += 256){
    float v = x[(size_t)row*1152+c] + mg[c]*ao[(size_t)row*1152+c];
    xw[(size_t)row*1152+c] = v;
    vals[cnt++] = v; mx = fmaxf(mx, fabsf(v));
  }
  r1[tid]=mx; __syncthreads();
  for (int st=128; st>0; st>>=1){ if (tid<st) r1[tid]=fmaxf(r1[tid],r1[tid+st]); __syncthreads(); }
  const float s_ = fmaxf(r1[0]*(1.f/127.f), 1e-8f);
  const float inv = 1.f/s_;
  int acc = 0; cnt = 0;
  for (int c = tid; c < 1152; c += 256){
    float q = rintf(vals[cnt++]*inv);
    q = fminf(fmaxf(q, -127.f), 127.f);
    q8[(size_t)row*1152+c] = (int8_t)q;
    acc += (int)q;
  }
  ri[tid]=acc; __syncthreads();
  for (int st=128; st>0; st>>=1){ if (tid<st) ri[tid]+=ri[tid+st]; __syncthreads(); }
  if (tid==0){ s_out[row]=s_; q_out[row]=ri[0]; }
}
// fused: xw += add; LN+mod; per-row int8 quant
__global__ void rlq_k(float* __restrict__ xw, const float* __restrict__ add,
                      const float* __restrict__ mod, int shift_row, int scale_row,
                      int8_t* __restrict__ q8, float* __restrict__ s_out, int* __restrict__ q_out){
  const int row = blockIdx.x, tid = threadIdx.x;
  const int b = row >> 11;
  const float* ms = mod + ((size_t)b*6 + shift_row)*1152;
  const float* mc = mod + ((size_t)b*6 + scale_row)*1152;
  __shared__ float r1[256], r2[256];
  __shared__ int ri[256];
  float s = 0.f, sq = 0.f, vals[5]; int cnt = 0;
  for (int c = tid; c < 1152; c += 256){
    float v = xw[(size_t)row*1152+c] + add[(size_t)row*1152+c];
    xw[(size_t)row*1152+c] = v;
    vals[cnt++] = v; s += v; sq += v*v;
  }
  r1[tid]=s; r2[tid]=sq; __syncthreads();
  for (int st=128; st>0; st>>=1){ if (tid<st){ r1[tid]+=r1[tid+st]; r2[tid]+=r2[tid+st]; } __syncthreads(); }
  float mean = r1[0]*(1.f/1152.f);
  float var  = r2[0]*(1.f/1152.f) - mean*mean;
  float rstd = rsqrtf(var + 1e-6f);
  __syncthreads();
  float mx = 0.f; cnt = 0;
  for (int c = tid; c < 1152; c += 256){
    float v = (vals[cnt]-mean)*rstd*(1.f+mc[c]) + ms[c];
    vals[cnt++] = v; mx = fmaxf(mx, fabsf(v));
  }
  r1[tid]=mx; __syncthreads();
  for (int st=128; st>0; st>>=1){ if (tid<st) r1[tid]=fmaxf(r1[tid],r1[tid+st]); __syncthreads(); }
  const float s_ = fmaxf(r1[0]*(1.f/127.f), 1e-8f);
  const float inv = 1.f/s_;
  int acc = 0; cnt = 0;
  for (int c = tid; c < 1152; c += 256){
    float q = rintf(vals[cnt++]*inv);
    q = fminf(fmaxf(q, -127.f), 127.f);
    q8[(size_t)row*1152+c] = (int8_t)q;
    acc += (int)q;
  }
  ri[tid]=acc; __syncthreads();
  for (int st=128; st>0; st>>=1){ if (tid<st) ri[tid]+=ri[tid+st]; __syncthreads(); }
  if (tid==0){ s_out[row]=s_; q_out[row]=ri[0]; }
}
// register-cached row quant (C_ <= 4608)
template<int SRC_F32>
__global__ void quant_rows_k(const void* __restrict__ src, int C_,
                             int8_t* __restrict__ q8, float* __restrict__ s_out, int* __restrict__ q_out){
  const int row = blockIdx.x, tid = threadIdx.x;
  __shared__ float red[256];
  __shared__ int redi[256];
  float vals[18];
  float mx = 0.f; int cnt = 0;
  for (int c = tid; c < C_; c += 256){
    float v = SRC_F32 ? ((const float*)src)[(size_t)row*C_+c] : b2f(((const u16*)src)[(size_t)row*C_+c]);
    vals[cnt++] = v;
    mx = fmaxf(mx, fabsf(v));
  }
  red[tid]=mx; __syncthreads();
  for (int st=128; st>0; st>>=1){ if (tid<st) red[tid]=fmaxf(red[tid],red[tid+st]); __syncthreads(); }
  const float s_ = fmaxf(red[0]*(1.f/127.f), 1e-8f);
  const float inv = 1.f/s_;
  int acc = 0; cnt = 0;
  for (int c = tid; c < C_; c += 256){
    float q = rintf(vals[cnt++]*inv);
    q = fminf(fmaxf(q, -127.f), 127.f);
    q8[(size_t)row*C_+c] = (int8_t)q;
    acc += (int)q;
  }
  redi[tid]=acc; __syncthreads();
  for (int st=128; st>0; st>>=1){ if (tid<st) redi[tid]+=redi[tid+st]; __syncthreads(); }
  if (tid==0){ s_out[row]=s_; q_out[row]=redi[0]; }
}

// ------- high-precision GEMM on pre-split bf16 hi/lo planes (R8 16x16, verified 0 conflicts) -------
// MODE 0: f32 out. MODE 1: QKV epilogue (qk hi/lo planes + V^T). MODE 2: KV epilogue (khi/klo + vtc)
template<int MODE>
__global__ __launch_bounds__(256,4) void gemm_hp2(
    const u16* __restrict__ Ah, const u16* __restrict__ Al, int lda,
    const u16* __restrict__ Wh, const u16* __restrict__ Wl, int ldw,
    const float* __restrict__ bias, float* __restrict__ out, int ldo, int M, int K,
    u16* __restrict__ qkh, u16* __restrict__ qkl, u16* __restrict__ vth){
  __shared__ u16 sAh[128*32];
  __shared__ u16 sAl[128*32];
  __shared__ u16 sWh[128*32];
  __shared__ u16 sWl[128*32];
  const int tid = threadIdx.x, lane = tid & 63;
  const int wv = tid >> 6, wx = wv & 1, wy = wv >> 1;
  const int quad = lane >> 4, l16 = lane & 15;
  const int m0 = blockIdx.y*128, n0 = blockIdx.x*128;
  f32x4 acc[4][4];
  #pragma unroll
  for (int i=0;i<4;i++)
    #pragma unroll
    for (int j=0;j<4;j++) acc[i][j] = (f32x4){0.f,0.f,0.f,0.f};
  for (int k0=0; k0<K; k0+=32){
    #pragma unroll
    for (int r=0;r<2;r++){
      int slotbase = r*256 + wv*64;        // wave-uniform LDS base (slot*16B)
      int slot = slotbase + lane;
      int row = slot >> 2;                 // 4 chunks of 16B per 32-u16 row
      int col8 = ((slot ^ (row>>1)) & 3) * 8;  // phys chunk = logical ^ ((row>>1)&3)
      int gm = m0 + row; if (gm > M-1) gm = M-1;
      size_t aoff = (size_t)gm*lda + k0 + col8;
      size_t woff = (size_t)(n0+row)*ldw + k0 + col8;
      gl2lds16(Ah + aoff, &sAh[(size_t)slotbase*8]);
      gl2lds16(Al + aoff, &sAl[(size_t)slotbase*8]);
      gl2lds16(Wh + woff, &sWh[(size_t)slotbase*8]);
      gl2lds16(Wl + woff, &sWl[(size_t)slotbase*8]);
    }
    __syncthreads();
    const int cs = ((quad ^ ((l16>>1)&3)) * 8);  // recovers logical chunk = quad
    bf16v8 ah[4], al[4], bh[4], bl[4];
    #pragma unroll
    for (int i=0;i<4;i++){
      ah[i] = ldv8(&sAh[(wy*64+i*16+l16)*32 + cs]);
      al[i] = ldv8(&sAl[(wy*64+i*16+l16)*32 + cs]);
    }
    #pragma unroll
    for (int j=0;j<4;j++){
      bh[j] = ldv8(&sWh[(wx*64+j*16+l16)*32 + cs]);
      bl[j] = ldv8(&sWl[(wx*64+j*16+l16)*32 + cs]);
    }
    #pragma unroll
    for (int i=0;i<4;i++)
      #pragma unroll
      for (int j=0;j<4;j++){
        acc[i][j] = MFMA_BF16(ah[i], bh[j], acc[i][j]);
        acc[i][j] = MFMA_BF16(ah[i], bl[j], acc[i][j]);
        acc[i][j] = MFMA_BF16(al[i], bh[j], acc[i][j]);
      }
    __syncthreads();
  }
  #pragma unroll
  for (int j=0;j<4;j++){
    int col = n0 + wx*64 + j*16 + l16;
    float bc = bias ? bias[col] : 0.f;
    #pragma unroll
    for (int i=0;i<4;i++)
      #pragma unroll
      for (int r=0;r<4;r++){
        int row = m0 + wy*64 + i*16 + quad*4 + r;
        if (row >= M) continue;
        float v = acc[i][j][r] + bc;
        if (MODE == 0){
          out[(size_t)row*ldo + col] = v;
        } else if (MODE == 1){
          if (col < 2304){
            u16 hh = f2b(v);
            qkh[(size_t)row*2304 + col] = hh;
            qkl[(size_t)row*2304 + col] = f2b(v - b2f(hh));
          } else {
            int vc = col - 2304;
            int hd_ = vc/72, d = vc - hd_*72;
            int z = row >> 8, s2 = row & 255;
            vth[((size_t)(z*16+hd_)*80 + d)*256 + s2] = f2b(v);
          }
        } else { // MODE 2: KV epilogue (448 rows): khi/klo planes + V^T [h][80][448]
          if (col < 1152){
            u16 hh = f2b(v);
            qkh[(size_t)row*1152 + col] = hh;
            qkl[(size_t)row*1152 + col] = f2b(v - b2f(hh));
          } else {
            int vc = col - 1152;
            int hd_ = vc/72, d = vc - hd_*72;
            vth[((size_t)hd_*80 + d)*448 + row] = f2b(v);
          }
        }
      }
  }
}

// ---------------- int8 GEMM, 32x32x32 MFMA, W8A8 epilogue (128B-row XOR swizzle) ----------------
__global__ __launch_bounds__(256,3) void gemm_i8(
    const int8_t* __restrict__ A, int lda, const int8_t* __restrict__ W, int ldw,
    const float* __restrict__ rs, const int* __restrict__ rq,
    const float* __restrict__ sw, const int* __restrict__ zw, const float* __restrict__ bias,
    void* __restrict__ out, int ldo, int M, int K, int do_gelu, int out_f32,
    const float* __restrict__ xwf, const float* __restrict__ modf, int do_final){
  __shared__ int8_t As[128*128];
  __shared__ int8_t Bs[128*128];
  const int tid = threadIdx.x, lane = tid & 63, wv = tid >> 6;
  const int wx = wv & 1, wy = wv >> 1;
  const int l32 = lane & 31, g = lane >> 5;
  const int m0 = blockIdx.y*128, n0 = blockIdx.x*128;
  const int srow = lane >> 3, schunk = lane & 7;
  const int scol = ((schunk ^ srow) & 7) * 16;   // XOR swizzle fetch column (128B rows)
  i32x16 acc[2][2];
  #pragma unroll
  for (int i=0;i<2;i++)
    #pragma unroll
    for (int j=0;j<2;j++)
      #pragma unroll
      for (int r=0;r<16;r++) acc[i][j][r] = 0;
  for (int k0 = 0; k0 < K; k0 += 128){
    #pragma unroll
    for (int i=0;i<4;i++){
      int rr = (i*4 + wv)*8;
      int gm = m0 + rr + srow; if (gm > M-1) gm = M-1;
      gl2lds16(A + (size_t)gm*lda + k0 + scol, &As[rr*128]);
      int gn = n0 + rr + srow;
      gl2lds16(W + (size_t)gn*ldw + k0 + scol, &Bs[rr*128]);
    }
    __syncthreads();
    #pragma unroll
    for (int kq=0; kq<4; kq++){
      i32x4 af[2], bw[2];
      #pragma unroll
      for (int i=0;i<2;i++){
        int row = wy*64 + i*32 + l32;
        int cs = (((kq*2 + g) ^ (row & 7))) * 16;
        af[i] = *(const i32x4*)&As[row*128 + cs];
      }
      #pragma unroll
      for (int j=0;j<2;j++){
        int row = wx*64 + j*32 + l32;
        int cs = (((kq*2 + g) ^ (row & 7))) * 16;
        bw[j] = *(const i32x4*)&Bs[row*128 + cs];
      }
      #pragma unroll
      for (int i=0;i<2;i++)
        #pragma unroll
        for (int j=0;j<2;j++)
          acc[i][j] = MFMA_I8_32(af[i], bw[j], acc[i][j]);
    }
    __syncthreads();
  }
  #pragma unroll
  for (int j=0;j<2;j++){
    int col = n0 + wx*64 + j*32 + l32;
    float swc = sw[col]; float zwc = (float)zw[col]; float bc = bias[col];
    #pragma unroll
    for (int i=0;i<2;i++)
      #pragma unroll
      for (int r=0;r<16;r++){
        int row = m0 + wy*64 + i*32 + (r&3) + 8*(r>>2) + 4*g;
        if (row < M){
          float v = ((float)acc[i][j][r] - (float)rq[row]*zwc) * (rs[row]*swc) + bc;
          if (do_gelu) v = gelu_t(v);
          if (do_final){
            int bb = row >> 11;
            float ov = xwf[(size_t)row*1152 + col] + modf[((size_t)bb*6+5)*1152 + col]*v;
            ((float*)out)[(size_t)row*ldo + col] = ov;
          } else if (out_f32) ((float*)out)[(size_t)row*ldo + col] = v;
          else                ((u16*)out)[(size_t)row*ldo + col] = f2b(v);
        }
      }
  }
}

// ---------------- self-attention, high precision ----------------
__global__ __launch_bounds__(256) void attn_self_hp(
    const u16* __restrict__ qkh, const u16* __restrict__ qkl,
    const u16* __restrict__ vth, u16* __restrict__ ohi, u16* __restrict__ olo, float scale){
  constexpr int NT = 16, PSTR = 264, VSTR = 256;
  __shared__ u16 PH[4*16*PSTR];
  __shared__ u16 PL[4*16*PSTR];
  const int tid = threadIdx.x, lane = tid & 63, wv = tid >> 6;
  const int quad = lane >> 4, l16 = lane & 15;
  const int h = blockIdx.y, z = blockIdx.z;
  const int qbase = z*256 + blockIdx.x*64;
  const int qc = h*72, kc = 1152 + h*72;
  const u16* Vth = vth + (size_t)(z*16+h)*80*VSTR;
  const bf16v8 zf = __builtin_bit_cast(bf16v8, (u16v8)0);
  const int mrow = qbase + wv*16 + l16;

  bf16v8 qh[3], ql[3];
  #pragma unroll
  for (int t=0;t<3;t++){
    if (t==2 && quad!=0){ qh[t]=zf; ql[t]=zf; }
    else {
      size_t off = (size_t)mrow*2304 + qc + t*32 + (t==2?0:quad*8);
      qh[t] = ldv8(qkh + off); ql[t] = ldv8(qkl + off);
    }
  }
  f32x4 sc[NT];
  #pragma unroll
  for (int nt=0; nt<NT; nt++){
    f32x4 a = {0.f,0.f,0.f,0.f};
    #pragma unroll
    for (int t=0;t<3;t++){
      bf16v8 kh = zf, kl = zf;
      if (!(t==2 && quad!=0)){
        size_t koff = (size_t)(z*256 + nt*16 + l16)*2304 + kc + t*32 + (t==2?0:quad*8);
        kh = ldv8(qkh + koff); kl = ldv8(qkl + koff);
      }
      a = MFMA_BF16(qh[t], kh, a);
      a = MFMA_BF16(qh[t], kl, a);
      a = MFMA_BF16(ql[t], kh, a);
    }
    sc[nt] = a;
  }
  float mx[4] = {-1e30f,-1e30f,-1e30f,-1e30f};
  #pragma unroll
  for (int nt=0; nt<NT; nt++)
    #pragma unroll
    for (int r=0;r<4;r++){ float v = sc[nt][r]*scale; sc[nt][r]=v; mx[r]=fmaxf(mx[r],v); }
  #pragma unroll
  for (int r=0;r<4;r++)
    for (int d=1; d<16; d<<=1) mx[r] = fmaxf(mx[r], __shfl_xor(mx[r], d, 64));
  float sm[4] = {0.f,0.f,0.f,0.f};
  #pragma unroll
  for (int nt=0; nt<NT; nt++)
    #pragma unroll
    for (int r=0;r<4;r++){ float p = __expf(sc[nt][r]-mx[r]); sc[nt][r]=p; sm[r]+=p; }
  #pragma unroll
  for (int r=0;r<4;r++){
    for (int d=1; d<16; d<<=1) sm[r] += __shfl_xor(sm[r], d, 64);
    sm[r] = 1.f/sm[r];
  }
  u16* Pwh = PH + wv*16*PSTR;
  u16* Pwl = PL + wv*16*PSTR;
  #pragma unroll
  for (int nt=0; nt<NT; nt++)
    #pragma unroll
    for (int r=0;r<4;r++){
      float p = sc[nt][r]*sm[r];
      u16 hi = f2b(p);
      Pwh[(quad*4+r)*PSTR + nt*16 + l16] = hi;
      Pwl[(quad*4+r)*PSTR + nt*16 + l16] = f2b(p - b2f(hi));
    }
  const u16* Prh = PH + wv*16*PSTR + (size_t)l16*PSTR;
  const u16* Prl = PL + wv*16*PSTR + (size_t)l16*PSTR;
  #pragma unroll
  for (int dt=0; dt<5; dt++){
    f32x4 o = {0.f,0.f,0.f,0.f};
    #pragma unroll
    for (int kk=0; kk<8; kk++){
      bf16v8 ph = ldv8(Prh + kk*32 + quad*8);
      bf16v8 pl = ldv8(Prl + kk*32 + quad*8);
      bf16v8 bv = ldv8(Vth + (size_t)(dt*16+l16)*VSTR + kk*32 + quad*8);
      o = MFMA_BF16(ph, bv, o);
      o = MFMA_BF16(pl, bv, o);
    }
    int d = dt*16 + l16;
    if (d < 72){
      #pragma unroll
      for (int r=0;r<4;r++){
        int row = qbase + wv*16 + quad*4 + r;
        size_t oi = (size_t)row*1152 + h*72 + d;
        u16 hh = f2b(o[r]);
        ohi[oi] = hh; olo[oi] = f2b(o[r] - b2f(hh));
      }
    }
  }
}

// ---------------- cross-attention, high-precision QK ----------------
__global__ __launch_bounds__(256) void attn_cross_hp(
    const float* __restrict__ Q32,
    const u16* __restrict__ Khi, const u16* __restrict__ Klo,
    const u16* __restrict__ Vt,                  // [h][80][448]
    float* __restrict__ O, float scale){
  constexpr int NT = 28, PSTR = 456, VSTR = 448;
  __shared__ u16 P[4*16*PSTR];
  const int tid = threadIdx.x, lane = tid & 63, wv = tid >> 6;
  const int quad = lane >> 4, l16 = lane & 15;
  const int h = blockIdx.y;
  const int qbase = blockIdx.x*64;
  const u16* Vth = Vt + (size_t)h*80*VSTR;
  const bf16v8 zf = __builtin_bit_cast(bf16v8, (u16v8)0);

  const int mrow = qbase + wv*16 + l16;
  const float* qp = Q32 + (size_t)mrow*1152 + h*72;
  bf16v8 qhi[3], qlo[3];
  #pragma unroll
  for (int t=0;t<3;t++){
    if (t==2 && quad!=0){ qhi[t]=zf; qlo[t]=zf; continue; }
    u16v8 hv, lv;
    #pragma unroll
    for (int j=0;j<8;j++){
      float v = qp[t*32 + (t==2?0:quad*8) + j];
      u16 h16 = f2b(v);
      hv[j] = h16; lv[j] = f2b(v - b2f(h16));
    }
    qhi[t] = __builtin_bit_cast(bf16v8, hv);
    qlo[t] = __builtin_bit_cast(bf16v8, lv);
  }
  f32x4 sc[NT];
  #pragma unroll
  for (int nt=0; nt<NT; nt++){
    f32x4 a = {0.f,0.f,0.f,0.f};
    #pragma unroll
    for (int t=0;t<3;t++){
      bf16v8 kh = zf, kl = zf;
      if (!(t==2 && quad!=0)){
        size_t koff = (size_t)(nt*16 + l16)*1152 + h*72 + t*32 + (t==2?0:quad*8);
        kh = ldv8(Khi + koff); kl = ldv8(Klo + koff);
      }
      a = MFMA_BF16(qhi[t], kh, a);
      a = MFMA_BF16(qhi[t], kl, a);
      a = MFMA_BF16(qlo[t], kh, a);
    }
    sc[nt] = a;
  }
  float mx[4] = {-1e30f,-1e30f,-1e30f,-1e30f};
  #pragma unroll
  for (int nt=0; nt<NT; nt++)
    #pragma unroll
    for (int r=0;r<4;r++){ float v = sc[nt][r]*scale; sc[nt][r]=v; mx[r]=fmaxf(mx[r],v); }
  #pragma unroll
  for (int r=0;r<4;r++)
    for (int d=1; d<16; d<<=1) mx[r] = fmaxf(mx[r], __shfl_xor(mx[r], d, 64));
  float sm[4] = {0.f,0.f,0.f,0.f};
  #pragma unroll
  for (int nt=0; nt<NT; nt++)
    #pragma unroll
    for (int r=0;r<4;r++){ float p = __expf(sc[nt][r]-mx[r]); sc[nt][r]=p; sm[r]+=p; }
  #pragma unroll
  for (int r=0;r<4;r++){
    for (int d=1; d<16; d<<=1) sm[r] += __shfl_xor(sm[r], d, 64);
    sm[r] = 1.f/sm[r];
  }
  u16* Pw = P + wv*16*PSTR;
  #pragma unroll
  for (int nt=0; nt<NT; nt++)
    #pragma unroll
    for (int r=0;r<4;r++)
      Pw[(quad*4+r)*PSTR + nt*16 + l16] = f2b(sc[nt][r]*sm[r]);
  const u16* Pr = P + wv*16*PSTR + (size_t)l16*PSTR;
  #pragma unroll
  for (int dt=0; dt<5; dt++){
    f32x4 o = {0.f,0.f,0.f,0.f};
    #pragma unroll
    for (int kk=0; kk<14; kk++){
      bf16v8 ap = ldv8(Pr + kk*32 + quad*8);
      bf16v8 bv = ldv8(Vth + (size_t)(dt*16+l16)*VSTR + kk*32 + quad*8);
      o = MFMA_BF16(ap, bv, o);
    }
    int d = dt*16 + l16;
    if (d < 72){
      #pragma unroll
      for (int r=0;r<4;r++){
        int row = qbase + wv*16 + quad*4 + r;
        O[(size_t)row*1152 + h*72 + d] = o[r];
      }
    }
  }
}

// ---------------- launch ----------------
extern "C" void kernel_launch(void* const* d_in, const int* in_sizes, int n_in,
                              void* d_out, int out_size, void* d_ws, size_t ws_size,
                              hipStream_t stream){
  const float* x    = (const float*)d_in[0];
  const float* y    = (const float*)d_in[1];
  const float* t    = (const float*)d_in[2];
  const float* sst  = (const float*)d_in[3];
  const float* Wqkv = (const float*)d_in[4];
  const float* bqkv = (const float*)d_in[5];
  const float* Wo   = (const float*)d_in[6];
  const float* bo   = (const float*)d_in[7];
  const float* Wkv  = (const float*)d_in[8];
  const float* bkv  = (const float*)d_in[9];
  const int*   qw_q  = (const int*)d_in[10];
  const float* sw_q  = (const float*)d_in[11];
  const int*   zw_q  = (const int*)d_in[12];
  const float* b_q   = (const float*)d_in[13];
  const int*   qw_cp = (const int*)d_in[14];
  const float* sw_cp = (const float*)d_in[15];
  const int*   zw_cp = (const int*)d_in[16];
  const float* b_cp  = (const float*)d_in[17];
  const int*   qw_f1 = (const int*)d_in[18];
  const float* sw_f1 = (const float*)d_in[19];
  const int*   zw_f1 = (const int*)d_in[20];
  const float* b_f1  = (const float*)d_in[21];
  const int*   qw_f2 = (const int*)d_in[22];
  const float* sw_f2 = (const float*)d_in[23];
  const int*   zw_f2 = (const int*)d_in[24];
  const float* b_f2  = (const float*)d_in[25];
  (void)in_sizes; (void)n_in; (void)out_size;

  constexpr size_t SZR = (size_t)4096*1152*4;        // 18,874,368
  constexpr size_t R0 = 0;                           // xw f32
  constexpr size_t R1 = R0 + SZR;                    // wqkv splits -> wkv/y splits -> q32 -> cpout -> q8h
  constexpr size_t R2 = R1 + SZR;                    // qkh -> aof f32 -> hbuf(part)
  constexpr size_t R3 = R2 + SZR;                    // qkl -> hbuf(part)
  constexpr size_t R4 = R3 + SZR;                    // xmh/ohi -> khi+klo+vtc -> w8f2
  constexpr size_t R5 = R4 + (size_t)9437184;        // xml/olo -> w8q,w8cp,w8f1
  constexpr size_t R6 = R5 + (size_t)9437184;        // vth -> woh/wol -> q8x
  constexpr size_t RS = R6 + (size_t)10485760;
  constexpr size_t RQ = RS + (size_t)4096*4;
  constexpr size_t RM = RQ + (size_t)4096*4;
  constexpr size_t WS_NEED = RM + (size_t)2*6*1152*4;  // ~100.1 MB (proven ws >= 121.8 MB)
  if (ws_size < WS_NEED) return;

  char* ws = (char*)d_ws;
  float*  xw    = (float*)(ws + R0);
  u16*    wqkvh = (u16*)(ws + R1);
  u16*    wqkvl = (u16*)(ws + R1 + (size_t)3456*1152*2);
  u16*    wkvh  = (u16*)(ws + R1);
  u16*    wkvl  = (u16*)(ws + R1 + (size_t)2304*1152*2);
  u16*    yh    = (u16*)(ws + R1 + (size_t)2*2304*1152*2);
  u16*    yl    = (u16*)(ws + R1 + (size_t)2*2304*1152*2 + (size_t)448*1152*2);
  float*  q32   = (float*)(ws + R1);
  float*  cpout = (float*)(ws + R1);
  int8_t* q8h   = (int8_t*)(ws + R1);
  u16*    qkh   = (u16*)(ws + R2);
  float*  aof   = (float*)(ws + R2);   // wo-out, later cross-attn out
  u16*    hbuf  = (u16*)(ws + R2);     // 4096x4608 bf16 spans R2+R3
  u16*    qkl   = (u16*)(ws + R3);
  u16*    xmh   = (u16*)(ws + R4);
  u16*    ohi   = (u16*)(ws + R4);
  u16*    khi   = (u16*)(ws + R4 + (size_t)4128768);
  u16*    klo   = (u16*)(ws + R4 + (size_t)5160960);
  u16*    vtc   = (u16*)(ws + R4 + (size_t)6193152);
  int8_t* w8f2  = (int8_t*)(ws + R4);
  u16*    xml   = (u16*)(ws + R5);
  u16*    olo   = (u16*)(ws + R5);
  int8_t* w8q   = (int8_t*)(ws + R5);
  int8_t* w8cp  = (int8_t*)(ws + R5 + (size_t)1327104);
  int8_t* w8f1  = (int8_t*)(ws + R5 + (size_t)2654208);
  u16*    vth   = (u16*)(ws + R6);
  u16*    woh   = (u16*)(ws + R6);
  u16*    wol   = (u16*)(ws + R6 + (size_t)1152*1152*2);
  int8_t* q8x   = (int8_t*)(ws + R6);
  float*  rs    = (float*)(ws + RS);
  int*    rq    = (int*)(ws + RQ);
  float*  mod   = (float*)(ws + RM);

  const float scale = 0.11785113019775793f; // 72^-0.5

  mod_add_k<<<(2*6*1152+255)/256,256,0,stream>>>(sst, t, mod);

  // ---- MSA branch (hp GEMMs on pre-split planes) ----
  ln_mod_split_k<<<4096,256,0,stream>>>(x, xmh, xml, mod, 0, 1);
  split2_k<<<(3456*1152+255)/256,256,0,stream>>>(Wqkv, wqkvh, wqkvl, 3456*1152);
  gemm_hp2<1><<<dim3(27,32),256,0,stream>>>(xmh,xml,1152, wqkvh,wqkvl,1152, bqkv, nullptr,0, 4096,1152, qkh,qkl,vth);
  attn_self_hp<<<dim3(4,16,16),256,0,stream>>>(qkh, qkl, vth, ohi, olo, scale);
  split2_k<<<(1152*1152+255)/256,256,0,stream>>>(Wo, woh, wol, 1152*1152);
  gemm_hp2<0><<<dim3(9,32),256,0,stream>>>(ohi,olo,1152, woh,wol,1152, bo, aof,1152, 4096,1152, nullptr,nullptr,nullptr);
  rgq_k<<<4096,256,0,stream>>>(x, aof, mod, 2, xw, q8x, rs, rq);

  // ---- cross-attn branch ----
  cross_prep_k<<<(5824512+255)/256,256,0,stream>>>(qw_q,w8q, qw_cp,w8cp, Wkv,wkvh,wkvl, y,yh,yl);
  gemm_hp2<2><<<dim3(18,4),256,0,stream>>>(yh,yl,1152, wkvh,wkvl,1152, bkv, nullptr,0, 448,1152, khi,klo,vtc);
  gemm_i8<<<dim3(9,32),256,0,stream>>>(q8x,1152, w8q,1152, rs,rq, sw_q,zw_q,b_q, q32,1152, 4096,1152, 0, 1, nullptr,nullptr,0);
  attn_cross_hp<<<dim3(64,16),256,0,stream>>>(q32, khi, klo, vtc, aof, scale);
  quant_rows_k<1><<<4096,256,0,stream>>>(aof, 1152, q8x, rs, rq);
  gemm_i8<<<dim3(9,32),256,0,stream>>>(q8x,1152, w8cp,1152, rs,rq, sw_cp,zw_cp,b_cp, cpout,1152, 4096,1152, 0, 1, nullptr,nullptr,0);

  // ---- MLP branch ----
  rlq_k<<<4096,256,0,stream>>>(xw, cpout, mod, 3, 4, q8x, rs, rq);
  mlp_prep_k<<<(10616832+255)/256,256,0,stream>>>(qw_f1, w8f1, qw_f2, w8f2);
  gemm_i8<<<dim3(36,32),256,0,stream>>>(q8x,1152, w8f1,1152, rs,rq, sw_f1,zw_f1,b_f1, hbuf,4608, 4096,1152, 1, 0, nullptr,nullptr,0);
  quant_rows_k<0><<<4096,256,0,stream>>>(hbuf, 4608, q8h, rs, rq);
  gemm_i8<<<dim3(9,32),256,0,stream>>>(q8h,4608, w8f2,4608, rs,rq, sw_f2,zw_f2,b_f2, d_out,1152, 4096,4608, 0, 1, xw,mod,1);
}

// Round 11
// 813.574 us; speedup vs baseline: 1.2773x; 1.1400x over previous
//
#include <hip/hip_runtime.h>
#include <stdint.h>

typedef unsigned short u16;
typedef _Float16 f16;
typedef f16    f16v8  __attribute__((ext_vector_type(8)));
typedef u16    u16v8  __attribute__((ext_vector_type(8)));
typedef float  f32x4  __attribute__((ext_vector_type(4)));
typedef int    i32x4  __attribute__((ext_vector_type(4)));
typedef int    i32x16 __attribute__((ext_vector_type(16)));

#define MFMA_F16(a,b,c)   __builtin_amdgcn_mfma_f32_16x16x32_f16((a),(b),(c),0,0,0)
#define MFMA_I8_32(a,b,c) __builtin_amdgcn_mfma_i32_32x32x32_i8((a),(b),(c),0,0,0)

__device__ __forceinline__ float b2f(u16 u){ union{unsigned u;float f;}v; v.u=((unsigned)u)<<16; return v.f; }
__device__ __forceinline__ u16 f2b(float f){ union{float f;unsigned u;}v; v.f=f;
  return (u16)((v.u + 0x7fffu + ((v.u>>16)&1u))>>16); }
__device__ __forceinline__ u16 f2h(float f){ f16 h = (f16)f; return __builtin_bit_cast(u16, h); }
__device__ __forceinline__ float h2f(u16 u){ return (float)__builtin_bit_cast(f16, u); }
__device__ __forceinline__ f16v8 ldh8(const u16* p){ return __builtin_bit_cast(f16v8, *(const u16v8*)p); }
__device__ __forceinline__ void gl2lds16(const void* g, void* l){
  __builtin_amdgcn_global_load_lds(
    (const __attribute__((address_space(1))) unsigned int*)g,
    (__attribute__((address_space(3))) unsigned int*)l,
    16, 0, 0);
}
__device__ __forceinline__ float gelu_t(float x){
  float t = tanhf(0.7978845608028654f*(x + 0.044715f*x*x*x));
  return 0.5f*x*(1.0f+t);
}

// ---------------- elementwise / prep ----------------
__global__ void mod_add_k(const float* __restrict__ sst, const float* __restrict__ t, float* __restrict__ mod){
  int i = blockIdx.x*256 + threadIdx.x;
  if (i < 2*6*1152) mod[i] = sst[i % 6912] + t[i];
}
// f32 -> f16 hi/lo planes (weights)
__global__ void split2h_k(const float* __restrict__ src, u16* __restrict__ hi, u16* __restrict__ lo, int n){
  int i = blockIdx.x*256 + threadIdx.x;
  if (i >= n) return;
  float v = src[i];
  f16 h = (f16)v;
  hi[i] = __builtin_bit_cast(u16, h);
  lo[i] = f2h(v - (float)h);
}
// fused cross-phase prep: conv qw_q, conv qw_cp, split Wkv (f16 hi/lo), y (f16 single)
__global__ void cross_prep_k(const int* __restrict__ qw_q, int8_t* __restrict__ w8q,
                             const int* __restrict__ qw_cp, int8_t* __restrict__ w8cp,
                             const float* __restrict__ Wkv, u16* __restrict__ wkvh, u16* __restrict__ wkvl,
                             const float* __restrict__ y, u16* __restrict__ yf){
  const int S1 = 1327104, S2 = 2654208, S3 = 5308416, S4 = 5824512;
  int i = blockIdx.x*256 + threadIdx.x;
  if (i < S1){ w8q[i] = (int8_t)qw_q[i]; }
  else if (i < S2){ int j = i - S1; w8cp[j] = (int8_t)qw_cp[j]; }
  else if (i < S3){ int j = i - S2; float v = Wkv[j]; f16 h = (f16)v;
    wkvh[j] = __builtin_bit_cast(u16, h); wkvl[j] = f2h(v - (float)h); }
  else if (i < S4){ int j = i - S3; yf[j] = f2h(y[j]); }
}
// fused MLP-phase prep: conv qw_f1, conv qw_f2
__global__ void mlp_prep_k(const int* __restrict__ qw_f1, int8_t* __restrict__ w8f1,
                           const int* __restrict__ qw_f2, int8_t* __restrict__ w8f2){
  const int S1 = 5308416, S2 = 10616832;
  int i = blockIdx.x*256 + threadIdx.x;
  if (i < S1){ w8f1[i] = (int8_t)qw_f1[i]; }
  else if (i < S2){ int j = i - S1; w8f2[j] = (int8_t)qw_f2[j]; }
}
// LN over C=1152 with modulation -> single f16 plane
__global__ void ln_mod_f16_k(const float* __restrict__ src, u16* __restrict__ xf,
                             const float* __restrict__ mod, int shift_row, int scale_row){
  const int row = blockIdx.x, tid = threadIdx.x;
  const int b = row >> 11;
  const float* ms = mod + ((size_t)b*6 + shift_row)*1152;
  const float* mc = mod + ((size_t)b*6 + scale_row)*1152;
  __shared__ float r1[256], r2[256];
  float s = 0.f, sq = 0.f, vals[5]; int cnt = 0;
  for (int c = tid; c < 1152; c += 256){
    float v = src[(size_t)row*1152+c];
    vals[cnt++] = v; s += v; sq += v*v;
  }
  r1[tid]=s; r2[tid]=sq; __syncthreads();
  for (int st=128; st>0; st>>=1){ if (tid<st){ r1[tid]+=r1[tid+st]; r2[tid]+=r2[tid+st]; } __syncthreads(); }
  float mean = r1[0]*(1.f/1152.f);
  float var  = r2[0]*(1.f/1152.f) - mean*mean;
  float rstd = rsqrtf(var + 1e-6f);
  cnt = 0;
  for (int c = tid; c < 1152; c += 256){
    float v = (vals[cnt++]-mean)*rstd*(1.f+mc[c]) + ms[c];
    xf[(size_t)row*1152+c] = f2h(v);
  }
}
// fused: xw = x + gate*ao, then per-row int8 quant of xw
__global__ void rgq_k(const float* __restrict__ x, const float* __restrict__ ao,
                      const float* __restrict__ mod, int gate_row, float* __restrict__ xw,
                      int8_t* __restrict__ q8, float* __restrict__ s_out, int* __restrict__ q_out){
  const int row = blockIdx.x, tid = threadIdx.x;
  const int b = row >> 11;
  const float* mg = mod + ((size_t)b*6 + gate_row)*1152;
  __shared__ float r1[256];
  __shared__ int ri[256];
  float mx = 0.f, vals[5]; int cnt = 0;
  for (int c = tid; c < 1152; c += 256){
    float v = x[(size_t)row*1152+c] + mg[c]*ao[(size_t)row*1152+c];
    xw[(size_t)row*1152+c] = v;
    vals[cnt++] = v; mx = fmaxf(mx, fabsf(v));
  }
  r1[tid]=mx; __syncthreads();
  for (int st=128; st>0; st>>=1){ if (tid<st) r1[tid]=fmaxf(r1[tid],r1[tid+st]); __syncthreads(); }
  const float s_ = fmaxf(r1[0]*(1.f/127.f), 1e-8f);
  const float inv = 1.f/s_;
  int acc = 0; cnt = 0;
  for (int c = tid; c < 1152; c += 256){
    float q = rintf(vals[cnt++]*inv);
    q = fminf(fmaxf(q, -127.f), 127.f);
    q8[(size_t)row*1152+c] = (int8_t)q;
    acc += (int)q;
  }
  ri[tid]=acc; __syncthreads();
  for (int st=128; st>0; st>>=1){ if (tid<st) ri[tid]+=ri[tid+st]; __syncthreads(); }
  if (tid==0){ s_out[row]=s_; q_out[row]=ri[0]; }
}
// fused: xw += add; LN+mod; per-row int8 quant
__global__ void rlq_k(float* __restrict__ xw, const float* __restrict__ add,
                      const float* __restrict__ mod, int shift_row, int scale_row,
                      int8_t* __restrict__ q8, float* __restrict__ s_out, int* __restrict__ q_out){
  const int row = blockIdx.x, tid = threadIdx.x;
  const int b = row >> 11;
  const float* ms = mod + ((size_t)b*6 + shift_row)*1152;
  const float* mc = mod + ((size_t)b*6 + scale_row)*1152;
  __shared__ float r1[256], r2[256];
  __shared__ int ri[256];
  float s = 0.f, sq = 0.f, vals[5]; int cnt = 0;
  for (int c = tid; c < 1152; c += 256){
    float v = xw[(size_t)row*1152+c] + add[(size_t)row*1152+c];
    xw[(size_t)row*1152+c] = v;
    vals[cnt++] = v; s += v; sq += v*v;
  }
  r1[tid]=s; r2[tid]=sq; __syncthreads();
  for (int st=128; st>0; st>>=1){ if (tid<st){ r1[tid]+=r1[tid+st]; r2[tid]+=r2[tid+st]; } __syncthreads(); }
  float mean = r1[0]*(1.f/1152.f);
  float var  = r2[0]*(1.f/1152.f) - mean*mean;
  float rstd = rsqrtf(var + 1e-6f);
  __syncthreads();
  float mx = 0.f; cnt = 0;
  for (int c = tid; c < 1152; c += 256){
    float v = (vals[cnt]-mean)*rstd*(1.f+mc[c]) + ms[c];
    vals[cnt++] = v; mx = fmaxf(mx, fabsf(v));
  }
  r1[tid]=mx; __syncthreads();
  for (int st=128; st>0; st>>=1){ if (tid<st) r1[tid]=fmaxf(r1[tid],r1[tid+st]); __syncthreads(); }
  const float s_ = fmaxf(r1[0]*(1.f/127.f), 1e-8f);
  const float inv = 1.f/s_;
  int acc = 0; cnt = 0;
  for (int c = tid; c < 1152; c += 256){
    float q = rintf(vals[cnt++]*inv);
    q = fminf(fmaxf(q, -127.f), 127.f);
    q8[(size_t)row*1152+c] = (int8_t)q;
    acc += (int)q;
  }
  ri[tid]=acc; __syncthreads();
  for (int st=128; st>0; st>>=1){ if (tid<st) ri[tid]+=ri[tid+st]; __syncthreads(); }
  if (tid==0){ s_out[row]=s_; q_out[row]=ri[0]; }
}
// register-cached row quant (C_ <= 4608)
template<int SRC_F32>
__global__ void quant_rows_k(const void* __restrict__ src, int C_,
                             int8_t* __restrict__ q8, float* __restrict__ s_out, int* __restrict__ q_out){
  const int row = blockIdx.x, tid = threadIdx.x;
  __shared__ float red[256];
  __shared__ int redi[256];
  float vals[18];
  float mx = 0.f; int cnt = 0;
  for (int c = tid; c < C_; c += 256){
    float v = SRC_F32 ? ((const float*)src)[(size_t)row*C_+c] : b2f(((const u16*)src)[(size_t)row*C_+c]);
    vals[cnt++] = v;
    mx = fmaxf(mx, fabsf(v));
  }
  red[tid]=mx; __syncthreads();
  for (int st=128; st>0; st>>=1){ if (tid<st) red[tid]=fmaxf(red[tid],red[tid+st]); __syncthreads(); }
  const float s_ = fmaxf(red[0]*(1.f/127.f), 1e-8f);
  const float inv = 1.f/s_;
  int acc = 0; cnt = 0;
  for (int c = tid; c < C_; c += 256){
    float q = rintf(vals[cnt++]*inv);
    q = fminf(fmaxf(q, -127.f), 127.f);
    q8[(size_t)row*C_+c] = (int8_t)q;
    acc += (int)q;
  }
  redi[tid]=acc; __syncthreads();
  for (int st=128; st>0; st>>=1){ if (tid<st) redi[tid]+=redi[tid+st]; __syncthreads(); }
  if (tid==0){ s_out[row]=s_; q_out[row]=redi[0]; }
}

// ------- f16 GEMM: out[M,N] = f16(A)[M,K] @ (Wh+Wl)[N,K]^T + bias -------
// A single f16 plane x B f16 hi/lo, 2 products (err ~2^-12 rel; see journal r11 error budget)
// BK=32, R8-verified XOR swizzle (0 conflicts). 24 KB LDS.
// MODE 0: f32 out. MODE 1: QKV epilogue (qk f16 plane + V^T f16). MODE 2: KV epilogue (k f16 + vtc f16)
template<int MODE>
__global__ __launch_bounds__(256,4) void gemm_f16k(
    const u16* __restrict__ Af, int lda,
    const u16* __restrict__ Wh, const u16* __restrict__ Wl, int ldw,
    const float* __restrict__ bias, float* __restrict__ out, int ldo, int M, int K,
    u16* __restrict__ e1, u16* __restrict__ e2){
  __shared__ u16 sA[128*32];
  __shared__ u16 sWh[128*32];
  __shared__ u16 sWl[128*32];
  const int tid = threadIdx.x, lane = tid & 63;
  const int wv = tid >> 6, wx = wv & 1, wy = wv >> 1;
  const int quad = lane >> 4, l16 = lane & 15;
  const int m0 = blockIdx.y*128, n0 = blockIdx.x*128;
  f32x4 acc[4][4];
  #pragma unroll
  for (int i=0;i<4;i++)
    #pragma unroll
    for (int j=0;j<4;j++) acc[i][j] = (f32x4){0.f,0.f,0.f,0.f};
  for (int k0=0; k0<K; k0+=32){
    #pragma unroll
    for (int r=0;r<2;r++){
      int slotbase = r*256 + wv*64;        // wave-uniform LDS base (slot*16B)
      int slot = slotbase + lane;
      int row = slot >> 2;                 // 4 chunks of 16B per 32-u16 row
      int col8 = ((slot ^ (row>>1)) & 3) * 8;  // phys chunk = logical ^ ((row>>1)&3)
      int gm = m0 + row; if (gm > M-1) gm = M-1;
      size_t aoff = (size_t)gm*lda + k0 + col8;
      size_t woff = (size_t)(n0+row)*ldw + k0 + col8;
      gl2lds16(Af + aoff, &sA[(size_t)slotbase*8]);
      gl2lds16(Wh + woff, &sWh[(size_t)slotbase*8]);
      gl2lds16(Wl + woff, &sWl[(size_t)slotbase*8]);
    }
    __syncthreads();
    const int cs = ((quad ^ ((l16>>1)&3)) * 8);  // recovers logical chunk = quad
    f16v8 a[4], bh[4], bl[4];
    #pragma unroll
    for (int i=0;i<4;i++) a[i] = ldh8(&sA[(wy*64+i*16+l16)*32 + cs]);
    #pragma unroll
    for (int j=0;j<4;j++){
      bh[j] = ldh8(&sWh[(wx*64+j*16+l16)*32 + cs]);
      bl[j] = ldh8(&sWl[(wx*64+j*16+l16)*32 + cs]);
    }
    #pragma unroll
    for (int i=0;i<4;i++)
      #pragma unroll
      for (int j=0;j<4;j++){
        acc[i][j] = MFMA_F16(a[i], bh[j], acc[i][j]);
        acc[i][j] = MFMA_F16(a[i], bl[j], acc[i][j]);
      }
    __syncthreads();
  }
  #pragma unroll
  for (int j=0;j<4;j++){
    int col = n0 + wx*64 + j*16 + l16;
    float bc = bias ? bias[col] : 0.f;
    #pragma unroll
    for (int i=0;i<4;i++)
      #pragma unroll
      for (int r=0;r<4;r++){
        int row = m0 + wy*64 + i*16 + quad*4 + r;
        if (row >= M) continue;
        float v = acc[i][j][r] + bc;
        if (MODE == 0){
          out[(size_t)row*ldo + col] = v;
        } else if (MODE == 1){
          if (col < 2304){
            e1[(size_t)row*2304 + col] = f2h(v);
          } else {
            int vc = col - 2304;
            int hd_ = vc/72, d = vc - hd_*72;
            int z = row >> 8, s2 = row & 255;
            e2[((size_t)(z*16+hd_)*80 + d)*256 + s2] = f2h(v);
          }
        } else { // MODE 2: KV epilogue (448 rows): k f16 plane + V^T [h][80][448] f16
          if (col < 1152){
            e1[(size_t)row*1152 + col] = f2h(v);
          } else {
            int vc = col - 1152;
            int hd_ = vc/72, d = vc - hd_*72;
            e2[((size_t)hd_*80 + d)*448 + row] = f2h(v);
          }
        }
      }
  }
}

// ---------------- int8 GEMM, 32x32x32 MFMA, W8A8 epilogue (128B-row XOR swizzle) ----------------
__global__ __launch_bounds__(256,3) void gemm_i8(
    const int8_t* __restrict__ A, int lda, const int8_t* __restrict__ W, int ldw,
    const float* __restrict__ rs, const int* __restrict__ rq,
    const float* __restrict__ sw, const int* __restrict__ zw, const float* __restrict__ bias,
    void* __restrict__ out, int ldo, int M, int K, int do_gelu, int out_f32,
    const float* __restrict__ xwf, const float* __restrict__ modf, int do_final){
  __shared__ int8_t As[128*128];
  __shared__ int8_t Bs[128*128];
  const int tid = threadIdx.x, lane = tid & 63, wv = tid >> 6;
  const int wx = wv & 1, wy = wv >> 1;
  const int l32 = lane & 31, g = lane >> 5;
  const int m0 = blockIdx.y*128, n0 = blockIdx.x*128;
  const int srow = lane >> 3, schunk = lane & 7;
  const int scol = ((schunk ^ srow) & 7) * 16;   // XOR swizzle fetch column (128B rows)
  i32x16 acc[2][2];
  #pragma unroll
  for (int i=0;i<2;i++)
    #pragma unroll
    for (int j=0;j<2;j++)
      #pragma unroll
      for (int r=0;r<16;r++) acc[i][j][r] = 0;
  for (int k0 = 0; k0 < K; k0 += 128){
    #pragma unroll
    for (int i=0;i<4;i++){
      int rr = (i*4 + wv)*8;
      int gm = m0 + rr + srow; if (gm > M-1) gm = M-1;
      gl2lds16(A + (size_t)gm*lda + k0 + scol, &As[rr*128]);
      int gn = n0 + rr + srow;
      gl2lds16(W + (size_t)gn*ldw + k0 + scol, &Bs[rr*128]);
    }
    __syncthreads();
    #pragma unroll
    for (int kq=0; kq<4; kq++){
      i32x4 af[2], bw[2];
      #pragma unroll
      for (int i=0;i<2;i++){
        int row = wy*64 + i*32 + l32;
        int cs = (((kq*2 + g) ^ (row & 7))) * 16;
        af[i] = *(const i32x4*)&As[row*128 + cs];
      }
      #pragma unroll
      for (int j=0;j<2;j++){
        int row = wx*64 + j*32 + l32;
        int cs = (((kq*2 + g) ^ (row & 7))) * 16;
        bw[j] = *(const i32x4*)&Bs[row*128 + cs];
      }
      #pragma unroll
      for (int i=0;i<2;i++)
        #pragma unroll
        for (int j=0;j<2;j++)
          acc[i][j] = MFMA_I8_32(af[i], bw[j], acc[i][j]);
    }
    __syncthreads();
  }
  #pragma unroll
  for (int j=0;j<2;j++){
    int col = n0 + wx*64 + j*32 + l32;
    float swc = sw[col]; float zwc = (float)zw[col]; float bc = bias[col];
    #pragma unroll
    for (int i=0;i<2;i++)
      #pragma unroll
      for (int r=0;r<16;r++){
        int row = m0 + wy*64 + i*32 + (r&3) + 8*(r>>2) + 4*g;
        if (row < M){
          float v = ((float)acc[i][j][r] - (float)rq[row]*zwc) * (rs[row]*swc) + bc;
          if (do_gelu) v = gelu_t(v);
          if (do_final){
            int bb = row >> 11;
            float ov = xwf[(size_t)row*1152 + col] + modf[((size_t)bb*6+5)*1152 + col]*v;
            ((float*)out)[(size_t)row*ldo + col] = ov;
          } else if (out_f32) ((float*)out)[(size_t)row*ldo + col] = v;
          else                ((u16*)out)[(size_t)row*ldo + col] = f2b(v);
        }
      }
  }
}

// ---------------- self-attention (f16 single planes) ----------------
__global__ __launch_bounds__(256) void attn_self_f16(
    const u16* __restrict__ qkf, const u16* __restrict__ vtf,
    u16* __restrict__ of, float scale){
  constexpr int NT = 16, PSTR = 264, VSTR = 256;
  __shared__ u16 P[4*16*PSTR];
  const int tid = threadIdx.x, lane = tid & 63, wv = tid >> 6;
  const int quad = lane >> 4, l16 = lane & 15;
  const int h = blockIdx.y, z = blockIdx.z;
  const int qbase = z*256 + blockIdx.x*64;
  const u16* Vth = vtf + (size_t)(z*16+h)*80*VSTR;
  const f16v8 zf = __builtin_bit_cast(f16v8, (u16v8)0);
  const int mrow = qbase + wv*16 + l16;

  f16v8 qf[3];
  #pragma unroll
  for (int t=0;t<3;t++){
    if (t==2 && quad!=0){ qf[t]=zf; }
    else qf[t] = ldh8(qkf + (size_t)mrow*2304 + h*72 + t*32 + (t==2?0:quad*8));
  }
  f32x4 sc[NT];
  #pragma unroll
  for (int nt=0; nt<NT; nt++){
    f32x4 a = {0.f,0.f,0.f,0.f};
    #pragma unroll
    for (int t=0;t<3;t++){
      f16v8 kf = zf;
      if (!(t==2 && quad!=0))
        kf = ldh8(qkf + (size_t)(z*256 + nt*16 + l16)*2304 + 1152 + h*72 + t*32 + (t==2?0:quad*8));
      a = MFMA_F16(qf[t], kf, a);
    }
    sc[nt] = a;
  }
  float mx[4] = {-1e30f,-1e30f,-1e30f,-1e30f};
  #pragma unroll
  for (int nt=0; nt<NT; nt++)
    #pragma unroll
    for (int r=0;r<4;r++){ float v = sc[nt][r]*scale; sc[nt][r]=v; mx[r]=fmaxf(mx[r],v); }
  #pragma unroll
  for (int r=0;r<4;r++)
    for (int d=1; d<16; d<<=1) mx[r] = fmaxf(mx[r], __shfl_xor(mx[r], d, 64));
  float sm[4] = {0.f,0.f,0.f,0.f};
  #pragma unroll
  for (int nt=0; nt<NT; nt++)
    #pragma unroll
    for (int r=0;r<4;r++){ float p = __expf(sc[nt][r]-mx[r]); sc[nt][r]=p; sm[r]+=p; }
  #pragma unroll
  for (int r=0;r<4;r++){
    for (int d=1; d<16; d<<=1) sm[r] += __shfl_xor(sm[r], d, 64);
    sm[r] = 1.f/sm[r];
  }
  u16* Pw = P + wv*16*PSTR;
  #pragma unroll
  for (int nt=0; nt<NT; nt++)
    #pragma unroll
    for (int r=0;r<4;r++)
      Pw[(quad*4+r)*PSTR + nt*16 + l16] = f2h(sc[nt][r]*sm[r]);
  const u16* Pr = P + wv*16*PSTR + (size_t)l16*PSTR;
  #pragma unroll
  for (int dt=0; dt<5; dt++){
    f32x4 o = {0.f,0.f,0.f,0.f};
    #pragma unroll
    for (int kk=0; kk<8; kk++){
      f16v8 pv = ldh8(Pr + kk*32 + quad*8);
      f16v8 bv = ldh8(Vth + (size_t)(dt*16+l16)*VSTR + kk*32 + quad*8);
      o = MFMA_F16(pv, bv, o);
    }
    int d = dt*16 + l16;
    if (d < 72){
      #pragma unroll
      for (int r=0;r<4;r++){
        int row = qbase + wv*16 + quad*4 + r;
        of[(size_t)row*1152 + h*72 + d] = f2h(o[r]);
      }
    }
  }
}

// ---------------- cross-attention (f16 q/k/P/V, f32 scores+softmax) ----------------
__global__ __launch_bounds__(256) void attn_cross_f16(
    const float* __restrict__ Q32,
    const u16* __restrict__ Kf,                  // 448x1152 f16
    const u16* __restrict__ Vt,                  // [h][80][448] f16
    float* __restrict__ O, float scale){
  constexpr int NT = 28, PSTR = 456, VSTR = 448;
  __shared__ u16 P[4*16*PSTR];
  const int tid = threadIdx.x, lane = tid & 63, wv = tid >> 6;
  const int quad = lane >> 4, l16 = lane & 15;
  const int h = blockIdx.y;
  const int qbase = blockIdx.x*64;
  const u16* Vth = Vt + (size_t)h*80*VSTR;
  const f16v8 zf = __builtin_bit_cast(f16v8, (u16v8)0);

  const int mrow = qbase + wv*16 + l16;
  const float* qp = Q32 + (size_t)mrow*1152 + h*72;
  f16v8 qf[3];
  #pragma unroll
  for (int t=0;t<3;t++){
    if (t==2 && quad!=0){ qf[t]=zf; continue; }
    u16v8 hv;
    #pragma unroll
    for (int j=0;j<8;j++) hv[j] = f2h(qp[t*32 + (t==2?0:quad*8) + j]);
    qf[t] = __builtin_bit_cast(f16v8, hv);
  }
  f32x4 sc[NT];
  #pragma unroll
  for (int nt=0; nt<NT; nt++){
    f32x4 a = {0.f,0.f,0.f,0.f};
    #pragma unroll
    for (int t=0;t<3;t++){
      f16v8 kf = zf;
      if (!(t==2 && quad!=0))
        kf = ldh8(Kf + (size_t)(nt*16 + l16)*1152 + h*72 + t*32 + (t==2?0:quad*8));
      a = MFMA_F16(qf[t], kf, a);
    }
    sc[nt] = a;
  }
  float mx[4] = {-1e30f,-1e30f,-1e30f,-1e30f};
  #pragma unroll
  for (int nt=0; nt<NT; nt++)
    #pragma unroll
    for (int r=0;r<4;r++){ float v = sc[nt][r]*scale; sc[nt][r]=v; mx[r]=fmaxf(mx[r],v); }
  #pragma unroll
  for (int r=0;r<4;r++)
    for (int d=1; d<16; d<<=1) mx[r] = fmaxf(mx[r], __shfl_xor(mx[r], d, 64));
  float sm[4] = {0.f,0.f,0.f,0.f};
  #pragma unroll
  for (int nt=0; nt<NT; nt++)
    #pragma unroll
    for (int r=0;r<4;r++){ float p = __expf(sc[nt][r]-mx[r]); sc[nt][r]=p; sm[r]+=p; }
  #pragma unroll
  for (int r=0;r<4;r++){
    for (int d=1; d<16; d<<=1) sm[r] += __shfl_xor(sm[r], d, 64);
    sm[r] = 1.f/sm[r];
  }
  u16* Pw = P + wv*16*PSTR;
  #pragma unroll
  for (int nt=0; nt<NT; nt++)
    #pragma unroll
    for (int r=0;r<4;r++)
      Pw[(quad*4+r)*PSTR + nt*16 + l16] = f2h(sc[nt][r]*sm[r]);
  const u16* Pr = P + wv*16*PSTR + (size_t)l16*PSTR;
  #pragma unroll
  for (int dt=0; dt<5; dt++){
    f32x4 o = {0.f,0.f,0.f,0.f};
    #pragma unroll
    for (int kk=0; kk<14; kk++){
      f16v8 pv = ldh8(Pr + kk*32 + quad*8);
      f16v8 bv = ldh8(Vth + (size_t)(dt*16+l16)*VSTR + kk*32 + quad*8);
      o = MFMA_F16(pv, bv, o);
    }
    int d = dt*16 + l16;
    if (d < 72){
      #pragma unroll
      for (int r=0;r<4;r++){
        int row = qbase + wv*16 + quad*4 + r;
        O[(size_t)row*1152 + h*72 + d] = o[r];
      }
    }
  }
}

// ---------------- launch ----------------
extern "C" void kernel_launch(void* const* d_in, const int* in_sizes, int n_in,
                              void* d_out, int out_size, void* d_ws, size_t ws_size,
                              hipStream_t stream){
  const float* x    = (const float*)d_in[0];
  const float* y    = (const float*)d_in[1];
  const float* t    = (const float*)d_in[2];
  const float* sst  = (const float*)d_in[3];
  const float* Wqkv = (const float*)d_in[4];
  const float* bqkv = (const float*)d_in[5];
  const float* Wo   = (const float*)d_in[6];
  const float* bo   = (const float*)d_in[7];
  const float* Wkv  = (const float*)d_in[8];
  const float* bkv  = (const float*)d_in[9];
  const int*   qw_q  = (const int*)d_in[10];
  const float* sw_q  = (const float*)d_in[11];
  const int*   zw_q  = (const int*)d_in[12];
  const float* b_q   = (const float*)d_in[13];
  const int*   qw_cp = (const int*)d_in[14];
  const float* sw_cp = (const float*)d_in[15];
  const int*   zw_cp = (const int*)d_in[16];
  const float* b_cp  = (const float*)d_in[17];
  const int*   qw_f1 = (const int*)d_in[18];
  const float* sw_f1 = (const float*)d_in[19];
  const int*   zw_f1 = (const int*)d_in[20];
  const float* b_f1  = (const float*)d_in[21];
  const int*   qw_f2 = (const int*)d_in[22];
  const float* sw_f2 = (const float*)d_in[23];
  const int*   zw_f2 = (const int*)d_in[24];
  const float* b_f2  = (const float*)d_in[25];
  (void)in_sizes; (void)n_in; (void)out_size;

  constexpr size_t SZR = (size_t)4096*1152*4;        // 18,874,368
  constexpr size_t R0 = 0;                           // xw f32
  constexpr size_t R1 = R0 + SZR;                    // wqkv f16 planes -> wkv/y -> q32 -> cpout -> q8h
  constexpr size_t R2 = R1 + SZR;                    // qkf (4096x2304 f16) -> aof f32 -> hbuf(part)
  constexpr size_t R3 = R2 + SZR;                    // hbuf(part)
  constexpr size_t R4 = R3 + SZR;                    // xmf/of -> kf+vtc -> w8f2
  constexpr size_t R5 = R4 + (size_t)9437184;        // w8q,w8cp,w8f1
  constexpr size_t R6 = R5 + (size_t)9437184;        // vtf -> woh/wol -> q8x
  constexpr size_t RS = R6 + (size_t)10485760;
  constexpr size_t RQ = RS + (size_t)4096*4;
  constexpr size_t RM = RQ + (size_t)4096*4;
  constexpr size_t WS_NEED = RM + (size_t)2*6*1152*4;  // ~100.1 MB (proven ws >= 121.8 MB)
  if (ws_size < WS_NEED) return;

  char* ws = (char*)d_ws;
  float*  xw    = (float*)(ws + R0);
  u16*    wqkvh = (u16*)(ws + R1);
  u16*    wqkvl = (u16*)(ws + R1 + (size_t)3456*1152*2);
  u16*    wkvh  = (u16*)(ws + R1);
  u16*    wkvl  = (u16*)(ws + R1 + (size_t)2304*1152*2);
  u16*    yf    = (u16*)(ws + R1 + (size_t)2*2304*1152*2);
  float*  q32   = (float*)(ws + R1);
  float*  cpout = (float*)(ws + R1);
  int8_t* q8h   = (int8_t*)(ws + R1);
  u16*    qkf   = (u16*)(ws + R2);     // 4096x2304 f16 (fills R2 exactly)
  float*  aof   = (float*)(ws + R2);   // wo-out, later cross-attn out
  u16*    hbuf  = (u16*)(ws + R2);     // 4096x4608 bf16 spans R2+R3
  u16*    xmf   = (u16*)(ws + R4);     // 4096x1152 f16
  u16*    of    = (u16*)(ws + R4);     // attn-self out f16 (aliases xmf, dead)
  u16*    kf    = (u16*)(ws + R4 + (size_t)4128768);
  u16*    vtc   = (u16*)(ws + R4 + (size_t)6193152);
  int8_t* w8f2  = (int8_t*)(ws + R4);
  int8_t* w8q   = (int8_t*)(ws + R5);
  int8_t* w8cp  = (int8_t*)(ws + R5 + (size_t)1327104);
  int8_t* w8f1  = (int8_t*)(ws + R5 + (size_t)2654208);
  u16*    vtf   = (u16*)(ws + R6);     // 256x80x256 f16 (fills R6 exactly)
  u16*    woh   = (u16*)(ws + R6);
  u16*    wol   = (u16*)(ws + R6 + (size_t)1152*1152*2);
  int8_t* q8x   = (int8_t*)(ws + R6);
  float*  rs    = (float*)(ws + RS);
  int*    rq    = (int*)(ws + RQ);
  float*  mod   = (float*)(ws + RM);

  const float scale = 0.11785113019775793f; // 72^-0.5

  mod_add_k<<<(2*6*1152+255)/256,256,0,stream>>>(sst, t, mod);

  // ---- MSA branch (f16 GEMMs) ----
  ln_mod_f16_k<<<4096,256,0,stream>>>(x, xmf, mod, 0, 1);
  split2h_k<<<(3456*1152+255)/256,256,0,stream>>>(Wqkv, wqkvh, wqkvl, 3456*1152);
  gemm_f16k<1><<<dim3(27,32),256,0,stream>>>(xmf,1152, wqkvh,wqkvl,1152, bqkv, nullptr,0, 4096,1152, qkf,vtf);
  attn_self_f16<<<dim3(4,16,16),256,0,stream>>>(qkf, vtf, of, scale);
  split2h_k<<<(1152*1152+255)/256,256,0,stream>>>(Wo, woh, wol, 1152*1152);
  gemm_f16k<0><<<dim3(9,32),256,0,stream>>>(of,1152, woh,wol,1152, bo, aof,1152, 4096,1152, nullptr,nullptr);
  rgq_k<<<4096,256,0,stream>>>(x, aof, mod, 2, xw, q8x, rs, rq);

  // ---- cross-attn branch ----
  cross_prep_k<<<(5824512+255)/256,256,0,stream>>>(qw_q,w8q, qw_cp,w8cp, Wkv,wkvh,wkvl, y,yf);
  gemm_f16k<2><<<dim3(18,4),256,0,stream>>>(yf,1152, wkvh,wkvl,1152, bkv, nullptr,0, 448,1152, kf,vtc);
  gemm_i8<<<dim3(9,32),256,0,stream>>>(q8x,1152, w8q,1152, rs,rq, sw_q,zw_q,b_q, q32,1152, 4096,1152, 0, 1, nullptr,nullptr,0);
  attn_cross_f16<<<dim3(64,16),256,0,stream>>>(q32, kf, vtc, aof, scale);
  quant_rows_k<1><<<4096,256,0,stream>>>(aof, 1152, q8x, rs, rq);
  gemm_i8<<<dim3(9,32),256,0,stream>>>(q8x,1152, w8cp,1152, rs,rq, sw_cp,zw_cp,b_cp, cpout,1152, 4096,1152, 0, 1, nullptr,nullptr,0);

  // ---- MLP branch ----
  rlq_k<<<4096,256,0,stream>>>(xw, cpout, mod, 3, 4, q8x, rs, rq);
  mlp_prep_k<<<(10616832+255)/256,256,0,stream>>>(qw_f1, w8f1, qw_f2, w8f2);
  gemm_i8<<<dim3(36,32),256,0,stream>>>(q8x,1152, w8f1,1152, rs,rq, sw_f1,zw_f1,b_f1, hbuf,4608, 4096,1152, 1, 0, nullptr,nullptr,0);
  quant_rows_k<0><<<4096,256,0,stream>>>(hbuf, 4608, q8h, rs, rq);
  gemm_i8<<<dim3(9,32),256,0,stream>>>(q8h,4608, w8f2,4608, rs,rq, sw_f2,zw_f2,b_f2, d_out,1152, 4096,4608, 0, 1, xw,mod,1);
}